// Round 12
// baseline (1909.954 us; speedup 1.0000x reference)
//
#include <hip/hip_runtime.h>
#include <hip/hip_bf16.h>

constexpr int B   = 4;
constexpr int N   = 1024;
constexpr int D   = 128;
constexpr int KNN = 10;
constexpr int NH  = 4;

typedef _Float16 half2v __attribute__((ext_vector_type(2)));

static __device__ __forceinline__ half2v pkrtz(float a, float b) {
  return __builtin_bit_cast(half2v, __builtin_amdgcn_cvt_pkrtz(a, b));
}

// ---------------------------------------------------------------- norm p2d
__global__ __launch_bounds__(256) void k_norm2d(const float* __restrict__ p2d,
                                                float* __restrict__ f2) {
  int i = blockIdx.x * 256 + threadIdx.x;  // over B*N
  const float* p = p2d + (size_t)i * 3;
  float x = p[0], y = p[1], z = p[2];
  float inr = 1.f / sqrtf(x * x + y * y + z * z);
  float* o = f2 + (size_t)i * 3;
  o[0] = x * inr; o[1] = y * inr; o[2] = z * inr;
}

// ---------------------------------------------------------------- KNN encode
__global__ __launch_bounds__(256) void k_encode(const float* __restrict__ pts,
                                                const float* __restrict__ w,
                                                const float* __restrict__ bias,
                                                float* __restrict__ desc) {
  __shared__ float P[N][3];
  __shared__ float xx[N];
  __shared__ float dist[N];
  __shared__ float rv[256];
  __shared__ int   ri[256];
  __shared__ float feat[6];
  __shared__ int   nidx[KNN];
  int t = threadIdx.x;
  int n = blockIdx.x, b = blockIdx.y;
  const float* pb = pts + (size_t)b * N * 3;
  for (int i = t; i < N; i += 256) {
    float x = pb[i * 3 + 0], y = pb[i * 3 + 1], z = pb[i * 3 + 2];
    P[i][0] = x; P[i][1] = y; P[i][2] = z;
    xx[i] = x * x + y * y + z * z;
  }
  __syncthreads();
  float cx = P[n][0], cy = P[n][1], cz = P[n][2], cxx = xx[n];
  for (int i = t; i < N; i += 256) {
    float ip = cx * P[i][0] + cy * P[i][1] + cz * P[i][2];
    dist[i] = 2.f * ip - cxx - xx[i];
  }
  __syncthreads();
  for (int kk = 0; kk < KNN; ++kk) {
    float bv = -3.0e38f; int bi = N;
    for (int i = t; i < N; i += 256) {
      float v = dist[i];
      if (v > bv) { bv = v; bi = i; }
    }
    rv[t] = bv; ri[t] = bi;
    __syncthreads();
    for (int s = 128; s > 0; s >>= 1) {
      if (t < s) {
        float v2 = rv[t + s]; int i2 = ri[t + s];
        if (v2 > rv[t] || (v2 == rv[t] && i2 < ri[t])) { rv[t] = v2; ri[t] = i2; }
      }
      __syncthreads();
    }
    if (t == 0) { nidx[kk] = ri[0]; dist[ri[0]] = -3.0e38f; }
    __syncthreads();
  }
  if (t == 0) {
    float sx = 0, sy = 0, sz = 0;
    for (int kk = 0; kk < KNN; ++kk) {
      int i = nidx[kk];
      sx += P[i][0]; sy += P[i][1]; sz += P[i][2];
    }
    const float invk = 1.f / KNN;
    feat[0] = sx * invk - cx; feat[1] = sy * invk - cy; feat[2] = sz * invk - cz;
    feat[3] = cx; feat[4] = cy; feat[5] = cz;
  }
  __syncthreads();
  if (t < D) {
    const float* wr = w + t * 6;
    float a = bias[t];
#pragma unroll
    for (int j = 0; j < 6; ++j) a += wr[j] * feat[j];
    desc[((size_t)b * D + t) * N + n] = a;
  }
}

// ---------------------------------------------------------------- tiled GEMM conv (unchanged from R9)
__global__ __launch_bounds__(256) void k_gemm(
    const float* __restrict__ pA0, const float* __restrict__ pA1,
    const float* __restrict__ pB0, const float* __restrict__ pB1,
    const float* __restrict__ w, const float* __restrict__ bias,
    const float* __restrict__ res, float* __restrict__ out,
    const float* __restrict__ stat, const float* __restrict__ g,
    const float* __restrict__ bt,
    int Cin, int catOff, size_t a_bstr, size_t b_bstr,
    int segCout, size_t segStride, int qkvMode) {
  __shared__ float As[64][36];
  __shared__ float Bs[32][128];
  __shared__ float Ac[256], Bc[256];
  const int tid = threadIdx.x;
  const int to = tid >> 4;
  const int tn = tid & 15;
  const int o0 = blockIdx.y * 64;
  const int zb = blockIdx.x;
  const int z  = zb >> 3;
  const int n0 = (zb & 7) * 128;
  const int s = z >> 2, b = z & 3;
  const int seg = o0 / segCout;
  const int oo  = o0 % segCout;

  const float* XA = (s ? pA1 : pA0) + (size_t)b * a_bstr;
  const float* XB = pB0 ? ((s ? pB1 : pB0) + (size_t)b * b_bstr) : nullptr;
  const bool segB = qkvMode && (seg > 0);

  if (stat) {
    const float* st = stat + (size_t)s * 256 * 2;
    float A = st[tid * 2 + 1] * g[tid];
    Ac[tid] = A;
    Bc[tid] = fmaf(-st[tid * 2 + 0], A, bt[tid]);
  }

  float acc[4][8];
#pragma unroll
  for (int i = 0; i < 4; ++i)
#pragma unroll
    for (int j = 0; j < 8; ++j) acc[i][j] = 0.f;

  for (int kb = 0; kb < Cin; kb += 32) {
    __syncthreads();
#pragma unroll
    for (int j = 0; j < 2; ++j) {
      int idx = j * 256 + tid;
      int o = idx >> 3, c4 = (idx & 7) * 4;
      float4 wv = *(const float4*)&w[(size_t)(o0 + o) * Cin + kb + c4];
      *(float4*)&As[o][c4] = wv;
    }
#pragma unroll
    for (int j = 0; j < 4; ++j) {
      int idx = j * 256 + tid;
      int r = idx >> 5, c4 = (idx & 31) * 4;
      int c = kb + r;
      const float* src;
      int cc = c;
      if (qkvMode) {
        src = segB ? XB : XA;
      } else if (c >= catOff) {
        src = XB; cc = c - catOff;
      } else {
        src = XA;
      }
      float4 v = *(const float4*)&src[(size_t)cc * N + n0 + c4];
      if (stat) {
        float A = Ac[c], Bb = Bc[c];
        v.x = fmaxf(fmaf(v.x, A, Bb), 0.f);
        v.y = fmaxf(fmaf(v.y, A, Bb), 0.f);
        v.z = fmaxf(fmaf(v.z, A, Bb), 0.f);
        v.w = fmaxf(fmaf(v.w, A, Bb), 0.f);
      }
      *(float4*)&Bs[r][c4] = v;
    }
    __syncthreads();
#pragma unroll
    for (int kk = 0; kk < 32; ++kk) {
      float af0 = As[to * 4 + 0][kk];
      float af1 = As[to * 4 + 1][kk];
      float af2 = As[to * 4 + 2][kk];
      float af3 = As[to * 4 + 3][kk];
      float4 b0 = *(const float4*)&Bs[kk][tn * 8];
      float4 b1 = *(const float4*)&Bs[kk][tn * 8 + 4];
      float bv[8] = {b0.x, b0.y, b0.z, b0.w, b1.x, b1.y, b1.z, b1.w};
#pragma unroll
      for (int j = 0; j < 8; ++j) {
        acc[0][j] = fmaf(af0, bv[j], acc[0][j]);
        acc[1][j] = fmaf(af1, bv[j], acc[1][j]);
        acc[2][j] = fmaf(af2, bv[j], acc[2][j]);
        acc[3][j] = fmaf(af3, bv[j], acc[3][j]);
      }
    }
  }
#pragma unroll
  for (int i = 0; i < 4; ++i) {
    int og = o0 + to * 4 + i;
    int o  = oo + to * 4 + i;
    float bi = bias[og];
    size_t ob = (size_t)seg * segStride + ((size_t)z * segCout + o) * N + n0 + tn * 8;
    float4 r0, r1;
    r0.x = acc[i][0] + bi; r0.y = acc[i][1] + bi;
    r0.z = acc[i][2] + bi; r0.w = acc[i][3] + bi;
    r1.x = acc[i][4] + bi; r1.y = acc[i][5] + bi;
    r1.z = acc[i][6] + bi; r1.w = acc[i][7] + bi;
    if (res) {
      float4 e0 = *(const float4*)&res[ob];
      float4 e1 = *(const float4*)&res[ob + 4];
      r0.x += e0.x; r0.y += e0.y; r0.z += e0.z; r0.w += e0.w;
      r1.x += e1.x; r1.y += e1.y; r1.z += e1.z; r1.w += e1.w;
    }
    *(float4*)&out[ob] = r0;
    *(float4*)&out[ob + 4] = r1;
  }
}

// ---------------------------------------------------------------- attention v8: f16 K/V + v_dot2, QPL=4
// grid (N/256, NH, 2*B) = 128 blocks, 4 waves. Wave s owns keys [s*256,(s+1)*256).
// Each lane owns FOUR queries (lq + qi*64): each K/V b128 read now feeds 16
// fdot2 (32 MACs) -> global LDS-read count halves vs v7 (the measured floor).
// 4 independent fdot2 chains/read give ILP at 1 wave/SIMD. Merge reuses the
// 67.6KB pool in TWO rounds of 128 q (no LDS growth). No min-waves bound
// (R4); ~240 VGPR expected — watch WRITE_SIZE for scratch.
__global__ __launch_bounds__(256) void k_attn(const float* __restrict__ Q,
                                              const float* __restrict__ Kt,
                                              const float* __restrict__ Vt,
                                              float* __restrict__ O) {
  __shared__ float pool[16896];          // staging (f16, 16KB); merge f32 67.6KB
  __shared__ float ms_[4][128], ls_[4][128];
  half2v* pool2 = (half2v*)pool;
  const int t  = threadIdx.x;
  const int lq = t & 63, s = t >> 6;
  const int q0 = blockIdx.x * 256;
  const int h  = blockIdx.y;
  const int z  = blockIdx.z;
  const size_t base = (size_t)z * (size_t)(D * N);
  const float* Kb = Kt + base;
  const float* Vb = Vt + base;
  const int sb2 = s * 1024;             // per-wave region: K [0,512), V [512,1024)
  const int kg  = lq & 7;               // staging key-group (4 keys)
  const int dp  = lq >> 3;              // 0..7

  const float scale = 0.17677669529663687f;  // 1/sqrt(32), folded into q
  half2v qp[4][16];
  float acc[4][32];
  float mx[4], lsum[4];
#pragma unroll
  for (int dd = 0; dd < 16; ++dd) {
    const float* r0 = Q + base + (size_t)((2 * dd) * 4 + h) * N + q0 + lq;
    const float* r1 = Q + base + (size_t)((2 * dd + 1) * 4 + h) * N + q0 + lq;
#pragma unroll
    for (int qi = 0; qi < 4; ++qi)
      qp[qi][dd] = pkrtz(r0[qi * 64] * scale, r1[qi * 64] * scale);
  }
#pragma unroll
  for (int qi = 0; qi < 4; ++qi) {
    mx[qi] = -1e30f; lsum[qi] = 0.f;
#pragma unroll
    for (int d = 0; d < 32; ++d) acc[qi][d] = 0.f;
  }

  for (int c = 0; c < 8; ++c) {
    const int k0 = s * 256 + c * 32;
    // ---- stage K: Kh[j][dd] = (K[2dd][j], K[2dd+1][j]) f16
#pragma unroll
    for (int rep = 0; rep < 2; ++rep) {
      int dd = dp + rep * 8;
      const float4 va = *(const float4*)(Kb + (size_t)((2 * dd) * 4 + h) * N + k0 + kg * 4);
      const float4 vb = *(const float4*)(Kb + (size_t)((2 * dd + 1) * 4 + h) * N + k0 + kg * 4);
      pool2[sb2 + (kg * 4 + 0) * 16 + dd] = pkrtz(va.x, vb.x);
      pool2[sb2 + (kg * 4 + 1) * 16 + dd] = pkrtz(va.y, vb.y);
      pool2[sb2 + (kg * 4 + 2) * 16 + dd] = pkrtz(va.z, vb.z);
      pool2[sb2 + (kg * 4 + 3) * 16 + dd] = pkrtz(va.w, vb.w);
    }
    // ---- stage V: Vp[d][jp] = (V[2jp][d], V[2jp+1][d]) f16
#pragma unroll
    for (int rep = 0; rep < 4; ++rep) {
      int d = dp + rep * 8;
      const float4 vv = *(const float4*)(Vb + (size_t)(d * 4 + h) * N + k0 + kg * 4);
      int idx = sb2 + 512 + d * 16 + kg * 2;
      pool2[idx]     = pkrtz(vv.x, vv.y);
      pool2[idx + 1] = pkrtz(vv.z, vv.w);
    }
    // ---- 4 steps of 8 keys
#pragma unroll
    for (int st = 0; st < 4; ++st) {
      float sc[4][8];
#pragma unroll
      for (int jj = 0; jj < 8; ++jj) {
        const int rb = sb2 + (st * 8 + jj) * 16;
        float aq0 = 0.f, aq1 = 0.f, aq2 = 0.f, aq3 = 0.f;
#pragma unroll
        for (int r = 0; r < 4; ++r) {
          float4 raw = *(const float4*)&pool2[rb + r * 4];
          half2v k0h = __builtin_bit_cast(half2v, raw.x);
          half2v k1h = __builtin_bit_cast(half2v, raw.y);
          half2v k2h = __builtin_bit_cast(half2v, raw.z);
          half2v k3h = __builtin_bit_cast(half2v, raw.w);
          aq0 = __builtin_amdgcn_fdot2(k0h, qp[0][r * 4 + 0], aq0, false);
          aq0 = __builtin_amdgcn_fdot2(k1h, qp[0][r * 4 + 1], aq0, false);
          aq0 = __builtin_amdgcn_fdot2(k2h, qp[0][r * 4 + 2], aq0, false);
          aq0 = __builtin_amdgcn_fdot2(k3h, qp[0][r * 4 + 3], aq0, false);
          aq1 = __builtin_amdgcn_fdot2(k0h, qp[1][r * 4 + 0], aq1, false);
          aq1 = __builtin_amdgcn_fdot2(k1h, qp[1][r * 4 + 1], aq1, false);
          aq1 = __builtin_amdgcn_fdot2(k2h, qp[1][r * 4 + 2], aq1, false);
          aq1 = __builtin_amdgcn_fdot2(k3h, qp[1][r * 4 + 3], aq1, false);
          aq2 = __builtin_amdgcn_fdot2(k0h, qp[2][r * 4 + 0], aq2, false);
          aq2 = __builtin_amdgcn_fdot2(k1h, qp[2][r * 4 + 1], aq2, false);
          aq2 = __builtin_amdgcn_fdot2(k2h, qp[2][r * 4 + 2], aq2, false);
          aq2 = __builtin_amdgcn_fdot2(k3h, qp[2][r * 4 + 3], aq2, false);
          aq3 = __builtin_amdgcn_fdot2(k0h, qp[3][r * 4 + 0], aq3, false);
          aq3 = __builtin_amdgcn_fdot2(k1h, qp[3][r * 4 + 1], aq3, false);
          aq3 = __builtin_amdgcn_fdot2(k2h, qp[3][r * 4 + 2], aq3, false);
          aq3 = __builtin_amdgcn_fdot2(k3h, qp[3][r * 4 + 3], aq3, false);
        }
        sc[0][jj] = aq0; sc[1][jj] = aq1; sc[2][jj] = aq2; sc[3][jj] = aq3;
      }
      // online softmax per query (f32)
      half2v p2[4][4];
#pragma unroll
      for (int qi = 0; qi < 4; ++qi) {
        float hm = sc[qi][0];
#pragma unroll
        for (int j = 1; j < 8; ++j) hm = fmaxf(hm, sc[qi][j]);
        float nm = fmaxf(mx[qi], hm);
        float cr = __expf(mx[qi] - nm);
        lsum[qi] *= cr;
#pragma unroll
        for (int d = 0; d < 32; ++d) acc[qi][d] *= cr;
        mx[qi] = nm;
#pragma unroll
        for (int j = 0; j < 8; ++j) {
          sc[qi][j] = __expf(sc[qi][j] - mx[qi]);
          lsum[qi] += sc[qi][j];
        }
#pragma unroll
        for (int u = 0; u < 4; ++u)
          p2[qi][u] = pkrtz(sc[qi][2 * u], sc[qi][2 * u + 1]);
      }
      // PV: one b128 read = 8 keys at dim d, feeds 4 queries
#pragma unroll
      for (int d = 0; d < 32; ++d) {
        float4 raw = *(const float4*)&pool2[sb2 + 512 + d * 16 + st * 4];
        half2v v0 = __builtin_bit_cast(half2v, raw.x);
        half2v v1 = __builtin_bit_cast(half2v, raw.y);
        half2v v2 = __builtin_bit_cast(half2v, raw.z);
        half2v v3 = __builtin_bit_cast(half2v, raw.w);
#pragma unroll
        for (int qi = 0; qi < 4; ++qi) {
          float aa = acc[qi][d];
          aa = __builtin_amdgcn_fdot2(v0, p2[qi][0], aa, false);
          aa = __builtin_amdgcn_fdot2(v1, p2[qi][1], aa, false);
          aa = __builtin_amdgcn_fdot2(v2, p2[qi][2], aa, false);
          aa = __builtin_amdgcn_fdot2(v3, p2[qi][3], aa, false);
          acc[qi][d] = aa;
        }
      }
    }
  }

  // ---- merge 4 key-split partials in TWO rounds of 128 q (pool reuse)
#pragma unroll
  for (int rr = 0; rr < 2; ++rr) {
    __syncthreads();                     // staging reads (rr=0) / prev merge reads (rr=1) done
    ms_[s][lq] = mx[2 * rr];     ms_[s][64 + lq] = mx[2 * rr + 1];
    ls_[s][lq] = lsum[2 * rr];   ls_[s][64 + lq] = lsum[2 * rr + 1];
#pragma unroll
    for (int d = 0; d < 32; ++d) {
      pool[(s * 128 + lq) * 33 + d] = acc[2 * rr][d];
      pool[(s * 128 + 64 + lq) * 33 + d] = acc[2 * rr + 1][d];
    }
    __syncthreads();
    {
      int qq = t & 127, dh = t >> 7;
      float M = fmaxf(fmaxf(ms_[0][qq], ms_[1][qq]), fmaxf(ms_[2][qq], ms_[3][qq]));
      float wg[4], L = 0.f;
#pragma unroll
      for (int ss = 0; ss < 4; ++ss) {
        wg[ss] = __expf(ms_[ss][qq] - M);
        L += ls_[ss][qq] * wg[ss];
      }
      float invL = 1.f / L;
#pragma unroll
      for (int k = 0; k < 16; ++k) {
        int d = dh * 16 + k;
        float o = 0.f;
#pragma unroll
        for (int ss = 0; ss < 4; ++ss) o += pool[(ss * 128 + qq) * 33 + d] * wg[ss];
        O[base + (size_t)(d * 4 + h) * N + q0 + rr * 128 + qq] = o * invL;
      }
    }
  }
}

// ---------------------------------------------------------------- BN stats (single pass)
__global__ __launch_bounds__(256) void k_bnstat(const float* __restrict__ h,
                                                float* __restrict__ stat) {
  int c = blockIdx.x, s = blockIdx.y, t = threadIdx.x;
  __shared__ float red[256], red2[256];
  const float* base = h + ((size_t)s * B * 256 + c) * N;
  float sum = 0, sq = 0;
  for (int b = 0; b < B; ++b)
    for (int i = t; i < N; i += 256) {
      float v = base[(size_t)b * 256 * N + i];
      sum += v; sq = fmaf(v, v, sq);
    }
  red[t] = sum; red2[t] = sq; __syncthreads();
  for (int sft = 128; sft > 0; sft >>= 1) {
    if (t < sft) { red[t] += red[t + sft]; red2[t] += red2[t + sft]; }
    __syncthreads();
  }
  if (t == 0) {
    float mean = red[0] / (float)(B * N);
    float var = fmaxf(red2[0] / (float)(B * N) - mean * mean, 0.f);
    stat[(s * 256 + c) * 2 + 0] = mean;
    stat[(s * 256 + c) * 2 + 1] = 1.f / sqrtf(var + 1e-5f);
  }
}

// ---------------------------------------------------------------- pairwise dist (8-m tile)
__global__ __launch_bounds__(256) void k_dist(const float* __restrict__ d0,
                                              const float* __restrict__ d1,
                                              float* __restrict__ la) {
  __shared__ float xm[8][128];
  __shared__ float n0s[8];
  int m0 = blockIdx.x * 8, b = blockIdx.y, t = threadIdx.x;
  const float* p0 = d0 + (size_t)b * D * N;
  const float* p1 = d1 + (size_t)b * D * N;
  for (int i = t; i < 8 * 128; i += 256) {
    int mm = i >> 7, d = i & 127;
    xm[mm][d] = p0[(size_t)d * N + m0 + mm];
  }
  __syncthreads();
  if (t < 8) {
    float s = 0;
    for (int d = 0; d < 128; ++d) s += xm[t][d] * xm[t][d];
    n0s[t] = s;
  }
  __syncthreads();
  float dot[8][4] = {{0}};
  float n1[4] = {0, 0, 0, 0};
  for (int d = 0; d < 128; ++d) {
    float v[4];
#pragma unroll
    for (int u = 0; u < 4; ++u) {
      v[u] = p1[(size_t)d * N + t + u * 256];
      n1[u] = fmaf(v[u], v[u], n1[u]);
    }
#pragma unroll
    for (int mm = 0; mm < 8; ++mm) {
      float x = xm[mm][d];
#pragma unroll
      for (int u = 0; u < 4; ++u) dot[mm][u] = fmaf(x, v[u], dot[mm][u]);
    }
  }
  for (int mm = 0; mm < 8; ++mm) {
    float* row = la + ((size_t)b * N + m0 + mm) * N;
#pragma unroll
    for (int u = 0; u < 4; ++u) {
      float dist2 = fmaxf(n0s[mm] + n1[u] - 2.f * dot[mm][u], 1e-30f);
      row[t + u * 256] = -sqrtf(dist2);
    }
  }
}

// ---------------------------------------------------------------- sinkhorn offset form
__global__ __launch_bounds__(256) void k_row_r(const float* __restrict__ l0,
                                               const float* __restrict__ cvec,
                                               float* __restrict__ r,
                                               int useC) {
  __shared__ float red[256];
  int t = threadIdx.x;
  int bm = blockIdx.x;              // over B*N
  int b = bm >> 10;
  const float* row = l0 + (size_t)bm * N;
  float v0 = row[t], v1 = row[t + 256], v2 = row[t + 512], v3 = row[t + 768];
  if (useC) {
    const float* cl = cvec + (size_t)b * N;
    v0 -= cl[t]; v1 -= cl[t + 256]; v2 -= cl[t + 512]; v3 -= cl[t + 768];
  }
  float mx = fmaxf(fmaxf(v0, v1), fmaxf(v2, v3));
  red[t] = mx; __syncthreads();
  for (int s = 128; s > 0; s >>= 1) {
    if (t < s) red[t] = fmaxf(red[t], red[t + s]);
    __syncthreads();
  }
  mx = red[0]; __syncthreads();
  float se = __expf(v0 - mx) + __expf(v1 - mx) + __expf(v2 - mx) + __expf(v3 - mx);
  red[t] = se; __syncthreads();
  for (int s = 128; s > 0; s >>= 1) {
    if (t < s) red[t] += red[t + s];
    __syncthreads();
  }
  if (t == 0) r[bm] = mx + __logf(red[0]);
}

__global__ __launch_bounds__(256) void k_col_part(const float* __restrict__ l0,
                                                  const float* __restrict__ r,
                                                  float* __restrict__ pmax,
                                                  float* __restrict__ psum) {
  int t = threadIdx.x;
  int n = blockIdx.x * 256 + t;
  int p = blockIdx.y, b = blockIdx.z;
  const float* base = l0 + ((size_t)b * N + p * 32) * N + n;
  const float* rr = r + (size_t)b * N + p * 32;
  float mx = -1e30f, s = 0;
  for (int m = 0; m < 32; ++m) {
    float v = base[(size_t)m * N] - rr[m];
    if (v > mx) { s = s * __expf(mx - v) + 1.f; mx = v; }
    else s += __expf(v - mx);
  }
  pmax[((size_t)b * 32 + p) * N + n] = mx;
  psum[((size_t)b * 32 + p) * N + n] = s;
}

__global__ __launch_bounds__(256) void k_col_fin(const float* __restrict__ pmax,
                                                 const float* __restrict__ psum,
                                                 float* __restrict__ cvec) {
  int i = blockIdx.x * 256 + threadIdx.x;  // over B*N
  int b = i / N, n = i % N;
  float mx = -1e30f;
#pragma unroll
  for (int p = 0; p < 32; ++p) mx = fmaxf(mx, pmax[((size_t)b * 32 + p) * N + n]);
  float s = 0;
#pragma unroll
  for (int p = 0; p < 32; ++p)
    s += psum[((size_t)b * 32 + p) * N + n] * __expf(pmax[((size_t)b * 32 + p) * N + n] - mx);
  cvec[i] = mx + __logf(s);
}

// ---------------------------------------------------------------- rodrigues + transform
__global__ __launch_bounds__(256) void k_rod(const float* __restrict__ pose,
                                             const float* __restrict__ p3d,
                                             float* __restrict__ p3dt) {
  int b = blockIdx.y;
  int n = blockIdx.x * 256 + threadIdx.x;
  const float* aa = pose + b * 6;
  float ax = aa[0], ay = aa[1], az = aa[2];
  float th = fmaxf(sqrtf(ax * ax + ay * ay + az * az), 1e-8f);
  float rx = ax / th, ry = ay / th, rz = az / th;
  float c = cosf(th), s = sinf(th), oc = 1.f - c;
  float R00 = c + oc * rx * rx,      R01 = oc * rx * ry - s * rz, R02 = oc * rx * rz + s * ry;
  float R10 = oc * ry * rx + s * rz, R11 = c + oc * ry * ry,      R12 = oc * ry * rz - s * rx;
  float R20 = oc * rz * rx - s * ry, R21 = oc * rz * ry + s * rx, R22 = c + oc * rz * rz;
  const float* p = p3d + ((size_t)b * N + n) * 3;
  float x = p[0], y = p[1], z = p[2];
  float X = R00 * x + R01 * y + R02 * z + aa[3];
  float Y = R10 * x + R11 * y + R12 * z + aa[4];
  float Z = R20 * x + R21 * y + R22 * z + aa[5];
  float inr = 1.f / sqrtf(X * X + Y * Y + Z * Z);
  float* o = p3dt + ((size_t)b * N + n) * 3;
  o[0] = X * inr; o[1] = Y * inr; o[2] = Z * inr;
}

// ---------------------------------------------------------------- final error (applies r,c offsets)
__global__ __launch_bounds__(256) void k_err(const float* __restrict__ l0,
                                             const float* __restrict__ r,
                                             const float* __restrict__ cvec,
                                             const float* __restrict__ f2,
                                             const float* __restrict__ p3dt,
                                             float* __restrict__ rowsum) {
  __shared__ float red[256];
  int m = blockIdx.x, b = blockIdx.y, t = threadIdx.x;
  const float* row = l0 + ((size_t)b * N + m) * N;
  const float* cl = cvec + (size_t)b * N;
  const float rm = r[(size_t)b * N + m];
  const float* f = f2 + ((size_t)b * N + m) * 3;
  float fx = f[0], fy = f[1], fz = f[2];
  float s = 0;
  for (int n = t; n < N; n += 256) {
    const float* pp = p3dt + ((size_t)b * N + n) * 3;
    float dot = fx * pp[0] + fy * pp[1] + fz * pp[2];
    s += __expf(row[n] - rm - cl[n]) * (1.f - dot);
  }
  red[t] = s; __syncthreads();
  for (int sft = 128; sft > 0; sft >>= 1) {
    if (t < sft) red[t] += red[t + sft];
    __syncthreads();
  }
  if (t == 0) rowsum[(size_t)b * N + m] = red[0];
}

__global__ __launch_bounds__(256) void k_err_fin(const float* __restrict__ rowsum,
                                                 float* __restrict__ out) {
  __shared__ float red[256];
  int b = blockIdx.x, t = threadIdx.x;
  float s = 0;
  for (int i = t; i < N; i += 256) s += rowsum[(size_t)b * N + i];
  red[t] = s; __syncthreads();
  for (int sft = 128; sft > 0; sft >>= 1) {
    if (t < sft) red[t] += red[t + sft];
    __syncthreads();
  }
  if (t == 0) out[b] = red[0];
}

// ================================================================= host
extern "C" void kernel_launch(void* const* d_in, const int* in_sizes, int n_in,
                              void* d_out, int out_size, void* d_ws, size_t ws_size,
                              hipStream_t stream) {
  const float* p2d     = (const float*)d_in[0];
  const float* p3d     = (const float*)d_in[1];
  const float* pose    = (const float*)d_in[2];
  const float* enc2d_w = (const float*)d_in[3];
  const float* enc2d_b = (const float*)d_in[4];
  const float* enc3d_w = (const float*)d_in[5];
  const float* enc3d_b = (const float*)d_in[6];
  const float* proj_w  = (const float*)d_in[7];
  const float* proj_b  = (const float*)d_in[8];
  const float* merge_w = (const float*)d_in[9];
  const float* merge_b = (const float*)d_in[10];
  const float* mlp1_w  = (const float*)d_in[11];
  const float* mlp1_b  = (const float*)d_in[12];
  const float* bn_g    = (const float*)d_in[13];
  const float* bn_b    = (const float*)d_in[14];
  const float* mlp2_w  = (const float*)d_in[15];
  const float* mlp2_b  = (const float*)d_in[16];

  float* W = (float*)d_ws;
  size_t off = 0;
  auto alloc = [&](size_t nelem) { float* p = W + off; off += nelem; return p; };
  const size_t SET = (size_t)B * D * N;
  float* f2    = alloc((size_t)B * N * 3);
  float* p3dt  = alloc((size_t)B * N * 3);
  float* descA = alloc(2 * SET);
  float* descB = alloc(2 * SET);
  float* qkv   = alloc(3 * 2 * SET);
  float* attnb = alloc(2 * SET);
  float* msgb  = alloc(2 * SET);
  float* hb    = alloc((size_t)2 * B * 256 * N);
  float* stat  = alloc(2 * 256 * 2);
  float* la    = alloc((size_t)B * N * N);
  float* pmax  = alloc((size_t)B * 32 * N);
  float* psum  = alloc((size_t)B * 32 * N);
  float* cvec  = alloc((size_t)B * N);
  float* rvec  = alloc((size_t)B * N);
  float* rowsum= alloc((size_t)B * N);
  (void)ws_size; (void)in_sizes; (void)n_in; (void)out_size;

  float* Qb = qkv;
  float* Kb = qkv + 2 * SET;
  float* Vb = qkv + 4 * SET;
  const size_t DS = (size_t)D * N;

  k_norm2d<<<(B * N) / 256, 256, 0, stream>>>(p2d, f2);
  k_encode<<<dim3(N, B), 256, 0, stream>>>(f2, enc2d_w, enc2d_b, descA);
  k_encode<<<dim3(N, B), 256, 0, stream>>>(p3d, enc3d_w, enc3d_b, descA + SET);

  float* dc = descA;
  float* dn = descB;
  for (int i = 0; i < 6; ++i) {
    int cross = (i & 1);
    const float* pw = proj_w + (size_t)i * 3 * D * D;
    const float* pb = proj_b + (size_t)i * 3 * D;
    float* d0 = dc;
    float* d1 = dc + SET;
    const float* sA = cross ? d1 : d0;
    const float* sB = cross ? d0 : d1;

    k_gemm<<<dim3(64, 6), 256, 0, stream>>>(
        d0, d1, sA, sB, pw, pb, nullptr, qkv, nullptr, nullptr, nullptr,
        D, D, DS, DS, D, 2 * SET, 1);
    k_attn<<<dim3(N / 256, NH, 2 * B), 256, 0, stream>>>(Qb, Kb, Vb, attnb);
    k_gemm<<<dim3(64, 2), 256, 0, stream>>>(
        attnb, attnb + SET, nullptr, nullptr, merge_w + (size_t)i * D * D,
        merge_b + (size_t)i * D, nullptr, msgb, nullptr, nullptr, nullptr,
        D, D, DS, DS, D, 0, 0);
    k_gemm<<<dim3(64, 4), 256, 0, stream>>>(
        dc, dc + SET, msgb, msgb + SET, mlp1_w + (size_t)i * 256 * 256,
        mlp1_b + (size_t)i * 256, nullptr, hb, nullptr, nullptr, nullptr,
        256, 128, DS, DS, 256, 0, 0);
    k_bnstat<<<dim3(256, 2), 256, 0, stream>>>(hb, stat);
    k_gemm<<<dim3(64, 2), 256, 0, stream>>>(
        hb, hb + (size_t)B * 256 * N, nullptr, nullptr,
        mlp2_w + (size_t)i * D * 256, mlp2_b + (size_t)i * D, dc, dn,
        stat, bn_g + (size_t)i * 256, bn_b + (size_t)i * 256,
        256, 256, (size_t)256 * N, 0, D, 0, 0);
    float* tmp = dc; dc = dn; dn = tmp;
  }

  k_dist<<<dim3(N / 8, B), 256, 0, stream>>>(dc, dc + SET, la);
  for (int it = 0; it < 10; ++it) {
    k_row_r<<<B * N, 256, 0, stream>>>(la, cvec, rvec, it > 0 ? 1 : 0);
    k_col_part<<<dim3(N / 256, 32, B), 256, 0, stream>>>(la, rvec, pmax, psum);
    k_col_fin<<<(B * N) / 256, 256, 0, stream>>>(pmax, psum, cvec);
  }
  k_rod<<<dim3(N / 256, B), 256, 0, stream>>>(pose, p3d, p3dt);
  k_err<<<dim3(N, B), 256, 0, stream>>>(la, rvec, cvec, f2, p3dt, rowsum);
  k_err_fin<<<B, 256, 0, stream>>>(rowsum, (float*)d_out);
}

// Round 13
// 1274.740 us; speedup vs baseline: 1.4983x; 1.4983x over previous
//
#include <hip/hip_runtime.h>
#include <hip/hip_bf16.h>

constexpr int B   = 4;
constexpr int N   = 1024;
constexpr int D   = 128;
constexpr int KNN = 10;
constexpr int NH  = 4;

typedef _Float16 half2v __attribute__((ext_vector_type(2)));

static __device__ __forceinline__ half2v pkrtz(float a, float b) {
  return __builtin_bit_cast(half2v, __builtin_amdgcn_cvt_pkrtz(a, b));
}
static __device__ __forceinline__ float h2f(half2v h) {
  return __builtin_bit_cast(float, h);
}

// ---------------------------------------------------------------- norm p2d
__global__ __launch_bounds__(256) void k_norm2d(const float* __restrict__ p2d,
                                                float* __restrict__ f2) {
  int i = blockIdx.x * 256 + threadIdx.x;  // over B*N
  const float* p = p2d + (size_t)i * 3;
  float x = p[0], y = p[1], z = p[2];
  float inr = 1.f / sqrtf(x * x + y * y + z * z);
  float* o = f2 + (size_t)i * 3;
  o[0] = x * inr; o[1] = y * inr; o[2] = z * inr;
}

// ---------------------------------------------------------------- KNN encode
__global__ __launch_bounds__(256) void k_encode(const float* __restrict__ pts,
                                                const float* __restrict__ w,
                                                const float* __restrict__ bias,
                                                float* __restrict__ desc) {
  __shared__ float P[N][3];
  __shared__ float xx[N];
  __shared__ float dist[N];
  __shared__ float rv[256];
  __shared__ int   ri[256];
  __shared__ float feat[6];
  __shared__ int   nidx[KNN];
  int t = threadIdx.x;
  int n = blockIdx.x, b = blockIdx.y;
  const float* pb = pts + (size_t)b * N * 3;
  for (int i = t; i < N; i += 256) {
    float x = pb[i * 3 + 0], y = pb[i * 3 + 1], z = pb[i * 3 + 2];
    P[i][0] = x; P[i][1] = y; P[i][2] = z;
    xx[i] = x * x + y * y + z * z;
  }
  __syncthreads();
  float cx = P[n][0], cy = P[n][1], cz = P[n][2], cxx = xx[n];
  for (int i = t; i < N; i += 256) {
    float ip = cx * P[i][0] + cy * P[i][1] + cz * P[i][2];
    dist[i] = 2.f * ip - cxx - xx[i];
  }
  __syncthreads();
  for (int kk = 0; kk < KNN; ++kk) {
    float bv = -3.0e38f; int bi = N;
    for (int i = t; i < N; i += 256) {
      float v = dist[i];
      if (v > bv) { bv = v; bi = i; }
    }
    rv[t] = bv; ri[t] = bi;
    __syncthreads();
    for (int s = 128; s > 0; s >>= 1) {
      if (t < s) {
        float v2 = rv[t + s]; int i2 = ri[t + s];
        if (v2 > rv[t] || (v2 == rv[t] && i2 < ri[t])) { rv[t] = v2; ri[t] = i2; }
      }
      __syncthreads();
    }
    if (t == 0) { nidx[kk] = ri[0]; dist[ri[0]] = -3.0e38f; }
    __syncthreads();
  }
  if (t == 0) {
    float sx = 0, sy = 0, sz = 0;
    for (int kk = 0; kk < KNN; ++kk) {
      int i = nidx[kk];
      sx += P[i][0]; sy += P[i][1]; sz += P[i][2];
    }
    const float invk = 1.f / KNN;
    feat[0] = sx * invk - cx; feat[1] = sy * invk - cy; feat[2] = sz * invk - cz;
    feat[3] = cx; feat[4] = cy; feat[5] = cz;
  }
  __syncthreads();
  if (t < D) {
    const float* wr = w + t * 6;
    float a = bias[t];
#pragma unroll
    for (int j = 0; j < 6; ++j) a += wr[j] * feat[j];
    desc[((size_t)b * D + t) * N + n] = a;
  }
}

// ---------------------------------------------------------------- tiled GEMM conv v2: f16 + v_dot2
// W and X tiles staged as f16 c-pairs; inner loop 32 v_dot2 (64 MAC) per
// c-pair vs 64 FMA+12 LDS in fp32 version -> VALU issues and LDS instr halve.
// Accumulation stays f32 (fdot2 f32-accum). BM=64 o, BN=128 n', BK=32.
__global__ __launch_bounds__(256) void k_gemm(
    const float* __restrict__ pA0, const float* __restrict__ pA1,
    const float* __restrict__ pB0, const float* __restrict__ pB1,
    const float* __restrict__ w, const float* __restrict__ bias,
    const float* __restrict__ res, float* __restrict__ out,
    const float* __restrict__ stat, const float* __restrict__ g,
    const float* __restrict__ bt,
    int Cin, int catOff, size_t a_bstr, size_t b_bstr,
    int segCout, size_t segStride, int qkvMode) {
  __shared__ half2v As2[64][20];   // [o][cpair], pad 20
  __shared__ half2v Bs2[16][128];  // [cpair][n]
  __shared__ float Ac[256], Bc[256];
  const int tid = threadIdx.x;
  const int to = tid >> 4;
  const int tn = tid & 15;
  const int o0 = blockIdx.y * 64;
  const int zb = blockIdx.x;
  const int z  = zb >> 3;
  const int n0 = (zb & 7) * 128;
  const int s = z >> 2, b = z & 3;
  const int seg = o0 / segCout;
  const int oo  = o0 % segCout;

  const float* XA = (s ? pA1 : pA0) + (size_t)b * a_bstr;
  const float* XB = pB0 ? ((s ? pB1 : pB0) + (size_t)b * b_bstr) : nullptr;
  const bool segB = qkvMode && (seg > 0);

  if (stat) {
    const float* st = stat + (size_t)s * 256 * 2;
    float A = st[tid * 2 + 1] * g[tid];
    Ac[tid] = A;
    Bc[tid] = fmaf(-st[tid * 2 + 0], A, bt[tid]);
  }

  float acc[4][8];
#pragma unroll
  for (int i = 0; i < 4; ++i)
#pragma unroll
    for (int j = 0; j < 8; ++j) acc[i][j] = 0.f;

  for (int kb = 0; kb < Cin; kb += 32) {
    __syncthreads();
    // stage W tile -> f16 pairs along c (contiguous in w's row-major layout)
#pragma unroll
    for (int j = 0; j < 2; ++j) {
      int idx = j * 256 + tid;
      int o = idx >> 3, c4 = (idx & 7) * 4;
      float4 wv = *(const float4*)&w[(size_t)(o0 + o) * Cin + kb + c4];
      As2[o][(c4 >> 1) + 0] = pkrtz(wv.x, wv.y);
      As2[o][(c4 >> 1) + 1] = pkrtz(wv.z, wv.w);
    }
    // stage X tile: rows c0=kb+2rp, c1=c0+1 packed as half2 per n
#pragma unroll
    for (int j = 0; j < 2; ++j) {
      int idx = j * 256 + tid;
      int rp = idx >> 5, c4 = (idx & 31) * 4;
      int c0 = kb + 2 * rp, c1 = c0 + 1;
      const float* s0; int cc0 = c0;
      const float* s1; int cc1 = c1;
      if (qkvMode) {
        s0 = segB ? XB : XA; s1 = s0;
      } else {
        if (c0 >= catOff) { s0 = XB; cc0 = c0 - catOff; } else s0 = XA;
        if (c1 >= catOff) { s1 = XB; cc1 = c1 - catOff; } else s1 = XA;
      }
      float4 v0 = *(const float4*)&s0[(size_t)cc0 * N + n0 + c4];
      float4 v1 = *(const float4*)&s1[(size_t)cc1 * N + n0 + c4];
      if (stat) {
        float A0 = Ac[c0], B0 = Bc[c0], A1 = Ac[c1], B1 = Bc[c1];
        v0.x = fmaxf(fmaf(v0.x, A0, B0), 0.f);
        v0.y = fmaxf(fmaf(v0.y, A0, B0), 0.f);
        v0.z = fmaxf(fmaf(v0.z, A0, B0), 0.f);
        v0.w = fmaxf(fmaf(v0.w, A0, B0), 0.f);
        v1.x = fmaxf(fmaf(v1.x, A1, B1), 0.f);
        v1.y = fmaxf(fmaf(v1.y, A1, B1), 0.f);
        v1.z = fmaxf(fmaf(v1.z, A1, B1), 0.f);
        v1.w = fmaxf(fmaf(v1.w, A1, B1), 0.f);
      }
      float4 packed;
      packed.x = h2f(pkrtz(v0.x, v1.x));
      packed.y = h2f(pkrtz(v0.y, v1.y));
      packed.z = h2f(pkrtz(v0.z, v1.z));
      packed.w = h2f(pkrtz(v0.w, v1.w));
      *(float4*)&Bs2[rp][c4] = packed;
    }
    __syncthreads();
#pragma unroll
    for (int kk = 0; kk < 16; ++kk) {
      half2v a0 = As2[to * 4 + 0][kk];
      half2v a1 = As2[to * 4 + 1][kk];
      half2v a2 = As2[to * 4 + 2][kk];
      half2v a3 = As2[to * 4 + 3][kk];
      float4 br0 = *(const float4*)&Bs2[kk][tn * 8];
      float4 br1 = *(const float4*)&Bs2[kk][tn * 8 + 4];
      half2v bv[8];
      bv[0] = __builtin_bit_cast(half2v, br0.x);
      bv[1] = __builtin_bit_cast(half2v, br0.y);
      bv[2] = __builtin_bit_cast(half2v, br0.z);
      bv[3] = __builtin_bit_cast(half2v, br0.w);
      bv[4] = __builtin_bit_cast(half2v, br1.x);
      bv[5] = __builtin_bit_cast(half2v, br1.y);
      bv[6] = __builtin_bit_cast(half2v, br1.z);
      bv[7] = __builtin_bit_cast(half2v, br1.w);
#pragma unroll
      for (int j = 0; j < 8; ++j) {
        acc[0][j] = __builtin_amdgcn_fdot2(a0, bv[j], acc[0][j], false);
        acc[1][j] = __builtin_amdgcn_fdot2(a1, bv[j], acc[1][j], false);
        acc[2][j] = __builtin_amdgcn_fdot2(a2, bv[j], acc[2][j], false);
        acc[3][j] = __builtin_amdgcn_fdot2(a3, bv[j], acc[3][j], false);
      }
    }
  }
#pragma unroll
  for (int i = 0; i < 4; ++i) {
    int og = o0 + to * 4 + i;
    int o  = oo + to * 4 + i;
    float bi = bias[og];
    size_t ob = (size_t)seg * segStride + ((size_t)z * segCout + o) * N + n0 + tn * 8;
    float4 r0, r1;
    r0.x = acc[i][0] + bi; r0.y = acc[i][1] + bi;
    r0.z = acc[i][2] + bi; r0.w = acc[i][3] + bi;
    r1.x = acc[i][4] + bi; r1.y = acc[i][5] + bi;
    r1.z = acc[i][6] + bi; r1.w = acc[i][7] + bi;
    if (res) {
      float4 e0 = *(const float4*)&res[ob];
      float4 e1 = *(const float4*)&res[ob + 4];
      r0.x += e0.x; r0.y += e0.y; r0.z += e0.z; r0.w += e0.w;
      r1.x += e1.x; r1.y += e1.y; r1.z += e1.z; r1.w += e1.w;
    }
    *(float4*)&out[ob] = r0;
    *(float4*)&out[ob + 4] = r1;
  }
}

// ---------------------------------------------------------------- attention v7 (REVERT: 74us verified)
// grid (N/128, NH, 2*B) = 256 blocks, 4 waves, QPL=2, f16 K/V + v_dot2.
// R12 lesson: QPL=4 shrank grid to 128 blocks (half the CUs idle) + 1 wave/SIMD
// -> 168us. v7's balance (256 blocks, ~2 blocks/CU, VGPR 160) is the optimum.
__global__ __launch_bounds__(256) void k_attn(const float* __restrict__ Q,
                                              const float* __restrict__ Kt,
                                              const float* __restrict__ Vt,
                                              float* __restrict__ O) {
  __shared__ float pool[16896];          // staging (f16, 16KB); merge f32
  __shared__ float ms_[4][128], ls_[4][128];
  half2v* pool2 = (half2v*)pool;
  const int t  = threadIdx.x;
  const int lq = t & 63, s = t >> 6;
  const int q0 = blockIdx.x * 128;
  const int h  = blockIdx.y;
  const int z  = blockIdx.z;
  const size_t base = (size_t)z * (size_t)(D * N);
  const float* Kb = Kt + base;
  const float* Vb = Vt + base;
  const int sb2 = s * 1024;             // per-wave region: K [0,512), V [512,1024)
  const int kg  = lq & 7;               // staging key-group (4 keys)
  const int dp  = lq >> 3;              // 0..7

  const float scale = 0.17677669529663687f;  // 1/sqrt(32), folded into q
  half2v qpA[16], qpB[16];
  float accA[32], accB[32];
#pragma unroll
  for (int dd = 0; dd < 16; ++dd) {
    float a0 = Q[base + (size_t)((2 * dd) * 4 + h) * N + q0 + lq] * scale;
    float a1 = Q[base + (size_t)((2 * dd + 1) * 4 + h) * N + q0 + lq] * scale;
    qpA[dd] = pkrtz(a0, a1);
    float b0 = Q[base + (size_t)((2 * dd) * 4 + h) * N + q0 + 64 + lq] * scale;
    float b1 = Q[base + (size_t)((2 * dd + 1) * 4 + h) * N + q0 + 64 + lq] * scale;
    qpB[dd] = pkrtz(b0, b1);
  }
#pragma unroll
  for (int d = 0; d < 32; ++d) { accA[d] = 0.f; accB[d] = 0.f; }
  float mxA = -1e30f, mxB = -1e30f, lA = 0.f, lB = 0.f;

  for (int c = 0; c < 8; ++c) {
    const int k0 = s * 256 + c * 32;
    // ---- stage K: Kh[j][dd] = (K[2dd][j], K[2dd+1][j]) f16
#pragma unroll
    for (int rep = 0; rep < 2; ++rep) {
      int dd = dp + rep * 8;
      const float4 va = *(const float4*)(Kb + (size_t)((2 * dd) * 4 + h) * N + k0 + kg * 4);
      const float4 vb = *(const float4*)(Kb + (size_t)((2 * dd + 1) * 4 + h) * N + k0 + kg * 4);
      pool2[sb2 + (kg * 4 + 0) * 16 + dd] = pkrtz(va.x, vb.x);
      pool2[sb2 + (kg * 4 + 1) * 16 + dd] = pkrtz(va.y, vb.y);
      pool2[sb2 + (kg * 4 + 2) * 16 + dd] = pkrtz(va.z, vb.z);
      pool2[sb2 + (kg * 4 + 3) * 16 + dd] = pkrtz(va.w, vb.w);
    }
    // ---- stage V: Vp[d][jp] = (V[2jp][d], V[2jp+1][d]) f16
#pragma unroll
    for (int rep = 0; rep < 4; ++rep) {
      int d = dp + rep * 8;
      const float4 vv = *(const float4*)(Vb + (size_t)(d * 4 + h) * N + k0 + kg * 4);
      int idx = sb2 + 512 + d * 16 + kg * 2;
      pool2[idx]     = pkrtz(vv.x, vv.y);
      pool2[idx + 1] = pkrtz(vv.z, vv.w);
    }
    // ---- 4 steps of 8 keys
#pragma unroll
    for (int st = 0; st < 4; ++st) {
      float scA[8], scB[8];
#pragma unroll
      for (int jj = 0; jj < 8; ++jj) {
        const int rb = sb2 + (st * 8 + jj) * 16;
        float a = 0.f, bq = 0.f;
#pragma unroll
        for (int r = 0; r < 4; ++r) {
          float4 raw = *(const float4*)&pool2[rb + r * 4];
          half2v k0h = __builtin_bit_cast(half2v, raw.x);
          half2v k1h = __builtin_bit_cast(half2v, raw.y);
          half2v k2h = __builtin_bit_cast(half2v, raw.z);
          half2v k3h = __builtin_bit_cast(half2v, raw.w);
          a  = __builtin_amdgcn_fdot2(k0h, qpA[r * 4 + 0], a,  false);
          a  = __builtin_amdgcn_fdot2(k1h, qpA[r * 4 + 1], a,  false);
          a  = __builtin_amdgcn_fdot2(k2h, qpA[r * 4 + 2], a,  false);
          a  = __builtin_amdgcn_fdot2(k3h, qpA[r * 4 + 3], a,  false);
          bq = __builtin_amdgcn_fdot2(k0h, qpB[r * 4 + 0], bq, false);
          bq = __builtin_amdgcn_fdot2(k1h, qpB[r * 4 + 1], bq, false);
          bq = __builtin_amdgcn_fdot2(k2h, qpB[r * 4 + 2], bq, false);
          bq = __builtin_amdgcn_fdot2(k3h, qpB[r * 4 + 3], bq, false);
        }
        scA[jj] = a; scB[jj] = bq;
      }
      // online softmax over these 8 keys (f32)
      float hA = scA[0], hB = scB[0];
#pragma unroll
      for (int j = 1; j < 8; ++j) { hA = fmaxf(hA, scA[j]); hB = fmaxf(hB, scB[j]); }
      float nmA = fmaxf(mxA, hA), nmB = fmaxf(mxB, hB);
      float cA = __expf(mxA - nmA), cB = __expf(mxB - nmB);
      lA *= cA; lB *= cB;
#pragma unroll
      for (int d = 0; d < 32; ++d) { accA[d] *= cA; accB[d] *= cB; }
      mxA = nmA; mxB = nmB;
#pragma unroll
      for (int j = 0; j < 8; ++j) {
        scA[j] = __expf(scA[j] - mxA); lA += scA[j];
        scB[j] = __expf(scB[j] - mxB); lB += scB[j];
      }
      // pack P to f16 (pair order matches Vp key-pairing)
      half2v pA2[4], pB2[4];
#pragma unroll
      for (int u = 0; u < 4; ++u) {
        pA2[u] = pkrtz(scA[2 * u], scA[2 * u + 1]);
        pB2[u] = pkrtz(scB[2 * u], scB[2 * u + 1]);
      }
      // PV: one b128 read = 8 keys at dim d
#pragma unroll
      for (int d = 0; d < 32; ++d) {
        float4 raw = *(const float4*)&pool2[sb2 + 512 + d * 16 + st * 4];
        half2v v0 = __builtin_bit_cast(half2v, raw.x);
        half2v v1 = __builtin_bit_cast(half2v, raw.y);
        half2v v2 = __builtin_bit_cast(half2v, raw.z);
        half2v v3 = __builtin_bit_cast(half2v, raw.w);
        float aa = accA[d];
        aa = __builtin_amdgcn_fdot2(v0, pA2[0], aa, false);
        aa = __builtin_amdgcn_fdot2(v1, pA2[1], aa, false);
        aa = __builtin_amdgcn_fdot2(v2, pA2[2], aa, false);
        aa = __builtin_amdgcn_fdot2(v3, pA2[3], aa, false);
        accA[d] = aa;
        float bb = accB[d];
        bb = __builtin_amdgcn_fdot2(v0, pB2[0], bb, false);
        bb = __builtin_amdgcn_fdot2(v1, pB2[1], bb, false);
        bb = __builtin_amdgcn_fdot2(v2, pB2[2], bb, false);
        bb = __builtin_amdgcn_fdot2(v3, pB2[3], bb, false);
        accB[d] = bb;
      }
    }
  }

  // ---- merge 4 key-split partials (f32)
  ms_[s][lq] = mxA; ms_[s][64 + lq] = mxB;
  ls_[s][lq] = lA;  ls_[s][64 + lq] = lB;
  __syncthreads();
#pragma unroll
  for (int d = 0; d < 32; ++d) {
    pool[(s * 128 + lq) * 33 + d] = accA[d];
    pool[(s * 128 + 64 + lq) * 33 + d] = accB[d];
  }
  __syncthreads();
  {
    int qq = t & 127, dh = t >> 7;
    float M = fmaxf(fmaxf(ms_[0][qq], ms_[1][qq]), fmaxf(ms_[2][qq], ms_[3][qq]));
    float wg[4], L = 0.f;
#pragma unroll
    for (int ss = 0; ss < 4; ++ss) {
      wg[ss] = __expf(ms_[ss][qq] - M);
      L += ls_[ss][qq] * wg[ss];
    }
    float invL = 1.f / L;
#pragma unroll
    for (int k = 0; k < 16; ++k) {
      int d = dh * 16 + k;
      float o = 0.f;
#pragma unroll
      for (int ss = 0; ss < 4; ++ss) o += pool[(ss * 128 + qq) * 33 + d] * wg[ss];
      O[base + (size_t)(d * 4 + h) * N + q0 + qq] = o * invL;
    }
  }
}

// ---------------------------------------------------------------- BN stats (single pass)
__global__ __launch_bounds__(256) void k_bnstat(const float* __restrict__ h,
                                                float* __restrict__ stat) {
  int c = blockIdx.x, s = blockIdx.y, t = threadIdx.x;
  __shared__ float red[256], red2[256];
  const float* base = h + ((size_t)s * B * 256 + c) * N;
  float sum = 0, sq = 0;
  for (int b = 0; b < B; ++b)
    for (int i = t; i < N; i += 256) {
      float v = base[(size_t)b * 256 * N + i];
      sum += v; sq = fmaf(v, v, sq);
    }
  red[t] = sum; red2[t] = sq; __syncthreads();
  for (int sft = 128; sft > 0; sft >>= 1) {
    if (t < sft) { red[t] += red[t + sft]; red2[t] += red2[t + sft]; }
    __syncthreads();
  }
  if (t == 0) {
    float mean = red[0] / (float)(B * N);
    float var = fmaxf(red2[0] / (float)(B * N) - mean * mean, 0.f);
    stat[(s * 256 + c) * 2 + 0] = mean;
    stat[(s * 256 + c) * 2 + 1] = 1.f / sqrtf(var + 1e-5f);
  }
}

// ---------------------------------------------------------------- pairwise dist (8-m tile)
__global__ __launch_bounds__(256) void k_dist(const float* __restrict__ d0,
                                              const float* __restrict__ d1,
                                              float* __restrict__ la) {
  __shared__ float xm[8][128];
  __shared__ float n0s[8];
  int m0 = blockIdx.x * 8, b = blockIdx.y, t = threadIdx.x;
  const float* p0 = d0 + (size_t)b * D * N;
  const float* p1 = d1 + (size_t)b * D * N;
  for (int i = t; i < 8 * 128; i += 256) {
    int mm = i >> 7, d = i & 127;
    xm[mm][d] = p0[(size_t)d * N + m0 + mm];
  }
  __syncthreads();
  if (t < 8) {
    float s = 0;
    for (int d = 0; d < 128; ++d) s += xm[t][d] * xm[t][d];
    n0s[t] = s;
  }
  __syncthreads();
  float dot[8][4] = {{0}};
  float n1[4] = {0, 0, 0, 0};
  for (int d = 0; d < 128; ++d) {
    float v[4];
#pragma unroll
    for (int u = 0; u < 4; ++u) {
      v[u] = p1[(size_t)d * N + t + u * 256];
      n1[u] = fmaf(v[u], v[u], n1[u]);
    }
#pragma unroll
    for (int mm = 0; mm < 8; ++mm) {
      float x = xm[mm][d];
#pragma unroll
      for (int u = 0; u < 4; ++u) dot[mm][u] = fmaf(x, v[u], dot[mm][u]);
    }
  }
  for (int mm = 0; mm < 8; ++mm) {
    float* row = la + ((size_t)b * N + m0 + mm) * N;
#pragma unroll
    for (int u = 0; u < 4; ++u) {
      float dist2 = fmaxf(n0s[mm] + n1[u] - 2.f * dot[mm][u], 1e-30f);
      row[t + u * 256] = -sqrtf(dist2);
    }
  }
}

// ---------------------------------------------------------------- sinkhorn offset form
__global__ __launch_bounds__(256) void k_row_r(const float* __restrict__ l0,
                                               const float* __restrict__ cvec,
                                               float* __restrict__ r,
                                               int useC) {
  __shared__ float red[256];
  int t = threadIdx.x;
  int bm = blockIdx.x;              // over B*N
  int b = bm >> 10;
  const float* row = l0 + (size_t)bm * N;
  float v0 = row[t], v1 = row[t + 256], v2 = row[t + 512], v3 = row[t + 768];
  if (useC) {
    const float* cl = cvec + (size_t)b * N;
    v0 -= cl[t]; v1 -= cl[t + 256]; v2 -= cl[t + 512]; v3 -= cl[t + 768];
  }
  float mx = fmaxf(fmaxf(v0, v1), fmaxf(v2, v3));
  red[t] = mx; __syncthreads();
  for (int s = 128; s > 0; s >>= 1) {
    if (t < s) red[t] = fmaxf(red[t], red[t + s]);
    __syncthreads();
  }
  mx = red[0]; __syncthreads();
  float se = __expf(v0 - mx) + __expf(v1 - mx) + __expf(v2 - mx) + __expf(v3 - mx);
  red[t] = se; __syncthreads();
  for (int s = 128; s > 0; s >>= 1) {
    if (t < s) red[t] += red[t + s];
    __syncthreads();
  }
  if (t == 0) r[bm] = mx + __logf(red[0]);
}

__global__ __launch_bounds__(256) void k_col_part(const float* __restrict__ l0,
                                                  const float* __restrict__ r,
                                                  float* __restrict__ pmax,
                                                  float* __restrict__ psum) {
  int t = threadIdx.x;
  int n = blockIdx.x * 256 + t;
  int p = blockIdx.y, b = blockIdx.z;
  const float* base = l0 + ((size_t)b * N + p * 32) * N + n;
  const float* rr = r + (size_t)b * N + p * 32;
  float mx = -1e30f, s = 0;
  for (int m = 0; m < 32; ++m) {
    float v = base[(size_t)m * N] - rr[m];
    if (v > mx) { s = s * __expf(mx - v) + 1.f; mx = v; }
    else s += __expf(v - mx);
  }
  pmax[((size_t)b * 32 + p) * N + n] = mx;
  psum[((size_t)b * 32 + p) * N + n] = s;
}

__global__ __launch_bounds__(256) void k_col_fin(const float* __restrict__ pmax,
                                                 const float* __restrict__ psum,
                                                 float* __restrict__ cvec) {
  int i = blockIdx.x * 256 + threadIdx.x;  // over B*N
  int b = i / N, n = i % N;
  float mx = -1e30f;
#pragma unroll
  for (int p = 0; p < 32; ++p) mx = fmaxf(mx, pmax[((size_t)b * 32 + p) * N + n]);
  float s = 0;
#pragma unroll
  for (int p = 0; p < 32; ++p)
    s += psum[((size_t)b * 32 + p) * N + n] * __expf(pmax[((size_t)b * 32 + p) * N + n] - mx);
  cvec[i] = mx + __logf(s);
}

// ---------------------------------------------------------------- rodrigues + transform
__global__ __launch_bounds__(256) void k_rod(const float* __restrict__ pose,
                                             const float* __restrict__ p3d,
                                             float* __restrict__ p3dt) {
  int b = blockIdx.y;
  int n = blockIdx.x * 256 + threadIdx.x;
  const float* aa = pose + b * 6;
  float ax = aa[0], ay = aa[1], az = aa[2];
  float th = fmaxf(sqrtf(ax * ax + ay * ay + az * az), 1e-8f);
  float rx = ax / th, ry = ay / th, rz = az / th;
  float c = cosf(th), s = sinf(th), oc = 1.f - c;
  float R00 = c + oc * rx * rx,      R01 = oc * rx * ry - s * rz, R02 = oc * rx * rz + s * ry;
  float R10 = oc * ry * rx + s * rz, R11 = c + oc * ry * ry,      R12 = oc * ry * rz - s * rx;
  float R20 = oc * rz * rx - s * ry, R21 = oc * rz * ry + s * rx, R22 = c + oc * rz * rz;
  const float* p = p3d + ((size_t)b * N + n) * 3;
  float x = p[0], y = p[1], z = p[2];
  float X = R00 * x + R01 * y + R02 * z + aa[3];
  float Y = R10 * x + R11 * y + R12 * z + aa[4];
  float Z = R20 * x + R21 * y + R22 * z + aa[5];
  float inr = 1.f / sqrtf(X * X + Y * Y + Z * Z);
  float* o = p3dt + ((size_t)b * N + n) * 3;
  o[0] = X * inr; o[1] = Y * inr; o[2] = Z * inr;
}

// ---------------------------------------------------------------- final error (applies r,c offsets)
__global__ __launch_bounds__(256) void k_err(const float* __restrict__ l0,
                                             const float* __restrict__ r,
                                             const float* __restrict__ cvec,
                                             const float* __restrict__ f2,
                                             const float* __restrict__ p3dt,
                                             float* __restrict__ rowsum) {
  __shared__ float red[256];
  int m = blockIdx.x, b = blockIdx.y, t = threadIdx.x;
  const float* row = l0 + ((size_t)b * N + m) * N;
  const float* cl = cvec + (size_t)b * N;
  const float rm = r[(size_t)b * N + m];
  const float* f = f2 + ((size_t)b * N + m) * 3;
  float fx = f[0], fy = f[1], fz = f[2];
  float s = 0;
  for (int n = t; n < N; n += 256) {
    const float* pp = p3dt + ((size_t)b * N + n) * 3;
    float dot = fx * pp[0] + fy * pp[1] + fz * pp[2];
    s += __expf(row[n] - rm - cl[n]) * (1.f - dot);
  }
  red[t] = s; __syncthreads();
  for (int sft = 128; sft > 0; sft >>= 1) {
    if (t < sft) red[t] += red[t + sft];
    __syncthreads();
  }
  if (t == 0) rowsum[(size_t)b * N + m] = red[0];
}

__global__ __launch_bounds__(256) void k_err_fin(const float* __restrict__ rowsum,
                                                 float* __restrict__ out) {
  __shared__ float red[256];
  int b = blockIdx.x, t = threadIdx.x;
  float s = 0;
  for (int i = t; i < N; i += 256) s += rowsum[(size_t)b * N + i];
  red[t] = s; __syncthreads();
  for (int sft = 128; sft > 0; sft >>= 1) {
    if (t < sft) red[t] += red[t + sft];
    __syncthreads();
  }
  if (t == 0) out[b] = red[0];
}

// ================================================================= host
extern "C" void kernel_launch(void* const* d_in, const int* in_sizes, int n_in,
                              void* d_out, int out_size, void* d_ws, size_t ws_size,
                              hipStream_t stream) {
  const float* p2d     = (const float*)d_in[0];
  const float* p3d     = (const float*)d_in[1];
  const float* pose    = (const float*)d_in[2];
  const float* enc2d_w = (const float*)d_in[3];
  const float* enc2d_b = (const float*)d_in[4];
  const float* enc3d_w = (const float*)d_in[5];
  const float* enc3d_b = (const float*)d_in[6];
  const float* proj_w  = (const float*)d_in[7];
  const float* proj_b  = (const float*)d_in[8];
  const float* merge_w = (const float*)d_in[9];
  const float* merge_b = (const float*)d_in[10];
  const float* mlp1_w  = (const float*)d_in[11];
  const float* mlp1_b  = (const float*)d_in[12];
  const float* bn_g    = (const float*)d_in[13];
  const float* bn_b    = (const float*)d_in[14];
  const float* mlp2_w  = (const float*)d_in[15];
  const float* mlp2_b  = (const float*)d_in[16];

  float* W = (float*)d_ws;
  size_t off = 0;
  auto alloc = [&](size_t nelem) { float* p = W + off; off += nelem; return p; };
  const size_t SET = (size_t)B * D * N;
  float* f2    = alloc((size_t)B * N * 3);
  float* p3dt  = alloc((size_t)B * N * 3);
  float* descA = alloc(2 * SET);
  float* descB = alloc(2 * SET);
  float* qkv   = alloc(3 * 2 * SET);
  float* attnb = alloc(2 * SET);
  float* msgb  = alloc(2 * SET);
  float* hb    = alloc((size_t)2 * B * 256 * N);
  float* stat  = alloc(2 * 256 * 2);
  float* la    = alloc((size_t)B * N * N);
  float* pmax  = alloc((size_t)B * 32 * N);
  float* psum  = alloc((size_t)B * 32 * N);
  float* cvec  = alloc((size_t)B * N);
  float* rvec  = alloc((size_t)B * N);
  float* rowsum= alloc((size_t)B * N);
  (void)ws_size; (void)in_sizes; (void)n_in; (void)out_size;

  float* Qb = qkv;
  float* Kb = qkv + 2 * SET;
  float* Vb = qkv + 4 * SET;
  const size_t DS = (size_t)D * N;

  k_norm2d<<<(B * N) / 256, 256, 0, stream>>>(p2d, f2);
  k_encode<<<dim3(N, B), 256, 0, stream>>>(f2, enc2d_w, enc2d_b, descA);
  k_encode<<<dim3(N, B), 256, 0, stream>>>(p3d, enc3d_w, enc3d_b, descA + SET);

  float* dc = descA;
  float* dn = descB;
  for (int i = 0; i < 6; ++i) {
    int cross = (i & 1);
    const float* pw = proj_w + (size_t)i * 3 * D * D;
    const float* pb = proj_b + (size_t)i * 3 * D;
    float* d0 = dc;
    float* d1 = dc + SET;
    const float* sA = cross ? d1 : d0;
    const float* sB = cross ? d0 : d1;

    k_gemm<<<dim3(64, 6), 256, 0, stream>>>(
        d0, d1, sA, sB, pw, pb, nullptr, qkv, nullptr, nullptr, nullptr,
        D, D, DS, DS, D, 2 * SET, 1);
    k_attn<<<dim3(N / 128, NH, 2 * B), 256, 0, stream>>>(Qb, Kb, Vb, attnb);
    k_gemm<<<dim3(64, 2), 256, 0, stream>>>(
        attnb, attnb + SET, nullptr, nullptr, merge_w + (size_t)i * D * D,
        merge_b + (size_t)i * D, nullptr, msgb, nullptr, nullptr, nullptr,
        D, D, DS, DS, D, 0, 0);
    k_gemm<<<dim3(64, 4), 256, 0, stream>>>(
        dc, dc + SET, msgb, msgb + SET, mlp1_w + (size_t)i * 256 * 256,
        mlp1_b + (size_t)i * 256, nullptr, hb, nullptr, nullptr, nullptr,
        256, 128, DS, DS, 256, 0, 0);
    k_bnstat<<<dim3(256, 2), 256, 0, stream>>>(hb, stat);
    k_gemm<<<dim3(64, 2), 256, 0, stream>>>(
        hb, hb + (size_t)B * 256 * N, nullptr, nullptr,
        mlp2_w + (size_t)i * D * 256, mlp2_b + (size_t)i * D, dc, dn,
        stat, bn_g + (size_t)i * 256, bn_b + (size_t)i * 256,
        256, 256, (size_t)256 * N, 0, D, 0, 0);
    float* tmp = dc; dc = dn; dn = tmp;
  }

  k_dist<<<dim3(N / 8, B), 256, 0, stream>>>(dc, dc + SET, la);
  for (int it = 0; it < 10; ++it) {
    k_row_r<<<B * N, 256, 0, stream>>>(la, cvec, rvec, it > 0 ? 1 : 0);
    k_col_part<<<dim3(N / 256, 32, B), 256, 0, stream>>>(la, rvec, pmax, psum);
    k_col_fin<<<(B * N) / 256, 256, 0, stream>>>(pmax, psum, cvec);
  }
  k_rod<<<dim3(N / 256, B), 256, 0, stream>>>(pose, p3d, p3dt);
  k_err<<<dim3(N, B), 256, 0, stream>>>(la, rvec, cvec, f2, p3dt, rowsum);
  k_err_fin<<<B, 256, 0, stream>>>(rowsum, (float*)d_out);
}

// Round 14
// 1258.728 us; speedup vs baseline: 1.5174x; 1.0127x over previous
//
#include <hip/hip_runtime.h>
#include <hip/hip_bf16.h>

constexpr int B   = 4;
constexpr int N   = 1024;
constexpr int D   = 128;
constexpr int KNN = 10;
constexpr int NH  = 4;

typedef _Float16 half2v __attribute__((ext_vector_type(2)));

static __device__ __forceinline__ half2v pkrtz(float a, float b) {
  return __builtin_bit_cast(half2v, __builtin_amdgcn_cvt_pkrtz(a, b));
}
static __device__ __forceinline__ float h2f(half2v h) {
  return __builtin_bit_cast(float, h);
}

// ---------------------------------------------------------------- norm p2d
__global__ __launch_bounds__(256) void k_norm2d(const float* __restrict__ p2d,
                                                float* __restrict__ f2) {
  int i = blockIdx.x * 256 + threadIdx.x;  // over B*N
  const float* p = p2d + (size_t)i * 3;
  float x = p[0], y = p[1], z = p[2];
  float inr = 1.f / sqrtf(x * x + y * y + z * z);
  float* o = f2 + (size_t)i * 3;
  o[0] = x * inr; o[1] = y * inr; o[2] = z * inr;
}

// ---------------------------------------------------------------- KNN encode
__global__ __launch_bounds__(256) void k_encode(const float* __restrict__ pts,
                                                const float* __restrict__ w,
                                                const float* __restrict__ bias,
                                                float* __restrict__ desc) {
  __shared__ float P[N][3];
  __shared__ float xx[N];
  __shared__ float dist[N];
  __shared__ float rv[256];
  __shared__ int   ri[256];
  __shared__ float feat[6];
  __shared__ int   nidx[KNN];
  int t = threadIdx.x;
  int n = blockIdx.x, b = blockIdx.y;
  const float* pb = pts + (size_t)b * N * 3;
  for (int i = t; i < N; i += 256) {
    float x = pb[i * 3 + 0], y = pb[i * 3 + 1], z = pb[i * 3 + 2];
    P[i][0] = x; P[i][1] = y; P[i][2] = z;
    xx[i] = x * x + y * y + z * z;
  }
  __syncthreads();
  float cx = P[n][0], cy = P[n][1], cz = P[n][2], cxx = xx[n];
  for (int i = t; i < N; i += 256) {
    float ip = cx * P[i][0] + cy * P[i][1] + cz * P[i][2];
    dist[i] = 2.f * ip - cxx - xx[i];
  }
  __syncthreads();
  for (int kk = 0; kk < KNN; ++kk) {
    float bv = -3.0e38f; int bi = N;
    for (int i = t; i < N; i += 256) {
      float v = dist[i];
      if (v > bv) { bv = v; bi = i; }
    }
    rv[t] = bv; ri[t] = bi;
    __syncthreads();
    for (int s = 128; s > 0; s >>= 1) {
      if (t < s) {
        float v2 = rv[t + s]; int i2 = ri[t + s];
        if (v2 > rv[t] || (v2 == rv[t] && i2 < ri[t])) { rv[t] = v2; ri[t] = i2; }
      }
      __syncthreads();
    }
    if (t == 0) { nidx[kk] = ri[0]; dist[ri[0]] = -3.0e38f; }
    __syncthreads();
  }
  if (t == 0) {
    float sx = 0, sy = 0, sz = 0;
    for (int kk = 0; kk < KNN; ++kk) {
      int i = nidx[kk];
      sx += P[i][0]; sy += P[i][1]; sz += P[i][2];
    }
    const float invk = 1.f / KNN;
    feat[0] = sx * invk - cx; feat[1] = sy * invk - cy; feat[2] = sz * invk - cz;
    feat[3] = cx; feat[4] = cy; feat[5] = cz;
  }
  __syncthreads();
  if (t < D) {
    const float* wr = w + t * 6;
    float a = bias[t];
#pragma unroll
    for (int j = 0; j < 6; ++j) a += wr[j] * feat[j];
    desc[((size_t)b * D + t) * N + n] = a;
  }
}

// ---------------------------------------------------------------- tiled GEMM conv v2: f16 + v_dot2
__global__ __launch_bounds__(256) void k_gemm(
    const float* __restrict__ pA0, const float* __restrict__ pA1,
    const float* __restrict__ pB0, const float* __restrict__ pB1,
    const float* __restrict__ w, const float* __restrict__ bias,
    const float* __restrict__ res, float* __restrict__ out,
    const float* __restrict__ stat, const float* __restrict__ g,
    const float* __restrict__ bt,
    int Cin, int catOff, size_t a_bstr, size_t b_bstr,
    int segCout, size_t segStride, int qkvMode) {
  __shared__ half2v As2[64][20];   // [o][cpair], pad 20
  __shared__ half2v Bs2[16][128];  // [cpair][n]
  __shared__ float Ac[256], Bc[256];
  const int tid = threadIdx.x;
  const int to = tid >> 4;
  const int tn = tid & 15;
  const int o0 = blockIdx.y * 64;
  const int zb = blockIdx.x;
  const int z  = zb >> 3;
  const int n0 = (zb & 7) * 128;
  const int s = z >> 2, b = z & 3;
  const int seg = o0 / segCout;
  const int oo  = o0 % segCout;

  const float* XA = (s ? pA1 : pA0) + (size_t)b * a_bstr;
  const float* XB = pB0 ? ((s ? pB1 : pB0) + (size_t)b * b_bstr) : nullptr;
  const bool segB = qkvMode && (seg > 0);

  if (stat) {
    const float* st = stat + (size_t)s * 256 * 2;
    float A = st[tid * 2 + 1] * g[tid];
    Ac[tid] = A;
    Bc[tid] = fmaf(-st[tid * 2 + 0], A, bt[tid]);
  }

  float acc[4][8];
#pragma unroll
  for (int i = 0; i < 4; ++i)
#pragma unroll
    for (int j = 0; j < 8; ++j) acc[i][j] = 0.f;

  for (int kb = 0; kb < Cin; kb += 32) {
    __syncthreads();
#pragma unroll
    for (int j = 0; j < 2; ++j) {
      int idx = j * 256 + tid;
      int o = idx >> 3, c4 = (idx & 7) * 4;
      float4 wv = *(const float4*)&w[(size_t)(o0 + o) * Cin + kb + c4];
      As2[o][(c4 >> 1) + 0] = pkrtz(wv.x, wv.y);
      As2[o][(c4 >> 1) + 1] = pkrtz(wv.z, wv.w);
    }
#pragma unroll
    for (int j = 0; j < 2; ++j) {
      int idx = j * 256 + tid;
      int rp = idx >> 5, c4 = (idx & 31) * 4;
      int c0 = kb + 2 * rp, c1 = c0 + 1;
      const float* s0; int cc0 = c0;
      const float* s1; int cc1 = c1;
      if (qkvMode) {
        s0 = segB ? XB : XA; s1 = s0;
      } else {
        if (c0 >= catOff) { s0 = XB; cc0 = c0 - catOff; } else s0 = XA;
        if (c1 >= catOff) { s1 = XB; cc1 = c1 - catOff; } else s1 = XA;
      }
      float4 v0 = *(const float4*)&s0[(size_t)cc0 * N + n0 + c4];
      float4 v1 = *(const float4*)&s1[(size_t)cc1 * N + n0 + c4];
      if (stat) {
        float A0 = Ac[c0], B0 = Bc[c0], A1 = Ac[c1], B1 = Bc[c1];
        v0.x = fmaxf(fmaf(v0.x, A0, B0), 0.f);
        v0.y = fmaxf(fmaf(v0.y, A0, B0), 0.f);
        v0.z = fmaxf(fmaf(v0.z, A0, B0), 0.f);
        v0.w = fmaxf(fmaf(v0.w, A0, B0), 0.f);
        v1.x = fmaxf(fmaf(v1.x, A1, B1), 0.f);
        v1.y = fmaxf(fmaf(v1.y, A1, B1), 0.f);
        v1.z = fmaxf(fmaf(v1.z, A1, B1), 0.f);
        v1.w = fmaxf(fmaf(v1.w, A1, B1), 0.f);
      }
      float4 packed;
      packed.x = h2f(pkrtz(v0.x, v1.x));
      packed.y = h2f(pkrtz(v0.y, v1.y));
      packed.z = h2f(pkrtz(v0.z, v1.z));
      packed.w = h2f(pkrtz(v0.w, v1.w));
      *(float4*)&Bs2[rp][c4] = packed;
    }
    __syncthreads();
#pragma unroll
    for (int kk = 0; kk < 16; ++kk) {
      half2v a0 = As2[to * 4 + 0][kk];
      half2v a1 = As2[to * 4 + 1][kk];
      half2v a2 = As2[to * 4 + 2][kk];
      half2v a3 = As2[to * 4 + 3][kk];
      float4 br0 = *(const float4*)&Bs2[kk][tn * 8];
      float4 br1 = *(const float4*)&Bs2[kk][tn * 8 + 4];
      half2v bv[8];
      bv[0] = __builtin_bit_cast(half2v, br0.x);
      bv[1] = __builtin_bit_cast(half2v, br0.y);
      bv[2] = __builtin_bit_cast(half2v, br0.z);
      bv[3] = __builtin_bit_cast(half2v, br0.w);
      bv[4] = __builtin_bit_cast(half2v, br1.x);
      bv[5] = __builtin_bit_cast(half2v, br1.y);
      bv[6] = __builtin_bit_cast(half2v, br1.z);
      bv[7] = __builtin_bit_cast(half2v, br1.w);
#pragma unroll
      for (int j = 0; j < 8; ++j) {
        acc[0][j] = __builtin_amdgcn_fdot2(a0, bv[j], acc[0][j], false);
        acc[1][j] = __builtin_amdgcn_fdot2(a1, bv[j], acc[1][j], false);
        acc[2][j] = __builtin_amdgcn_fdot2(a2, bv[j], acc[2][j], false);
        acc[3][j] = __builtin_amdgcn_fdot2(a3, bv[j], acc[3][j], false);
      }
    }
  }
#pragma unroll
  for (int i = 0; i < 4; ++i) {
    int og = o0 + to * 4 + i;
    int o  = oo + to * 4 + i;
    float bi = bias[og];
    size_t ob = (size_t)seg * segStride + ((size_t)z * segCout + o) * N + n0 + tn * 8;
    float4 r0, r1;
    r0.x = acc[i][0] + bi; r0.y = acc[i][1] + bi;
    r0.z = acc[i][2] + bi; r0.w = acc[i][3] + bi;
    r1.x = acc[i][4] + bi; r1.y = acc[i][5] + bi;
    r1.z = acc[i][6] + bi; r1.w = acc[i][7] + bi;
    if (res) {
      float4 e0 = *(const float4*)&res[ob];
      float4 e1 = *(const float4*)&res[ob + 4];
      r0.x += e0.x; r0.y += e0.y; r0.z += e0.z; r0.w += e0.w;
      r1.x += e1.x; r1.y += e1.y; r1.z += e1.z; r1.w += e1.w;
    }
    *(float4*)&out[ob] = r0;
    *(float4*)&out[ob + 4] = r1;
  }
}

// ---------------------------------------------------------------- attention v9: 8 waves x 128 keys
// grid (N/128, NH, 2*B) = 256 blocks, 512 thr = 8 waves, QPL=2, f16 K/V+v_dot2.
// R13 post-mortem: v7 at 4 waves was 1 wave/SIMD (grid=1 block/CU) -> LDS
// latency exposed (74us vs 41us floor). Same total work split over 8 waves of
// 128 keys each = 2 waves/SIMD residency -> overlap. 8-way merge reuses the
// same 67.6KB pool in two rounds of 64 q (round 0 = accA, round 1 = accB);
// LDS stays 71680B, VGPR ~160. R12 lesson respected: grid not shrunk.
__global__ __launch_bounds__(512) void k_attn(const float* __restrict__ Q,
                                              const float* __restrict__ Kt,
                                              const float* __restrict__ Vt,
                                              float* __restrict__ O) {
  __shared__ float pool[16896];          // staging f16 (8x4KB=32KB); merge f32 67.6KB
  __shared__ float ms_[8][64], ls_[8][64];
  half2v* pool2 = (half2v*)pool;
  const int t  = threadIdx.x;
  const int lq = t & 63, s = t >> 6;    // wave id 0..7
  const int q0 = blockIdx.x * 128;
  const int h  = blockIdx.y;
  const int z  = blockIdx.z;
  const size_t base = (size_t)z * (size_t)(D * N);
  const float* Kb = Kt + base;
  const float* Vb = Vt + base;
  const int sb2 = s * 1024;             // per-wave region: K [0,512), V [512,1024)
  const int kg  = lq & 7;               // staging key-group (4 keys)
  const int dp  = lq >> 3;              // 0..7

  const float scale = 0.17677669529663687f;  // 1/sqrt(32), folded into q
  half2v qpA[16], qpB[16];
  float accA[32], accB[32];
#pragma unroll
  for (int dd = 0; dd < 16; ++dd) {
    float a0 = Q[base + (size_t)((2 * dd) * 4 + h) * N + q0 + lq] * scale;
    float a1 = Q[base + (size_t)((2 * dd + 1) * 4 + h) * N + q0 + lq] * scale;
    qpA[dd] = pkrtz(a0, a1);
    float b0 = Q[base + (size_t)((2 * dd) * 4 + h) * N + q0 + 64 + lq] * scale;
    float b1 = Q[base + (size_t)((2 * dd + 1) * 4 + h) * N + q0 + 64 + lq] * scale;
    qpB[dd] = pkrtz(b0, b1);
  }
#pragma unroll
  for (int d = 0; d < 32; ++d) { accA[d] = 0.f; accB[d] = 0.f; }
  float mxA = -1e30f, mxB = -1e30f, lA = 0.f, lB = 0.f;

  // wave s owns keys [s*128, (s+1)*128): 4 chunks of 32
  for (int c = 0; c < 4; ++c) {
    const int k0 = s * 128 + c * 32;
    // ---- stage K: Kh[j][dd] = (K[2dd][j], K[2dd+1][j]) f16
#pragma unroll
    for (int rep = 0; rep < 2; ++rep) {
      int dd = dp + rep * 8;
      const float4 va = *(const float4*)(Kb + (size_t)((2 * dd) * 4 + h) * N + k0 + kg * 4);
      const float4 vb = *(const float4*)(Kb + (size_t)((2 * dd + 1) * 4 + h) * N + k0 + kg * 4);
      pool2[sb2 + (kg * 4 + 0) * 16 + dd] = pkrtz(va.x, vb.x);
      pool2[sb2 + (kg * 4 + 1) * 16 + dd] = pkrtz(va.y, vb.y);
      pool2[sb2 + (kg * 4 + 2) * 16 + dd] = pkrtz(va.z, vb.z);
      pool2[sb2 + (kg * 4 + 3) * 16 + dd] = pkrtz(va.w, vb.w);
    }
    // ---- stage V: Vp[d][jp] = (V[2jp][d], V[2jp+1][d]) f16
#pragma unroll
    for (int rep = 0; rep < 4; ++rep) {
      int d = dp + rep * 8;
      const float4 vv = *(const float4*)(Vb + (size_t)(d * 4 + h) * N + k0 + kg * 4);
      int idx = sb2 + 512 + d * 16 + kg * 2;
      pool2[idx]     = pkrtz(vv.x, vv.y);
      pool2[idx + 1] = pkrtz(vv.z, vv.w);
    }
    // ---- 4 steps of 8 keys
#pragma unroll
    for (int st = 0; st < 4; ++st) {
      float scA[8], scB[8];
#pragma unroll
      for (int jj = 0; jj < 8; ++jj) {
        const int rb = sb2 + (st * 8 + jj) * 16;
        float a = 0.f, bq = 0.f;
#pragma unroll
        for (int r = 0; r < 4; ++r) {
          float4 raw = *(const float4*)&pool2[rb + r * 4];
          half2v k0h = __builtin_bit_cast(half2v, raw.x);
          half2v k1h = __builtin_bit_cast(half2v, raw.y);
          half2v k2h = __builtin_bit_cast(half2v, raw.z);
          half2v k3h = __builtin_bit_cast(half2v, raw.w);
          a  = __builtin_amdgcn_fdot2(k0h, qpA[r * 4 + 0], a,  false);
          a  = __builtin_amdgcn_fdot2(k1h, qpA[r * 4 + 1], a,  false);
          a  = __builtin_amdgcn_fdot2(k2h, qpA[r * 4 + 2], a,  false);
          a  = __builtin_amdgcn_fdot2(k3h, qpA[r * 4 + 3], a,  false);
          bq = __builtin_amdgcn_fdot2(k0h, qpB[r * 4 + 0], bq, false);
          bq = __builtin_amdgcn_fdot2(k1h, qpB[r * 4 + 1], bq, false);
          bq = __builtin_amdgcn_fdot2(k2h, qpB[r * 4 + 2], bq, false);
          bq = __builtin_amdgcn_fdot2(k3h, qpB[r * 4 + 3], bq, false);
        }
        scA[jj] = a; scB[jj] = bq;
      }
      // online softmax over these 8 keys (f32)
      float hA = scA[0], hB = scB[0];
#pragma unroll
      for (int j = 1; j < 8; ++j) { hA = fmaxf(hA, scA[j]); hB = fmaxf(hB, scB[j]); }
      float nmA = fmaxf(mxA, hA), nmB = fmaxf(mxB, hB);
      float cA = __expf(mxA - nmA), cB = __expf(mxB - nmB);
      lA *= cA; lB *= cB;
#pragma unroll
      for (int d = 0; d < 32; ++d) { accA[d] *= cA; accB[d] *= cB; }
      mxA = nmA; mxB = nmB;
#pragma unroll
      for (int j = 0; j < 8; ++j) {
        scA[j] = __expf(scA[j] - mxA); lA += scA[j];
        scB[j] = __expf(scB[j] - mxB); lB += scB[j];
      }
      // pack P to f16 (pair order matches Vp key-pairing)
      half2v pA2[4], pB2[4];
#pragma unroll
      for (int u = 0; u < 4; ++u) {
        pA2[u] = pkrtz(scA[2 * u], scA[2 * u + 1]);
        pB2[u] = pkrtz(scB[2 * u], scB[2 * u + 1]);
      }
      // PV: one b128 read = 8 keys at dim d
#pragma unroll
      for (int d = 0; d < 32; ++d) {
        float4 raw = *(const float4*)&pool2[sb2 + 512 + d * 16 + st * 4];
        half2v v0 = __builtin_bit_cast(half2v, raw.x);
        half2v v1 = __builtin_bit_cast(half2v, raw.y);
        half2v v2 = __builtin_bit_cast(half2v, raw.z);
        half2v v3 = __builtin_bit_cast(half2v, raw.w);
        float aa = accA[d];
        aa = __builtin_amdgcn_fdot2(v0, pA2[0], aa, false);
        aa = __builtin_amdgcn_fdot2(v1, pA2[1], aa, false);
        aa = __builtin_amdgcn_fdot2(v2, pA2[2], aa, false);
        aa = __builtin_amdgcn_fdot2(v3, pA2[3], aa, false);
        accA[d] = aa;
        float bb = accB[d];
        bb = __builtin_amdgcn_fdot2(v0, pB2[0], bb, false);
        bb = __builtin_amdgcn_fdot2(v1, pB2[1], bb, false);
        bb = __builtin_amdgcn_fdot2(v2, pB2[2], bb, false);
        bb = __builtin_amdgcn_fdot2(v3, pB2[3], bb, false);
        accB[d] = bb;
      }
    }
  }

  // ---- merge 8 key-split partials in TWO rounds of 64 q (pool reuse)
#pragma unroll
  for (int rr = 0; rr < 2; ++rr) {
    __syncthreads();                     // staging reads (rr=0) / prev merge reads (rr=1) done
    ms_[s][lq] = rr ? mxB : mxA;
    ls_[s][lq] = rr ? lB  : lA;
#pragma unroll
    for (int d = 0; d < 32; ++d)
      pool[(s * 64 + lq) * 33 + d] = rr ? accB[d] : accA[d];
    __syncthreads();
    {
      int qq = t & 63, dg = t >> 6;      // dg 0..7 -> 4 d each
      float M = ms_[0][qq];
#pragma unroll
      for (int ss = 1; ss < 8; ++ss) M = fmaxf(M, ms_[ss][qq]);
      float wg[8], L = 0.f;
#pragma unroll
      for (int ss = 0; ss < 8; ++ss) {
        wg[ss] = __expf(ms_[ss][qq] - M);
        L += ls_[ss][qq] * wg[ss];
      }
      float invL = 1.f / L;
#pragma unroll
      for (int k = 0; k < 4; ++k) {
        int d = dg * 4 + k;
        float o = 0.f;
#pragma unroll
        for (int ss = 0; ss < 8; ++ss) o += pool[(ss * 64 + qq) * 33 + d] * wg[ss];
        O[base + (size_t)(d * 4 + h) * N + q0 + rr * 64 + qq] = o * invL;
      }
    }
  }
}

// ---------------------------------------------------------------- BN stats (single pass)
__global__ __launch_bounds__(256) void k_bnstat(const float* __restrict__ h,
                                                float* __restrict__ stat) {
  int c = blockIdx.x, s = blockIdx.y, t = threadIdx.x;
  __shared__ float red[256], red2[256];
  const float* base = h + ((size_t)s * B * 256 + c) * N;
  float sum = 0, sq = 0;
  for (int b = 0; b < B; ++b)
    for (int i = t; i < N; i += 256) {
      float v = base[(size_t)b * 256 * N + i];
      sum += v; sq = fmaf(v, v, sq);
    }
  red[t] = sum; red2[t] = sq; __syncthreads();
  for (int sft = 128; sft > 0; sft >>= 1) {
    if (t < sft) { red[t] += red[t + sft]; red2[t] += red2[t + sft]; }
    __syncthreads();
  }
  if (t == 0) {
    float mean = red[0] / (float)(B * N);
    float var = fmaxf(red2[0] / (float)(B * N) - mean * mean, 0.f);
    stat[(s * 256 + c) * 2 + 0] = mean;
    stat[(s * 256 + c) * 2 + 1] = 1.f / sqrtf(var + 1e-5f);
  }
}

// ---------------------------------------------------------------- pairwise dist (8-m tile)
__global__ __launch_bounds__(256) void k_dist(const float* __restrict__ d0,
                                              const float* __restrict__ d1,
                                              float* __restrict__ la) {
  __shared__ float xm[8][128];
  __shared__ float n0s[8];
  int m0 = blockIdx.x * 8, b = blockIdx.y, t = threadIdx.x;
  const float* p0 = d0 + (size_t)b * D * N;
  const float* p1 = d1 + (size_t)b * D * N;
  for (int i = t; i < 8 * 128; i += 256) {
    int mm = i >> 7, d = i & 127;
    xm[mm][d] = p0[(size_t)d * N + m0 + mm];
  }
  __syncthreads();
  if (t < 8) {
    float s = 0;
    for (int d = 0; d < 128; ++d) s += xm[t][d] * xm[t][d];
    n0s[t] = s;
  }
  __syncthreads();
  float dot[8][4] = {{0}};
  float n1[4] = {0, 0, 0, 0};
  for (int d = 0; d < 128; ++d) {
    float v[4];
#pragma unroll
    for (int u = 0; u < 4; ++u) {
      v[u] = p1[(size_t)d * N + t + u * 256];
      n1[u] = fmaf(v[u], v[u], n1[u]);
    }
#pragma unroll
    for (int mm = 0; mm < 8; ++mm) {
      float x = xm[mm][d];
#pragma unroll
      for (int u = 0; u < 4; ++u) dot[mm][u] = fmaf(x, v[u], dot[mm][u]);
    }
  }
  for (int mm = 0; mm < 8; ++mm) {
    float* row = la + ((size_t)b * N + m0 + mm) * N;
#pragma unroll
    for (int u = 0; u < 4; ++u) {
      float dist2 = fmaxf(n0s[mm] + n1[u] - 2.f * dot[mm][u], 1e-30f);
      row[t + u * 256] = -sqrtf(dist2);
    }
  }
}

// ---------------------------------------------------------------- sinkhorn offset form
__global__ __launch_bounds__(256) void k_row_r(const float* __restrict__ l0,
                                               const float* __restrict__ cvec,
                                               float* __restrict__ r,
                                               int useC) {
  __shared__ float red[256];
  int t = threadIdx.x;
  int bm = blockIdx.x;              // over B*N
  int b = bm >> 10;
  const float* row = l0 + (size_t)bm * N;
  float v0 = row[t], v1 = row[t + 256], v2 = row[t + 512], v3 = row[t + 768];
  if (useC) {
    const float* cl = cvec + (size_t)b * N;
    v0 -= cl[t]; v1 -= cl[t + 256]; v2 -= cl[t + 512]; v3 -= cl[t + 768];
  }
  float mx = fmaxf(fmaxf(v0, v1), fmaxf(v2, v3));
  red[t] = mx; __syncthreads();
  for (int s = 128; s > 0; s >>= 1) {
    if (t < s) red[t] = fmaxf(red[t], red[t + s]);
    __syncthreads();
  }
  mx = red[0]; __syncthreads();
  float se = __expf(v0 - mx) + __expf(v1 - mx) + __expf(v2 - mx) + __expf(v3 - mx);
  red[t] = se; __syncthreads();
  for (int s = 128; s > 0; s >>= 1) {
    if (t < s) red[t] += red[t + s];
    __syncthreads();
  }
  if (t == 0) r[bm] = mx + __logf(red[0]);
}

__global__ __launch_bounds__(256) void k_col_part(const float* __restrict__ l0,
                                                  const float* __restrict__ r,
                                                  float* __restrict__ pmax,
                                                  float* __restrict__ psum) {
  int t = threadIdx.x;
  int n = blockIdx.x * 256 + t;
  int p = blockIdx.y, b = blockIdx.z;
  const float* base = l0 + ((size_t)b * N + p * 32) * N + n;
  const float* rr = r + (size_t)b * N + p * 32;
  float mx = -1e30f, s = 0;
  for (int m = 0; m < 32; ++m) {
    float v = base[(size_t)m * N] - rr[m];
    if (v > mx) { s = s * __expf(mx - v) + 1.f; mx = v; }
    else s += __expf(v - mx);
  }
  pmax[((size_t)b * 32 + p) * N + n] = mx;
  psum[((size_t)b * 32 + p) * N + n] = s;
}

__global__ __launch_bounds__(256) void k_col_fin(const float* __restrict__ pmax,
                                                 const float* __restrict__ psum,
                                                 float* __restrict__ cvec) {
  int i = blockIdx.x * 256 + threadIdx.x;  // over B*N
  int b = i / N, n = i % N;
  float mx = -1e30f;
#pragma unroll
  for (int p = 0; p < 32; ++p) mx = fmaxf(mx, pmax[((size_t)b * 32 + p) * N + n]);
  float s = 0;
#pragma unroll
  for (int p = 0; p < 32; ++p)
    s += psum[((size_t)b * 32 + p) * N + n] * __expf(pmax[((size_t)b * 32 + p) * N + n] - mx);
  cvec[i] = mx + __logf(s);
}

// ---------------------------------------------------------------- rodrigues + transform
__global__ __launch_bounds__(256) void k_rod(const float* __restrict__ pose,
                                             const float* __restrict__ p3d,
                                             float* __restrict__ p3dt) {
  int b = blockIdx.y;
  int n = blockIdx.x * 256 + threadIdx.x;
  const float* aa = pose + b * 6;
  float ax = aa[0], ay = aa[1], az = aa[2];
  float th = fmaxf(sqrtf(ax * ax + ay * ay + az * az), 1e-8f);
  float rx = ax / th, ry = ay / th, rz = az / th;
  float c = cosf(th), s = sinf(th), oc = 1.f - c;
  float R00 = c + oc * rx * rx,      R01 = oc * rx * ry - s * rz, R02 = oc * rx * rz + s * ry;
  float R10 = oc * ry * rx + s * rz, R11 = c + oc * ry * ry,      R12 = oc * ry * rz - s * rx;
  float R20 = oc * rz * rx - s * ry, R21 = oc * rz * ry + s * rx, R22 = c + oc * rz * rz;
  const float* p = p3d + ((size_t)b * N + n) * 3;
  float x = p[0], y = p[1], z = p[2];
  float X = R00 * x + R01 * y + R02 * z + aa[3];
  float Y = R10 * x + R11 * y + R12 * z + aa[4];
  float Z = R20 * x + R21 * y + R22 * z + aa[5];
  float inr = 1.f / sqrtf(X * X + Y * Y + Z * Z);
  float* o = p3dt + ((size_t)b * N + n) * 3;
  o[0] = X * inr; o[1] = Y * inr; o[2] = Z * inr;
}

// ---------------------------------------------------------------- final error (applies r,c offsets)
__global__ __launch_bounds__(256) void k_err(const float* __restrict__ l0,
                                             const float* __restrict__ r,
                                             const float* __restrict__ cvec,
                                             const float* __restrict__ f2,
                                             const float* __restrict__ p3dt,
                                             float* __restrict__ rowsum) {
  __shared__ float red[256];
  int m = blockIdx.x, b = blockIdx.y, t = threadIdx.x;
  const float* row = l0 + ((size_t)b * N + m) * N;
  const float* cl = cvec + (size_t)b * N;
  const float rm = r[(size_t)b * N + m];
  const float* f = f2 + ((size_t)b * N + m) * 3;
  float fx = f[0], fy = f[1], fz = f[2];
  float s = 0;
  for (int n = t; n < N; n += 256) {
    const float* pp = p3dt + ((size_t)b * N + n) * 3;
    float dot = fx * pp[0] + fy * pp[1] + fz * pp[2];
    s += __expf(row[n] - rm - cl[n]) * (1.f - dot);
  }
  red[t] = s; __syncthreads();
  for (int sft = 128; sft > 0; sft >>= 1) {
    if (t < sft) red[t] += red[t + sft];
    __syncthreads();
  }
  if (t == 0) rowsum[(size_t)b * N + m] = red[0];
}

__global__ __launch_bounds__(256) void k_err_fin(const float* __restrict__ rowsum,
                                                 float* __restrict__ out) {
  __shared__ float red[256];
  int b = blockIdx.x, t = threadIdx.x;
  float s = 0;
  for (int i = t; i < N; i += 256) s += rowsum[(size_t)b * N + i];
  red[t] = s; __syncthreads();
  for (int sft = 128; sft > 0; sft >>= 1) {
    if (t < sft) red[t] += red[t + sft];
    __syncthreads();
  }
  if (t == 0) out[b] = red[0];
}

// ================================================================= host
extern "C" void kernel_launch(void* const* d_in, const int* in_sizes, int n_in,
                              void* d_out, int out_size, void* d_ws, size_t ws_size,
                              hipStream_t stream) {
  const float* p2d     = (const float*)d_in[0];
  const float* p3d     = (const float*)d_in[1];
  const float* pose    = (const float*)d_in[2];
  const float* enc2d_w = (const float*)d_in[3];
  const float* enc2d_b = (const float*)d_in[4];
  const float* enc3d_w = (const float*)d_in[5];
  const float* enc3d_b = (const float*)d_in[6];
  const float* proj_w  = (const float*)d_in[7];
  const float* proj_b  = (const float*)d_in[8];
  const float* merge_w = (const float*)d_in[9];
  const float* merge_b = (const float*)d_in[10];
  const float* mlp1_w  = (const float*)d_in[11];
  const float* mlp1_b  = (const float*)d_in[12];
  const float* bn_g    = (const float*)d_in[13];
  const float* bn_b    = (const float*)d_in[14];
  const float* mlp2_w  = (const float*)d_in[15];
  const float* mlp2_b  = (const float*)d_in[16];

  float* W = (float*)d_ws;
  size_t off = 0;
  auto alloc = [&](size_t nelem) { float* p = W + off; off += nelem; return p; };
  const size_t SET = (size_t)B * D * N;
  float* f2    = alloc((size_t)B * N * 3);
  float* p3dt  = alloc((size_t)B * N * 3);
  float* descA = alloc(2 * SET);
  float* descB = alloc(2 * SET);
  float* qkv   = alloc(3 * 2 * SET);
  float* attnb = alloc(2 * SET);
  float* msgb  = alloc(2 * SET);
  float* hb    = alloc((size_t)2 * B * 256 * N);
  float* stat  = alloc(2 * 256 * 2);
  float* la    = alloc((size_t)B * N * N);
  float* pmax  = alloc((size_t)B * 32 * N);
  float* psum  = alloc((size_t)B * 32 * N);
  float* cvec  = alloc((size_t)B * N);
  float* rvec  = alloc((size_t)B * N);
  float* rowsum= alloc((size_t)B * N);
  (void)ws_size; (void)in_sizes; (void)n_in; (void)out_size;

  float* Qb = qkv;
  float* Kb = qkv + 2 * SET;
  float* Vb = qkv + 4 * SET;
  const size_t DS = (size_t)D * N;

  k_norm2d<<<(B * N) / 256, 256, 0, stream>>>(p2d, f2);
  k_encode<<<dim3(N, B), 256, 0, stream>>>(f2, enc2d_w, enc2d_b, descA);
  k_encode<<<dim3(N, B), 256, 0, stream>>>(p3d, enc3d_w, enc3d_b, descA + SET);

  float* dc = descA;
  float* dn = descB;
  for (int i = 0; i < 6; ++i) {
    int cross = (i & 1);
    const float* pw = proj_w + (size_t)i * 3 * D * D;
    const float* pb = proj_b + (size_t)i * 3 * D;
    float* d0 = dc;
    float* d1 = dc + SET;
    const float* sA = cross ? d1 : d0;
    const float* sB = cross ? d0 : d1;

    k_gemm<<<dim3(64, 6), 256, 0, stream>>>(
        d0, d1, sA, sB, pw, pb, nullptr, qkv, nullptr, nullptr, nullptr,
        D, D, DS, DS, D, 2 * SET, 1);
    k_attn<<<dim3(N / 128, NH, 2 * B), 512, 0, stream>>>(Qb, Kb, Vb, attnb);
    k_gemm<<<dim3(64, 2), 256, 0, stream>>>(
        attnb, attnb + SET, nullptr, nullptr, merge_w + (size_t)i * D * D,
        merge_b + (size_t)i * D, nullptr, msgb, nullptr, nullptr, nullptr,
        D, D, DS, DS, D, 0, 0);
    k_gemm<<<dim3(64, 4), 256, 0, stream>>>(
        dc, dc + SET, msgb, msgb + SET, mlp1_w + (size_t)i * 256 * 256,
        mlp1_b + (size_t)i * 256, nullptr, hb, nullptr, nullptr, nullptr,
        256, 128, DS, DS, 256, 0, 0);
    k_bnstat<<<dim3(256, 2), 256, 0, stream>>>(hb, stat);
    k_gemm<<<dim3(64, 2), 256, 0, stream>>>(
        hb, hb + (size_t)B * 256 * N, nullptr, nullptr,
        mlp2_w + (size_t)i * D * 256, mlp2_b + (size_t)i * D, dc, dn,
        stat, bn_g + (size_t)i * 256, bn_b + (size_t)i * 256,
        256, 256, (size_t)256 * N, 0, D, 0, 0);
    float* tmp = dc; dc = dn; dn = tmp;
  }

  k_dist<<<dim3(N / 8, B), 256, 0, stream>>>(dc, dc + SET, la);
  for (int it = 0; it < 10; ++it) {
    k_row_r<<<B * N, 256, 0, stream>>>(la, cvec, rvec, it > 0 ? 1 : 0);
    k_col_part<<<dim3(N / 256, 32, B), 256, 0, stream>>>(la, rvec, pmax, psum);
    k_col_fin<<<(B * N) / 256, 256, 0, stream>>>(pmax, psum, cvec);
  }
  k_rod<<<dim3(N / 256, B), 256, 0, stream>>>(pose, p3d, p3dt);
  k_err<<<dim3(N, B), 256, 0, stream>>>(la, rvec, cvec, f2, p3dt, rowsum);
  k_err_fin<<<B, 256, 0, stream>>>(rowsum, (float*)d_out);
}

// Round 15
// 1123.211 us; speedup vs baseline: 1.7004x; 1.1207x over previous
//
#include <hip/hip_runtime.h>
#include <hip/hip_bf16.h>

constexpr int B   = 4;
constexpr int N   = 1024;
constexpr int D   = 128;
constexpr int KNN = 10;
constexpr int NH  = 4;

typedef _Float16 half2v __attribute__((ext_vector_type(2)));
typedef _Float16 f16x8  __attribute__((ext_vector_type(8)));
typedef float    f32x4  __attribute__((ext_vector_type(4)));

static __device__ __forceinline__ half2v pkrtz(float a, float b) {
  return __builtin_bit_cast(half2v, __builtin_amdgcn_cvt_pkrtz(a, b));
}
static __device__ __forceinline__ float h2f(half2v h) {
  return __builtin_bit_cast(float, h);
}

// ---------------------------------------------------------------- norm p2d
__global__ __launch_bounds__(256) void k_norm2d(const float* __restrict__ p2d,
                                                float* __restrict__ f2) {
  int i = blockIdx.x * 256 + threadIdx.x;  // over B*N
  const float* p = p2d + (size_t)i * 3;
  float x = p[0], y = p[1], z = p[2];
  float inr = 1.f / sqrtf(x * x + y * y + z * z);
  float* o = f2 + (size_t)i * 3;
  o[0] = x * inr; o[1] = y * inr; o[2] = z * inr;
}

// ---------------------------------------------------------------- KNN encode
__global__ __launch_bounds__(256) void k_encode(const float* __restrict__ pts,
                                                const float* __restrict__ w,
                                                const float* __restrict__ bias,
                                                float* __restrict__ desc) {
  __shared__ float P[N][3];
  __shared__ float xx[N];
  __shared__ float dist[N];
  __shared__ float rv[256];
  __shared__ int   ri[256];
  __shared__ float feat[6];
  __shared__ int   nidx[KNN];
  int t = threadIdx.x;
  int n = blockIdx.x, b = blockIdx.y;
  const float* pb = pts + (size_t)b * N * 3;
  for (int i = t; i < N; i += 256) {
    float x = pb[i * 3 + 0], y = pb[i * 3 + 1], z = pb[i * 3 + 2];
    P[i][0] = x; P[i][1] = y; P[i][2] = z;
    xx[i] = x * x + y * y + z * z;
  }
  __syncthreads();
  float cx = P[n][0], cy = P[n][1], cz = P[n][2], cxx = xx[n];
  for (int i = t; i < N; i += 256) {
    float ip = cx * P[i][0] + cy * P[i][1] + cz * P[i][2];
    dist[i] = 2.f * ip - cxx - xx[i];
  }
  __syncthreads();
  for (int kk = 0; kk < KNN; ++kk) {
    float bv = -3.0e38f; int bi = N;
    for (int i = t; i < N; i += 256) {
      float v = dist[i];
      if (v > bv) { bv = v; bi = i; }
    }
    rv[t] = bv; ri[t] = bi;
    __syncthreads();
    for (int s = 128; s > 0; s >>= 1) {
      if (t < s) {
        float v2 = rv[t + s]; int i2 = ri[t + s];
        if (v2 > rv[t] || (v2 == rv[t] && i2 < ri[t])) { rv[t] = v2; ri[t] = i2; }
      }
      __syncthreads();
    }
    if (t == 0) { nidx[kk] = ri[0]; dist[ri[0]] = -3.0e38f; }
    __syncthreads();
  }
  if (t == 0) {
    float sx = 0, sy = 0, sz = 0;
    for (int kk = 0; kk < KNN; ++kk) {
      int i = nidx[kk];
      sx += P[i][0]; sy += P[i][1]; sz += P[i][2];
    }
    const float invk = 1.f / KNN;
    feat[0] = sx * invk - cx; feat[1] = sy * invk - cy; feat[2] = sz * invk - cz;
    feat[3] = cx; feat[4] = cy; feat[5] = cz;
  }
  __syncthreads();
  if (t < D) {
    const float* wr = w + t * 6;
    float a = bias[t];
#pragma unroll
    for (int j = 0; j < 6; ++j) a += wr[j] * feat[j];
    desc[((size_t)b * D + t) * N + n] = a;
  }
}

// ---------------------------------------------------------------- tiled GEMM conv v3: MFMA f16
// out = W(f16) * X(f16) + bias (+res), f32 accum via v_mfma_f32_16x16x32_f16.
// Block 256 thr = 4 waves; output 64o x 128n; wave = (wo,wn) quadrant 32o x 64n
// = 8 MFMA tiles of 16x16 per k-step (K=32). A-frag: lane reads 8 contiguous
// f16 at As[o=wo*32+ti*16+(l&15)][(l>>4)*8] (one b128). B-frag: 4 b32 reads
// Bs[kp=(l>>4)*4+e][n] of half2(k even,k odd) — A/B share the same k-order so
// any internal k-permutation cancels. C/D layout (HW-verified m89):
// row=(l>>4)*4+reg, col=l&15. LDS 16.6KB -> 3-4 blocks/CU.
__global__ __launch_bounds__(256) void k_gemm(
    const float* __restrict__ pA0, const float* __restrict__ pA1,
    const float* __restrict__ pB0, const float* __restrict__ pB1,
    const float* __restrict__ w, const float* __restrict__ bias,
    const float* __restrict__ res, float* __restrict__ out,
    const float* __restrict__ stat, const float* __restrict__ g,
    const float* __restrict__ bt,
    int Cin, int catOff, size_t a_bstr, size_t b_bstr,
    int segCout, size_t segStride, int qkvMode) {
  __shared__ _Float16 As[64][48];   // [o][c], 96B rows (16B-aligned)
  __shared__ half2v   Bs[16][132];  // [cpair][n], 528B rows (16B-aligned, 2-way banks)
  __shared__ float Ac[256], Bc[256];
  const int tid = threadIdx.x;
  const int wv  = tid >> 6;        // wave 0..3
  const int l   = tid & 63;
  const int wo  = wv >> 1;         // o half (32 rows)
  const int wn  = wv & 1;          // n half (64 cols)
  const int lr  = l & 15;
  const int lg  = l >> 4;          // k-group / D-row group
  const int o0 = blockIdx.y * 64;
  const int zb = blockIdx.x;
  const int z  = zb >> 3;
  const int n0 = (zb & 7) * 128;
  const int s = z >> 2, b = z & 3;
  const int seg = o0 / segCout;
  const int oo  = o0 % segCout;

  const float* XA = (s ? pA1 : pA0) + (size_t)b * a_bstr;
  const float* XB = pB0 ? ((s ? pB1 : pB0) + (size_t)b * b_bstr) : nullptr;
  const bool segB = qkvMode && (seg > 0);

  if (stat) {
    const float* st = stat + (size_t)s * 256 * 2;
    float A = st[tid * 2 + 1] * g[tid];
    Ac[tid] = A;
    Bc[tid] = fmaf(-st[tid * 2 + 0], A, bt[tid]);
  }

  f32x4 acc[2][4];
#pragma unroll
  for (int i = 0; i < 2; ++i)
#pragma unroll
    for (int j = 0; j < 4; ++j) acc[i][j] = (f32x4){0.f, 0.f, 0.f, 0.f};

  for (int kb = 0; kb < Cin; kb += 32) {
    __syncthreads();
    // stage W tile -> f16 [64][48]
#pragma unroll
    for (int j = 0; j < 2; ++j) {
      int idx = j * 256 + tid;
      int o = idx >> 3, c4 = (idx & 7) * 4;
      float4 wvv = *(const float4*)&w[(size_t)(o0 + o) * Cin + kb + c4];
      *(half2v*)&As[o][c4]     = pkrtz(wvv.x, wvv.y);
      *(half2v*)&As[o][c4 + 2] = pkrtz(wvv.z, wvv.w);
    }
    // stage X tile: k-pairs of half2 per n
#pragma unroll
    for (int j = 0; j < 2; ++j) {
      int idx = j * 256 + tid;
      int rp = idx >> 5, c4 = (idx & 31) * 4;
      int c0 = kb + 2 * rp, c1 = c0 + 1;
      const float* s0; int cc0 = c0;
      const float* s1; int cc1 = c1;
      if (qkvMode) {
        s0 = segB ? XB : XA; s1 = s0;
      } else {
        if (c0 >= catOff) { s0 = XB; cc0 = c0 - catOff; } else s0 = XA;
        if (c1 >= catOff) { s1 = XB; cc1 = c1 - catOff; } else s1 = XA;
      }
      float4 v0 = *(const float4*)&s0[(size_t)cc0 * N + n0 + c4];
      float4 v1 = *(const float4*)&s1[(size_t)cc1 * N + n0 + c4];
      if (stat) {
        float A0 = Ac[c0], B0 = Bc[c0], A1 = Ac[c1], B1 = Bc[c1];
        v0.x = fmaxf(fmaf(v0.x, A0, B0), 0.f);
        v0.y = fmaxf(fmaf(v0.y, A0, B0), 0.f);
        v0.z = fmaxf(fmaf(v0.z, A0, B0), 0.f);
        v0.w = fmaxf(fmaf(v0.w, A0, B0), 0.f);
        v1.x = fmaxf(fmaf(v1.x, A1, B1), 0.f);
        v1.y = fmaxf(fmaf(v1.y, A1, B1), 0.f);
        v1.z = fmaxf(fmaf(v1.z, A1, B1), 0.f);
        v1.w = fmaxf(fmaf(v1.w, A1, B1), 0.f);
      }
      float4 packed;
      packed.x = h2f(pkrtz(v0.x, v1.x));
      packed.y = h2f(pkrtz(v0.y, v1.y));
      packed.z = h2f(pkrtz(v0.z, v1.z));
      packed.w = h2f(pkrtz(v0.w, v1.w));
      *(float4*)&Bs[rp][c4] = packed;
    }
    __syncthreads();
    // compute: 2 A-frags (b128 each), 4 B-frags (4 b32 each), 8 MFMA
    f16x8 afr0 = *(const f16x8*)&As[wo * 32 + lr][lg * 8];
    f16x8 afr1 = *(const f16x8*)&As[wo * 32 + 16 + lr][lg * 8];
#pragma unroll
    for (int tj = 0; tj < 4; ++tj) {
      int nn = wn * 64 + tj * 16 + lr;
      float4 btmp;
      btmp.x = *(const float*)&Bs[lg * 4 + 0][nn];
      btmp.y = *(const float*)&Bs[lg * 4 + 1][nn];
      btmp.z = *(const float*)&Bs[lg * 4 + 2][nn];
      btmp.w = *(const float*)&Bs[lg * 4 + 3][nn];
      f16x8 bfr = __builtin_bit_cast(f16x8, btmp);
      acc[0][tj] = __builtin_amdgcn_mfma_f32_16x16x32_f16(afr0, bfr, acc[0][tj], 0, 0, 0);
      acc[1][tj] = __builtin_amdgcn_mfma_f32_16x16x32_f16(afr1, bfr, acc[1][tj], 0, 0, 0);
    }
  }
  // epilogue: lane holds D[row=lg*4+r][col=lr] per tile
#pragma unroll
  for (int ti = 0; ti < 2; ++ti) {
#pragma unroll
    for (int tj = 0; tj < 4; ++tj) {
      int nn = n0 + wn * 64 + tj * 16 + lr;
#pragma unroll
      for (int r = 0; r < 4; ++r) {
        int lrow = wo * 32 + ti * 16 + lg * 4 + r;
        size_t ob = (size_t)seg * segStride +
                    ((size_t)z * segCout + oo + lrow) * N + nn;
        float v = acc[ti][tj][r] + bias[o0 + lrow];
        if (res) v += res[ob];
        out[ob] = v;
      }
    }
  }
}

// ---------------------------------------------------------------- attention v9: 8 waves x 128 keys (71us verified)
__global__ __launch_bounds__(512) void k_attn(const float* __restrict__ Q,
                                              const float* __restrict__ Kt,
                                              const float* __restrict__ Vt,
                                              float* __restrict__ O) {
  __shared__ float pool[16896];
  __shared__ float ms_[8][64], ls_[8][64];
  half2v* pool2 = (half2v*)pool;
  const int t  = threadIdx.x;
  const int lq = t & 63, s = t >> 6;    // wave id 0..7
  const int q0 = blockIdx.x * 128;
  const int h  = blockIdx.y;
  const int z  = blockIdx.z;
  const size_t base = (size_t)z * (size_t)(D * N);
  const float* Kb = Kt + base;
  const float* Vb = Vt + base;
  const int sb2 = s * 1024;
  const int kg  = lq & 7;
  const int dp  = lq >> 3;

  const float scale = 0.17677669529663687f;
  half2v qpA[16], qpB[16];
  float accA[32], accB[32];
#pragma unroll
  for (int dd = 0; dd < 16; ++dd) {
    float a0 = Q[base + (size_t)((2 * dd) * 4 + h) * N + q0 + lq] * scale;
    float a1 = Q[base + (size_t)((2 * dd + 1) * 4 + h) * N + q0 + lq] * scale;
    qpA[dd] = pkrtz(a0, a1);
    float b0 = Q[base + (size_t)((2 * dd) * 4 + h) * N + q0 + 64 + lq] * scale;
    float b1 = Q[base + (size_t)((2 * dd + 1) * 4 + h) * N + q0 + 64 + lq] * scale;
    qpB[dd] = pkrtz(b0, b1);
  }
#pragma unroll
  for (int d = 0; d < 32; ++d) { accA[d] = 0.f; accB[d] = 0.f; }
  float mxA = -1e30f, mxB = -1e30f, lA = 0.f, lB = 0.f;

  for (int c = 0; c < 4; ++c) {
    const int k0 = s * 128 + c * 32;
#pragma unroll
    for (int rep = 0; rep < 2; ++rep) {
      int dd = dp + rep * 8;
      const float4 va = *(const float4*)(Kb + (size_t)((2 * dd) * 4 + h) * N + k0 + kg * 4);
      const float4 vb = *(const float4*)(Kb + (size_t)((2 * dd + 1) * 4 + h) * N + k0 + kg * 4);
      pool2[sb2 + (kg * 4 + 0) * 16 + dd] = pkrtz(va.x, vb.x);
      pool2[sb2 + (kg * 4 + 1) * 16 + dd] = pkrtz(va.y, vb.y);
      pool2[sb2 + (kg * 4 + 2) * 16 + dd] = pkrtz(va.z, vb.z);
      pool2[sb2 + (kg * 4 + 3) * 16 + dd] = pkrtz(va.w, vb.w);
    }
#pragma unroll
    for (int rep = 0; rep < 4; ++rep) {
      int d = dp + rep * 8;
      const float4 vv = *(const float4*)(Vb + (size_t)(d * 4 + h) * N + k0 + kg * 4);
      int idx = sb2 + 512 + d * 16 + kg * 2;
      pool2[idx]     = pkrtz(vv.x, vv.y);
      pool2[idx + 1] = pkrtz(vv.z, vv.w);
    }
#pragma unroll
    for (int st = 0; st < 4; ++st) {
      float scA[8], scB[8];
#pragma unroll
      for (int jj = 0; jj < 8; ++jj) {
        const int rb = sb2 + (st * 8 + jj) * 16;
        float a = 0.f, bq = 0.f;
#pragma unroll
        for (int r = 0; r < 4; ++r) {
          float4 raw = *(const float4*)&pool2[rb + r * 4];
          half2v k0h = __builtin_bit_cast(half2v, raw.x);
          half2v k1h = __builtin_bit_cast(half2v, raw.y);
          half2v k2h = __builtin_bit_cast(half2v, raw.z);
          half2v k3h = __builtin_bit_cast(half2v, raw.w);
          a  = __builtin_amdgcn_fdot2(k0h, qpA[r * 4 + 0], a,  false);
          a  = __builtin_amdgcn_fdot2(k1h, qpA[r * 4 + 1], a,  false);
          a  = __builtin_amdgcn_fdot2(k2h, qpA[r * 4 + 2], a,  false);
          a  = __builtin_amdgcn_fdot2(k3h, qpA[r * 4 + 3], a,  false);
          bq = __builtin_amdgcn_fdot2(k0h, qpB[r * 4 + 0], bq, false);
          bq = __builtin_amdgcn_fdot2(k1h, qpB[r * 4 + 1], bq, false);
          bq = __builtin_amdgcn_fdot2(k2h, qpB[r * 4 + 2], bq, false);
          bq = __builtin_amdgcn_fdot2(k3h, qpB[r * 4 + 3], bq, false);
        }
        scA[jj] = a; scB[jj] = bq;
      }
      float hA = scA[0], hB = scB[0];
#pragma unroll
      for (int j = 1; j < 8; ++j) { hA = fmaxf(hA, scA[j]); hB = fmaxf(hB, scB[j]); }
      float nmA = fmaxf(mxA, hA), nmB = fmaxf(mxB, hB);
      float cA = __expf(mxA - nmA), cB = __expf(mxB - nmB);
      lA *= cA; lB *= cB;
#pragma unroll
      for (int d = 0; d < 32; ++d) { accA[d] *= cA; accB[d] *= cB; }
      mxA = nmA; mxB = nmB;
#pragma unroll
      for (int j = 0; j < 8; ++j) {
        scA[j] = __expf(scA[j] - mxA); lA += scA[j];
        scB[j] = __expf(scB[j] - mxB); lB += scB[j];
      }
      half2v pA2[4], pB2[4];
#pragma unroll
      for (int u = 0; u < 4; ++u) {
        pA2[u] = pkrtz(scA[2 * u], scA[2 * u + 1]);
        pB2[u] = pkrtz(scB[2 * u], scB[2 * u + 1]);
      }
#pragma unroll
      for (int d = 0; d < 32; ++d) {
        float4 raw = *(const float4*)&pool2[sb2 + 512 + d * 16 + st * 4];
        half2v v0 = __builtin_bit_cast(half2v, raw.x);
        half2v v1 = __builtin_bit_cast(half2v, raw.y);
        half2v v2 = __builtin_bit_cast(half2v, raw.z);
        half2v v3 = __builtin_bit_cast(half2v, raw.w);
        float aa = accA[d];
        aa = __builtin_amdgcn_fdot2(v0, pA2[0], aa, false);
        aa = __builtin_amdgcn_fdot2(v1, pA2[1], aa, false);
        aa = __builtin_amdgcn_fdot2(v2, pA2[2], aa, false);
        aa = __builtin_amdgcn_fdot2(v3, pA2[3], aa, false);
        accA[d] = aa;
        float bb = accB[d];
        bb = __builtin_amdgcn_fdot2(v0, pB2[0], bb, false);
        bb = __builtin_amdgcn_fdot2(v1, pB2[1], bb, false);
        bb = __builtin_amdgcn_fdot2(v2, pB2[2], bb, false);
        bb = __builtin_amdgcn_fdot2(v3, pB2[3], bb, false);
        accB[d] = bb;
      }
    }
  }

#pragma unroll
  for (int rr = 0; rr < 2; ++rr) {
    __syncthreads();
    ms_[s][lq] = rr ? mxB : mxA;
    ls_[s][lq] = rr ? lB  : lA;
#pragma unroll
    for (int d = 0; d < 32; ++d)
      pool[(s * 64 + lq) * 33 + d] = rr ? accB[d] : accA[d];
    __syncthreads();
    {
      int qq = t & 63, dg = t >> 6;
      float M = ms_[0][qq];
#pragma unroll
      for (int ss = 1; ss < 8; ++ss) M = fmaxf(M, ms_[ss][qq]);
      float wg[8], L = 0.f;
#pragma unroll
      for (int ss = 0; ss < 8; ++ss) {
        wg[ss] = __expf(ms_[ss][qq] - M);
        L += ls_[ss][qq] * wg[ss];
      }
      float invL = 1.f / L;
#pragma unroll
      for (int k = 0; k < 4; ++k) {
        int d = dg * 4 + k;
        float o = 0.f;
#pragma unroll
        for (int ss = 0; ss < 8; ++ss) o += pool[(ss * 64 + qq) * 33 + d] * wg[ss];
        O[base + (size_t)(d * 4 + h) * N + q0 + rr * 64 + qq] = o * invL;
      }
    }
  }
}

// ---------------------------------------------------------------- BN stats (single pass)
__global__ __launch_bounds__(256) void k_bnstat(const float* __restrict__ h,
                                                float* __restrict__ stat) {
  int c = blockIdx.x, s = blockIdx.y, t = threadIdx.x;
  __shared__ float red[256], red2[256];
  const float* base = h + ((size_t)s * B * 256 + c) * N;
  float sum = 0, sq = 0;
  for (int b = 0; b < B; ++b)
    for (int i = t; i < N; i += 256) {
      float v = base[(size_t)b * 256 * N + i];
      sum += v; sq = fmaf(v, v, sq);
    }
  red[t] = sum; red2[t] = sq; __syncthreads();
  for (int sft = 128; sft > 0; sft >>= 1) {
    if (t < sft) { red[t] += red[t + sft]; red2[t] += red2[t + sft]; }
    __syncthreads();
  }
  if (t == 0) {
    float mean = red[0] / (float)(B * N);
    float var = fmaxf(red2[0] / (float)(B * N) - mean * mean, 0.f);
    stat[(s * 256 + c) * 2 + 0] = mean;
    stat[(s * 256 + c) * 2 + 1] = 1.f / sqrtf(var + 1e-5f);
  }
}

// ---------------------------------------------------------------- pairwise dist (8-m tile)
__global__ __launch_bounds__(256) void k_dist(const float* __restrict__ d0,
                                              const float* __restrict__ d1,
                                              float* __restrict__ la) {
  __shared__ float xm[8][128];
  __shared__ float n0s[8];
  int m0 = blockIdx.x * 8, b = blockIdx.y, t = threadIdx.x;
  const float* p0 = d0 + (size_t)b * D * N;
  const float* p1 = d1 + (size_t)b * D * N;
  for (int i = t; i < 8 * 128; i += 256) {
    int mm = i >> 7, d = i & 127;
    xm[mm][d] = p0[(size_t)d * N + m0 + mm];
  }
  __syncthreads();
  if (t < 8) {
    float s = 0;
    for (int d = 0; d < 128; ++d) s += xm[t][d] * xm[t][d];
    n0s[t] = s;
  }
  __syncthreads();
  float dot[8][4] = {{0}};
  float n1[4] = {0, 0, 0, 0};
  for (int d = 0; d < 128; ++d) {
    float v[4];
#pragma unroll
    for (int u = 0; u < 4; ++u) {
      v[u] = p1[(size_t)d * N + t + u * 256];
      n1[u] = fmaf(v[u], v[u], n1[u]);
    }
#pragma unroll
    for (int mm = 0; mm < 8; ++mm) {
      float x = xm[mm][d];
#pragma unroll
      for (int u = 0; u < 4; ++u) dot[mm][u] = fmaf(x, v[u], dot[mm][u]);
    }
  }
  for (int mm = 0; mm < 8; ++mm) {
    float* row = la + ((size_t)b * N + m0 + mm) * N;
#pragma unroll
    for (int u = 0; u < 4; ++u) {
      float dist2 = fmaxf(n0s[mm] + n1[u] - 2.f * dot[mm][u], 1e-30f);
      row[t + u * 256] = -sqrtf(dist2);
    }
  }
}

// ---------------------------------------------------------------- sinkhorn offset form
__global__ __launch_bounds__(256) void k_row_r(const float* __restrict__ l0,
                                               const float* __restrict__ cvec,
                                               float* __restrict__ r,
                                               int useC) {
  __shared__ float red[256];
  int t = threadIdx.x;
  int bm = blockIdx.x;              // over B*N
  int b = bm >> 10;
  const float* row = l0 + (size_t)bm * N;
  float v0 = row[t], v1 = row[t + 256], v2 = row[t + 512], v3 = row[t + 768];
  if (useC) {
    const float* cl = cvec + (size_t)b * N;
    v0 -= cl[t]; v1 -= cl[t + 256]; v2 -= cl[t + 512]; v3 -= cl[t + 768];
  }
  float mx = fmaxf(fmaxf(v0, v1), fmaxf(v2, v3));
  red[t] = mx; __syncthreads();
  for (int s = 128; s > 0; s >>= 1) {
    if (t < s) red[t] = fmaxf(red[t], red[t + s]);
    __syncthreads();
  }
  mx = red[0]; __syncthreads();
  float se = __expf(v0 - mx) + __expf(v1 - mx) + __expf(v2 - mx) + __expf(v3 - mx);
  red[t] = se; __syncthreads();
  for (int s = 128; s > 0; s >>= 1) {
    if (t < s) red[t] += red[t + s];
    __syncthreads();
  }
  if (t == 0) r[bm] = mx + __logf(red[0]);
}

__global__ __launch_bounds__(256) void k_col_part(const float* __restrict__ l0,
                                                  const float* __restrict__ r,
                                                  float* __restrict__ pmax,
                                                  float* __restrict__ psum) {
  int t = threadIdx.x;
  int n = blockIdx.x * 256 + t;
  int p = blockIdx.y, b = blockIdx.z;
  const float* base = l0 + ((size_t)b * N + p * 32) * N + n;
  const float* rr = r + (size_t)b * N + p * 32;
  float mx = -1e30f, s = 0;
  for (int m = 0; m < 32; ++m) {
    float v = base[(size_t)m * N] - rr[m];
    if (v > mx) { s = s * __expf(mx - v) + 1.f; mx = v; }
    else s += __expf(v - mx);
  }
  pmax[((size_t)b * 32 + p) * N + n] = mx;
  psum[((size_t)b * 32 + p) * N + n] = s;
}

__global__ __launch_bounds__(256) void k_col_fin(const float* __restrict__ pmax,
                                                 const float* __restrict__ psum,
                                                 float* __restrict__ cvec) {
  int i = blockIdx.x * 256 + threadIdx.x;  // over B*N
  int b = i / N, n = i % N;
  float mx = -1e30f;
#pragma unroll
  for (int p = 0; p < 32; ++p) mx = fmaxf(mx, pmax[((size_t)b * 32 + p) * N + n]);
  float s = 0;
#pragma unroll
  for (int p = 0; p < 32; ++p)
    s += psum[((size_t)b * 32 + p) * N + n] * __expf(pmax[((size_t)b * 32 + p) * N + n] - mx);
  cvec[i] = mx + __logf(s);
}

// ---------------------------------------------------------------- rodrigues + transform
__global__ __launch_bounds__(256) void k_rod(const float* __restrict__ pose,
                                             const float* __restrict__ p3d,
                                             float* __restrict__ p3dt) {
  int b = blockIdx.y;
  int n = blockIdx.x * 256 + threadIdx.x;
  const float* aa = pose + b * 6;
  float ax = aa[0], ay = aa[1], az = aa[2];
  float th = fmaxf(sqrtf(ax * ax + ay * ay + az * az), 1e-8f);
  float rx = ax / th, ry = ay / th, rz = az / th;
  float c = cosf(th), s = sinf(th), oc = 1.f - c;
  float R00 = c + oc * rx * rx,      R01 = oc * rx * ry - s * rz, R02 = oc * rx * rz + s * ry;
  float R10 = oc * ry * rx + s * rz, R11 = c + oc * ry * ry,      R12 = oc * ry * rz - s * rx;
  float R20 = oc * rz * rx - s * ry, R21 = oc * rz * ry + s * rx, R22 = c + oc * rz * rz;
  const float* p = p3d + ((size_t)b * N + n) * 3;
  float x = p[0], y = p[1], z = p[2];
  float X = R00 * x + R01 * y + R02 * z + aa[3];
  float Y = R10 * x + R11 * y + R12 * z + aa[4];
  float Z = R20 * x + R21 * y + R22 * z + aa[5];
  float inr = 1.f / sqrtf(X * X + Y * Y + Z * Z);
  float* o = p3dt + ((size_t)b * N + n) * 3;
  o[0] = X * inr; o[1] = Y * inr; o[2] = Z * inr;
}

// ---------------------------------------------------------------- final error (applies r,c offsets)
__global__ __launch_bounds__(256) void k_err(const float* __restrict__ l0,
                                             const float* __restrict__ r,
                                             const float* __restrict__ cvec,
                                             const float* __restrict__ f2,
                                             const float* __restrict__ p3dt,
                                             float* __restrict__ rowsum) {
  __shared__ float red[256];
  int m = blockIdx.x, b = blockIdx.y, t = threadIdx.x;
  const float* row = l0 + ((size_t)b * N + m) * N;
  const float* cl = cvec + (size_t)b * N;
  const float rm = r[(size_t)b * N + m];
  const float* f = f2 + ((size_t)b * N + m) * 3;
  float fx = f[0], fy = f[1], fz = f[2];
  float s = 0;
  for (int n = t; n < N; n += 256) {
    const float* pp = p3dt + ((size_t)b * N + n) * 3;
    float dot = fx * pp[0] + fy * pp[1] + fz * pp[2];
    s += __expf(row[n] - rm - cl[n]) * (1.f - dot);
  }
  red[t] = s; __syncthreads();
  for (int sft = 128; sft > 0; sft >>= 1) {
    if (t < sft) red[t] += red[t + sft];
    __syncthreads();
  }
  if (t == 0) rowsum[(size_t)b * N + m] = red[0];
}

__global__ __launch_bounds__(256) void k_err_fin(const float* __restrict__ rowsum,
                                                 float* __restrict__ out) {
  __shared__ float red[256];
  int b = blockIdx.x, t = threadIdx.x;
  float s = 0;
  for (int i = t; i < N; i += 256) s += rowsum[(size_t)b * N + i];
  red[t] = s; __syncthreads();
  for (int sft = 128; sft > 0; sft >>= 1) {
    if (t < sft) red[t] += red[t + sft];
    __syncthreads();
  }
  if (t == 0) out[b] = red[0];
}

// ================================================================= host
extern "C" void kernel_launch(void* const* d_in, const int* in_sizes, int n_in,
                              void* d_out, int out_size, void* d_ws, size_t ws_size,
                              hipStream_t stream) {
  const float* p2d     = (const float*)d_in[0];
  const float* p3d     = (const float*)d_in[1];
  const float* pose    = (const float*)d_in[2];
  const float* enc2d_w = (const float*)d_in[3];
  const float* enc2d_b = (const float*)d_in[4];
  const float* enc3d_w = (const float*)d_in[5];
  const float* enc3d_b = (const float*)d_in[6];
  const float* proj_w  = (const float*)d_in[7];
  const float* proj_b  = (const float*)d_in[8];
  const float* merge_w = (const float*)d_in[9];
  const float* merge_b = (const float*)d_in[10];
  const float* mlp1_w  = (const float*)d_in[11];
  const float* mlp1_b  = (const float*)d_in[12];
  const float* bn_g    = (const float*)d_in[13];
  const float* bn_b    = (const float*)d_in[14];
  const float* mlp2_w  = (const float*)d_in[15];
  const float* mlp2_b  = (const float*)d_in[16];

  float* W = (float*)d_ws;
  size_t off = 0;
  auto alloc = [&](size_t nelem) { float* p = W + off; off += nelem; return p; };
  const size_t SET = (size_t)B * D * N;
  float* f2    = alloc((size_t)B * N * 3);
  float* p3dt  = alloc((size_t)B * N * 3);
  float* descA = alloc(2 * SET);
  float* descB = alloc(2 * SET);
  float* qkv   = alloc(3 * 2 * SET);
  float* attnb = alloc(2 * SET);
  float* msgb  = alloc(2 * SET);
  float* hb    = alloc((size_t)2 * B * 256 * N);
  float* stat  = alloc(2 * 256 * 2);
  float* la    = alloc((size_t)B * N * N);
  float* pmax  = alloc((size_t)B * 32 * N);
  float* psum  = alloc((size_t)B * 32 * N);
  float* cvec  = alloc((size_t)B * N);
  float* rvec  = alloc((size_t)B * N);
  float* rowsum= alloc((size_t)B * N);
  (void)ws_size; (void)in_sizes; (void)n_in; (void)out_size;

  float* Qb = qkv;
  float* Kb = qkv + 2 * SET;
  float* Vb = qkv + 4 * SET;
  const size_t DS = (size_t)D * N;

  k_norm2d<<<(B * N) / 256, 256, 0, stream>>>(p2d, f2);
  k_encode<<<dim3(N, B), 256, 0, stream>>>(f2, enc2d_w, enc2d_b, descA);
  k_encode<<<dim3(N, B), 256, 0, stream>>>(p3d, enc3d_w, enc3d_b, descA + SET);

  float* dc = descA;
  float* dn = descB;
  for (int i = 0; i < 6; ++i) {
    int cross = (i & 1);
    const float* pw = proj_w + (size_t)i * 3 * D * D;
    const float* pb = proj_b + (size_t)i * 3 * D;
    float* d0 = dc;
    float* d1 = dc + SET;
    const float* sA = cross ? d1 : d0;
    const float* sB = cross ? d0 : d1;

    k_gemm<<<dim3(64, 6), 256, 0, stream>>>(
        d0, d1, sA, sB, pw, pb, nullptr, qkv, nullptr, nullptr, nullptr,
        D, D, DS, DS, D, 2 * SET, 1);
    k_attn<<<dim3(N / 128, NH, 2 * B), 512, 0, stream>>>(Qb, Kb, Vb, attnb);
    k_gemm<<<dim3(64, 2), 256, 0, stream>>>(
        attnb, attnb + SET, nullptr, nullptr, merge_w + (size_t)i * D * D,
        merge_b + (size_t)i * D, nullptr, msgb, nullptr, nullptr, nullptr,
        D, D, DS, DS, D, 0, 0);
    k_gemm<<<dim3(64, 4), 256, 0, stream>>>(
        dc, dc + SET, msgb, msgb + SET, mlp1_w + (size_t)i * 256 * 256,
        mlp1_b + (size_t)i * 256, nullptr, hb, nullptr, nullptr, nullptr,
        256, 128, DS, DS, 256, 0, 0);
    k_bnstat<<<dim3(256, 2), 256, 0, stream>>>(hb, stat);
    k_gemm<<<dim3(64, 2), 256, 0, stream>>>(
        hb, hb + (size_t)B * 256 * N, nullptr, nullptr,
        mlp2_w + (size_t)i * D * 256, mlp2_b + (size_t)i * D, dc, dn,
        stat, bn_g + (size_t)i * 256, bn_b + (size_t)i * 256,
        256, 256, (size_t)256 * N, 0, D, 0, 0);
    float* tmp = dc; dc = dn; dn = tmp;
  }

  k_dist<<<dim3(N / 8, B), 256, 0, stream>>>(dc, dc + SET, la);
  for (int it = 0; it < 10; ++it) {
    k_row_r<<<B * N, 256, 0, stream>>>(la, cvec, rvec, it > 0 ? 1 : 0);
    k_col_part<<<dim3(N / 256, 32, B), 256, 0, stream>>>(la, rvec, pmax, psum);
    k_col_fin<<<(B * N) / 256, 256, 0, stream>>>(pmax, psum, cvec);
  }
  k_rod<<<dim3(N / 256, B), 256, 0, stream>>>(pose, p3d, p3dt);
  k_err<<<dim3(N, B), 256, 0, stream>>>(la, rvec, cvec, f2, p3dt, rowsum);
  k_err_fin<<<B, 256, 0, stream>>>(rowsum, (float*)d_out);
}

// Round 16
// 938.267 us; speedup vs baseline: 2.0356x; 1.1971x over previous
//
#include <hip/hip_runtime.h>
#include <hip/hip_bf16.h>

constexpr int B   = 4;
constexpr int N   = 1024;
constexpr int D   = 128;
constexpr int KNN = 10;
constexpr int NH  = 4;

typedef _Float16 half2v __attribute__((ext_vector_type(2)));
typedef _Float16 f16x4  __attribute__((ext_vector_type(4)));
typedef _Float16 f16x8  __attribute__((ext_vector_type(8)));
typedef float    f32x4  __attribute__((ext_vector_type(4)));

static __device__ __forceinline__ half2v pkrtz(float a, float b) {
  return __builtin_bit_cast(half2v, __builtin_amdgcn_cvt_pkrtz(a, b));
}
static __device__ __forceinline__ float h2f(half2v h) {
  return __builtin_bit_cast(float, h);
}

// ---------------------------------------------------------------- norm p2d
__global__ __launch_bounds__(256) void k_norm2d(const float* __restrict__ p2d,
                                                float* __restrict__ f2) {
  int i = blockIdx.x * 256 + threadIdx.x;  // over B*N
  const float* p = p2d + (size_t)i * 3;
  float x = p[0], y = p[1], z = p[2];
  float inr = 1.f / sqrtf(x * x + y * y + z * z);
  float* o = f2 + (size_t)i * 3;
  o[0] = x * inr; o[1] = y * inr; o[2] = z * inr;
}

// ---------------------------------------------------------------- KNN encode
__global__ __launch_bounds__(256) void k_encode(const float* __restrict__ pts,
                                                const float* __restrict__ w,
                                                const float* __restrict__ bias,
                                                float* __restrict__ desc) {
  __shared__ float P[N][3];
  __shared__ float xx[N];
  __shared__ float dist[N];
  __shared__ float rv[256];
  __shared__ int   ri[256];
  __shared__ float feat[6];
  __shared__ int   nidx[KNN];
  int t = threadIdx.x;
  int n = blockIdx.x, b = blockIdx.y;
  const float* pb = pts + (size_t)b * N * 3;
  for (int i = t; i < N; i += 256) {
    float x = pb[i * 3 + 0], y = pb[i * 3 + 1], z = pb[i * 3 + 2];
    P[i][0] = x; P[i][1] = y; P[i][2] = z;
    xx[i] = x * x + y * y + z * z;
  }
  __syncthreads();
  float cx = P[n][0], cy = P[n][1], cz = P[n][2], cxx = xx[n];
  for (int i = t; i < N; i += 256) {
    float ip = cx * P[i][0] + cy * P[i][1] + cz * P[i][2];
    dist[i] = 2.f * ip - cxx - xx[i];
  }
  __syncthreads();
  for (int kk = 0; kk < KNN; ++kk) {
    float bv = -3.0e38f; int bi = N;
    for (int i = t; i < N; i += 256) {
      float v = dist[i];
      if (v > bv) { bv = v; bi = i; }
    }
    rv[t] = bv; ri[t] = bi;
    __syncthreads();
    for (int s = 128; s > 0; s >>= 1) {
      if (t < s) {
        float v2 = rv[t + s]; int i2 = ri[t + s];
        if (v2 > rv[t] || (v2 == rv[t] && i2 < ri[t])) { rv[t] = v2; ri[t] = i2; }
      }
      __syncthreads();
    }
    if (t == 0) { nidx[kk] = ri[0]; dist[ri[0]] = -3.0e38f; }
    __syncthreads();
  }
  if (t == 0) {
    float sx = 0, sy = 0, sz = 0;
    for (int kk = 0; kk < KNN; ++kk) {
      int i = nidx[kk];
      sx += P[i][0]; sy += P[i][1]; sz += P[i][2];
    }
    const float invk = 1.f / KNN;
    feat[0] = sx * invk - cx; feat[1] = sy * invk - cy; feat[2] = sz * invk - cz;
    feat[3] = cx; feat[4] = cy; feat[5] = cz;
  }
  __syncthreads();
  if (t < D) {
    const float* wr = w + t * 6;
    float a = bias[t];
#pragma unroll
    for (int j = 0; j < 6; ++j) a += wr[j] * feat[j];
    desc[((size_t)b * D + t) * N + n] = a;
  }
}

// ---------------------------------------------------------------- tiled GEMM conv v3: MFMA f16 (R15, validated)
__global__ __launch_bounds__(256) void k_gemm(
    const float* __restrict__ pA0, const float* __restrict__ pA1,
    const float* __restrict__ pB0, const float* __restrict__ pB1,
    const float* __restrict__ w, const float* __restrict__ bias,
    const float* __restrict__ res, float* __restrict__ out,
    const float* __restrict__ stat, const float* __restrict__ g,
    const float* __restrict__ bt,
    int Cin, int catOff, size_t a_bstr, size_t b_bstr,
    int segCout, size_t segStride, int qkvMode) {
  __shared__ _Float16 As[64][48];
  __shared__ half2v   Bs[16][132];
  __shared__ float Ac[256], Bc[256];
  const int tid = threadIdx.x;
  const int wv  = tid >> 6;
  const int l   = tid & 63;
  const int wo  = wv >> 1;
  const int wn  = wv & 1;
  const int lr  = l & 15;
  const int lg  = l >> 4;
  const int o0 = blockIdx.y * 64;
  const int zb = blockIdx.x;
  const int z  = zb >> 3;
  const int n0 = (zb & 7) * 128;
  const int s = z >> 2, b = z & 3;
  const int seg = o0 / segCout;
  const int oo  = o0 % segCout;

  const float* XA = (s ? pA1 : pA0) + (size_t)b * a_bstr;
  const float* XB = pB0 ? ((s ? pB1 : pB0) + (size_t)b * b_bstr) : nullptr;
  const bool segB = qkvMode && (seg > 0);

  if (stat) {
    const float* st = stat + (size_t)s * 256 * 2;
    float A = st[tid * 2 + 1] * g[tid];
    Ac[tid] = A;
    Bc[tid] = fmaf(-st[tid * 2 + 0], A, bt[tid]);
  }

  f32x4 acc[2][4];
#pragma unroll
  for (int i = 0; i < 2; ++i)
#pragma unroll
    for (int j = 0; j < 4; ++j) acc[i][j] = (f32x4){0.f, 0.f, 0.f, 0.f};

  for (int kb = 0; kb < Cin; kb += 32) {
    __syncthreads();
#pragma unroll
    for (int j = 0; j < 2; ++j) {
      int idx = j * 256 + tid;
      int o = idx >> 3, c4 = (idx & 7) * 4;
      float4 wvv = *(const float4*)&w[(size_t)(o0 + o) * Cin + kb + c4];
      *(half2v*)&As[o][c4]     = pkrtz(wvv.x, wvv.y);
      *(half2v*)&As[o][c4 + 2] = pkrtz(wvv.z, wvv.w);
    }
#pragma unroll
    for (int j = 0; j < 2; ++j) {
      int idx = j * 256 + tid;
      int rp = idx >> 5, c4 = (idx & 31) * 4;
      int c0 = kb + 2 * rp, c1 = c0 + 1;
      const float* s0; int cc0 = c0;
      const float* s1; int cc1 = c1;
      if (qkvMode) {
        s0 = segB ? XB : XA; s1 = s0;
      } else {
        if (c0 >= catOff) { s0 = XB; cc0 = c0 - catOff; } else s0 = XA;
        if (c1 >= catOff) { s1 = XB; cc1 = c1 - catOff; } else s1 = XA;
      }
      float4 v0 = *(const float4*)&s0[(size_t)cc0 * N + n0 + c4];
      float4 v1 = *(const float4*)&s1[(size_t)cc1 * N + n0 + c4];
      if (stat) {
        float A0 = Ac[c0], B0 = Bc[c0], A1 = Ac[c1], B1 = Bc[c1];
        v0.x = fmaxf(fmaf(v0.x, A0, B0), 0.f);
        v0.y = fmaxf(fmaf(v0.y, A0, B0), 0.f);
        v0.z = fmaxf(fmaf(v0.z, A0, B0), 0.f);
        v0.w = fmaxf(fmaf(v0.w, A0, B0), 0.f);
        v1.x = fmaxf(fmaf(v1.x, A1, B1), 0.f);
        v1.y = fmaxf(fmaf(v1.y, A1, B1), 0.f);
        v1.z = fmaxf(fmaf(v1.z, A1, B1), 0.f);
        v1.w = fmaxf(fmaf(v1.w, A1, B1), 0.f);
      }
      float4 packed;
      packed.x = h2f(pkrtz(v0.x, v1.x));
      packed.y = h2f(pkrtz(v0.y, v1.y));
      packed.z = h2f(pkrtz(v0.z, v1.z));
      packed.w = h2f(pkrtz(v0.w, v1.w));
      *(float4*)&Bs[rp][c4] = packed;
    }
    __syncthreads();
    f16x8 afr0 = *(const f16x8*)&As[wo * 32 + lr][lg * 8];
    f16x8 afr1 = *(const f16x8*)&As[wo * 32 + 16 + lr][lg * 8];
#pragma unroll
    for (int tj = 0; tj < 4; ++tj) {
      int nn = wn * 64 + tj * 16 + lr;
      float4 btmp;
      btmp.x = *(const float*)&Bs[lg * 4 + 0][nn];
      btmp.y = *(const float*)&Bs[lg * 4 + 1][nn];
      btmp.z = *(const float*)&Bs[lg * 4 + 2][nn];
      btmp.w = *(const float*)&Bs[lg * 4 + 3][nn];
      f16x8 bfr = __builtin_bit_cast(f16x8, btmp);
      acc[0][tj] = __builtin_amdgcn_mfma_f32_16x16x32_f16(afr0, bfr, acc[0][tj], 0, 0, 0);
      acc[1][tj] = __builtin_amdgcn_mfma_f32_16x16x32_f16(afr1, bfr, acc[1][tj], 0, 0, 0);
    }
  }
#pragma unroll
  for (int ti = 0; ti < 2; ++ti) {
#pragma unroll
    for (int tj = 0; tj < 4; ++tj) {
      int nn = n0 + wn * 64 + tj * 16 + lr;
#pragma unroll
      for (int r = 0; r < 4; ++r) {
        int lrow = wo * 32 + ti * 16 + lg * 4 + r;
        size_t ob = (size_t)seg * segStride +
                    ((size_t)z * segCout + oo + lrow) * N + nn;
        float v = acc[ti][tj][r] + bias[o0 + lrow];
        if (res) v += res[ob];
        out[ob] = v;
      }
    }
  }
}

// ---------------------------------------------------------------- attention v10: MFMA flash
// grid (N/128, NH, 2*B) = 256 blocks, 512 thr = 8 waves. Q-SPLIT: wave w owns
// 16 queries (q0=blk*128+w*16) and loops ALL 1024 keys; no merge phase.
// head_dim=32 == MFMA K: S^T[16k][16q] = one mfma_f32_16x16x32_f16(K_frag,
// Q_frag). Q-frag loop-invariant in regs. C-layout (m89): lane holds
// S^T[k=(l>>4)*4+r][q=l&15] -> per-q reduce = 2 shfl_xor(16,32). PV via
// mfma_f32_16x16x16f16: P^T's C-layout IS the B-frag layout (slot j=reg r);
// V^T A-frag = b64 from V_lds[d][k]. k-permutation cancels (A,B share map).
// LDS 19KB (K[128][40] + V[32][136] f16), 2 barriers/chunk of 128 keys.
__global__ __launch_bounds__(512) void k_attn(const float* __restrict__ Q,
                                              const float* __restrict__ Kt,
                                              const float* __restrict__ Vt,
                                              float* __restrict__ O) {
  __shared__ _Float16 Klds[128][40];   // [key][d], 80B rows (16B-aligned)
  __shared__ _Float16 Vlds[32][136];   // [d][key], 272B rows
  const int t  = threadIdx.x;
  const int l  = t & 63, w = t >> 6;   // wave 0..7
  const int lr = l & 15, lg = l >> 4;
  const int q0 = blockIdx.x * 128 + w * 16;
  const int h  = blockIdx.y;
  const int z  = blockIdx.z;
  const size_t base = (size_t)z * (size_t)(D * N);
  const float* Kg = Kt + base + (size_t)h * N;   // + d*4*N
  const float* Vg = Vt + base + (size_t)h * N;
  const float scale = 0.17677669529663687f;      // 1/sqrt(32) folded into Q

  // Q-frag (B operand of 16x16x32): slot j = Q[d=lg*8+j][q0+lr]
  f16x8 qfrag;
  {
    float qv[8];
#pragma unroll
    for (int j = 0; j < 8; ++j)
      qv[j] = Q[base + (size_t)((lg * 8 + j) * 4 + h) * N + q0 + lr] * scale;
    float4 qp;
    qp.x = h2f(pkrtz(qv[0], qv[1]));
    qp.y = h2f(pkrtz(qv[2], qv[3]));
    qp.z = h2f(pkrtz(qv[4], qv[5]));
    qp.w = h2f(pkrtz(qv[6], qv[7]));
    qfrag = __builtin_bit_cast(f16x8, qp);
  }

  f32x4 oacc0 = (f32x4){0.f, 0.f, 0.f, 0.f};
  f32x4 oacc1 = (f32x4){0.f, 0.f, 0.f, 0.f};
  float m = -1e30f, lsum = 0.f;

  for (int c = 0; c < 8; ++c) {
    const int k0 = c * 128;
    __syncthreads();
    // ---- stage K chunk: Klds[kk][d] f16. thread: kk=t&127, d-octet=(t>>7)*8
    {
      int kk = t & 127, d0 = (t >> 7) * 8;
      float kv[8];
#pragma unroll
      for (int j = 0; j < 8; ++j)
        kv[j] = Kg[(size_t)((d0 + j) * 4) * N + k0 + kk];
      float4 pk;
      pk.x = h2f(pkrtz(kv[0], kv[1]));
      pk.y = h2f(pkrtz(kv[2], kv[3]));
      pk.z = h2f(pkrtz(kv[4], kv[5]));
      pk.w = h2f(pkrtz(kv[6], kv[7]));
      *(float4*)&Klds[kk][d0] = pk;
      // ---- stage V chunk: Vlds[d][kk] f16. thread: d=t&31, k-octet=(t>>5)*8
      int dv = t & 31, ko = (t >> 5) * 8;
      const float* vp = Vg + (size_t)(dv * 4) * N + k0 + ko;
      float4 v0 = *(const float4*)vp;
      float4 v1 = *(const float4*)(vp + 4);
      float4 pv;
      pv.x = h2f(pkrtz(v0.x, v0.y)); pv.y = h2f(pkrtz(v0.z, v0.w));
      pv.z = h2f(pkrtz(v1.x, v1.y)); pv.w = h2f(pkrtz(v1.z, v1.w));
      *(float4*)&Vlds[dv][ko] = pv;
    }
    __syncthreads();
    // ---- 8 key-tiles of 16
#pragma unroll
    for (int kt = 0; kt < 8; ++kt) {
      f16x8 kfrag = *(const f16x8*)&Klds[kt * 16 + lr][lg * 8];
      f32x4 s = __builtin_amdgcn_mfma_f32_16x16x32_f16(
          kfrag, qfrag, (f32x4){0.f, 0.f, 0.f, 0.f}, 0, 0, 0);
      // per-query online softmax (q = lr; keys spread over regs+lanegroups)
      float tmax = fmaxf(fmaxf(s[0], s[1]), fmaxf(s[2], s[3]));
      tmax = fmaxf(tmax, __shfl_xor(tmax, 16, 64));
      tmax = fmaxf(tmax, __shfl_xor(tmax, 32, 64));
      float nm = fmaxf(m, tmax);
      float corr = __expf(m - nm);
      m = nm;
      lsum *= corr;
#pragma unroll
      for (int r = 0; r < 4; ++r) { oacc0[r] *= corr; oacc1[r] *= corr; }
      float p0 = __expf(s[0] - m), p1 = __expf(s[1] - m);
      float p2 = __expf(s[2] - m), p3 = __expf(s[3] - m);
      float ts = p0 + p1 + p2 + p3;
      ts += __shfl_xor(ts, 16, 64);
      ts += __shfl_xor(ts, 32, 64);
      lsum += ts;
      float2 ptmp;
      ptmp.x = h2f(pkrtz(p0, p1));
      ptmp.y = h2f(pkrtz(p2, p3));
      f16x4 pfrag = __builtin_bit_cast(f16x4, ptmp);
      // V^T A-frags (b64): lane = V[d=tile*16+lr][k0t + lg*4 + j]
      float2 vt0 = *(const float2*)&Vlds[lr][kt * 16 + lg * 4];
      float2 vt1 = *(const float2*)&Vlds[16 + lr][kt * 16 + lg * 4];
      f16x4 vf0 = __builtin_bit_cast(f16x4, vt0);
      f16x4 vf1 = __builtin_bit_cast(f16x4, vt1);
      oacc0 = __builtin_amdgcn_mfma_f32_16x16x16f16(vf0, pfrag, oacc0, 0, 0, 0);
      oacc1 = __builtin_amdgcn_mfma_f32_16x16x16f16(vf1, pfrag, oacc1, 0, 0, 0);
    }
  }
  // ---- epilogue: lane holds O^T[d=tile*16+lg*4+r][q=lr]
  float invL = 1.f / lsum;
#pragma unroll
  for (int r = 0; r < 4; ++r) {
    int d0 = lg * 4 + r;
    O[base + (size_t)(d0 * 4 + h) * N + q0 + lr] = oacc0[r] * invL;
    int d1 = 16 + lg * 4 + r;
    O[base + (size_t)(d1 * 4 + h) * N + q0 + lr] = oacc1[r] * invL;
  }
}

// ---------------------------------------------------------------- BN stats (single pass)
__global__ __launch_bounds__(256) void k_bnstat(const float* __restrict__ h,
                                                float* __restrict__ stat) {
  int c = blockIdx.x, s = blockIdx.y, t = threadIdx.x;
  __shared__ float red[256], red2[256];
  const float* base = h + ((size_t)s * B * 256 + c) * N;
  float sum = 0, sq = 0;
  for (int b = 0; b < B; ++b)
    for (int i = t; i < N; i += 256) {
      float v = base[(size_t)b * 256 * N + i];
      sum += v; sq = fmaf(v, v, sq);
    }
  red[t] = sum; red2[t] = sq; __syncthreads();
  for (int sft = 128; sft > 0; sft >>= 1) {
    if (t < sft) { red[t] += red[t + sft]; red2[t] += red2[t + sft]; }
    __syncthreads();
  }
  if (t == 0) {
    float mean = red[0] / (float)(B * N);
    float var = fmaxf(red2[0] / (float)(B * N) - mean * mean, 0.f);
    stat[(s * 256 + c) * 2 + 0] = mean;
    stat[(s * 256 + c) * 2 + 1] = 1.f / sqrtf(var + 1e-5f);
  }
}

// ---------------------------------------------------------------- pairwise dist (8-m tile)
__global__ __launch_bounds__(256) void k_dist(const float* __restrict__ d0,
                                              const float* __restrict__ d1,
                                              float* __restrict__ la) {
  __shared__ float xm[8][128];
  __shared__ float n0s[8];
  int m0 = blockIdx.x * 8, b = blockIdx.y, t = threadIdx.x;
  const float* p0 = d0 + (size_t)b * D * N;
  const float* p1 = d1 + (size_t)b * D * N;
  for (int i = t; i < 8 * 128; i += 256) {
    int mm = i >> 7, d = i & 127;
    xm[mm][d] = p0[(size_t)d * N + m0 + mm];
  }
  __syncthreads();
  if (t < 8) {
    float s = 0;
    for (int d = 0; d < 128; ++d) s += xm[t][d] * xm[t][d];
    n0s[t] = s;
  }
  __syncthreads();
  float dot[8][4] = {{0}};
  float n1[4] = {0, 0, 0, 0};
  for (int d = 0; d < 128; ++d) {
    float v[4];
#pragma unroll
    for (int u = 0; u < 4; ++u) {
      v[u] = p1[(size_t)d * N + t + u * 256];
      n1[u] = fmaf(v[u], v[u], n1[u]);
    }
#pragma unroll
    for (int mm = 0; mm < 8; ++mm) {
      float x = xm[mm][d];
#pragma unroll
      for (int u = 0; u < 4; ++u) dot[mm][u] = fmaf(x, v[u], dot[mm][u]);
    }
  }
  for (int mm = 0; mm < 8; ++mm) {
    float* row = la + ((size_t)b * N + m0 + mm) * N;
#pragma unroll
    for (int u = 0; u < 4; ++u) {
      float dist2 = fmaxf(n0s[mm] + n1[u] - 2.f * dot[mm][u], 1e-30f);
      row[t + u * 256] = -sqrtf(dist2);
    }
  }
}

// ---------------------------------------------------------------- sinkhorn offset form
__global__ __launch_bounds__(256) void k_row_r(const float* __restrict__ l0,
                                               const float* __restrict__ cvec,
                                               float* __restrict__ r,
                                               int useC) {
  __shared__ float red[256];
  int t = threadIdx.x;
  int bm = blockIdx.x;              // over B*N
  int b = bm >> 10;
  const float* row = l0 + (size_t)bm * N;
  float v0 = row[t], v1 = row[t + 256], v2 = row[t + 512], v3 = row[t + 768];
  if (useC) {
    const float* cl = cvec + (size_t)b * N;
    v0 -= cl[t]; v1 -= cl[t + 256]; v2 -= cl[t + 512]; v3 -= cl[t + 768];
  }
  float mx = fmaxf(fmaxf(v0, v1), fmaxf(v2, v3));
  red[t] = mx; __syncthreads();
  for (int s = 128; s > 0; s >>= 1) {
    if (t < s) red[t] = fmaxf(red[t], red[t + s]);
    __syncthreads();
  }
  mx = red[0]; __syncthreads();
  float se = __expf(v0 - mx) + __expf(v1 - mx) + __expf(v2 - mx) + __expf(v3 - mx);
  red[t] = se; __syncthreads();
  for (int s = 128; s > 0; s >>= 1) {
    if (t < s) red[t] += red[t + s];
    __syncthreads();
  }
  if (t == 0) r[bm] = mx + __logf(red[0]);
}

__global__ __launch_bounds__(256) void k_col_part(const float* __restrict__ l0,
                                                  const float* __restrict__ r,
                                                  float* __restrict__ pmax,
                                                  float* __restrict__ psum) {
  int t = threadIdx.x;
  int n = blockIdx.x * 256 + t;
  int p = blockIdx.y, b = blockIdx.z;
  const float* base = l0 + ((size_t)b * N + p * 32) * N + n;
  const float* rr = r + (size_t)b * N + p * 32;
  float mx = -1e30f, s = 0;
  for (int m = 0; m < 32; ++m) {
    float v = base[(size_t)m * N] - rr[m];
    if (v > mx) { s = s * __expf(mx - v) + 1.f; mx = v; }
    else s += __expf(v - mx);
  }
  pmax[((size_t)b * 32 + p) * N + n] = mx;
  psum[((size_t)b * 32 + p) * N + n] = s;
}

__global__ __launch_bounds__(256) void k_col_fin(const float* __restrict__ pmax,
                                                 const float* __restrict__ psum,
                                                 float* __restrict__ cvec) {
  int i = blockIdx.x * 256 + threadIdx.x;  // over B*N
  int b = i / N, n = i % N;
  float mx = -1e30f;
#pragma unroll
  for (int p = 0; p < 32; ++p) mx = fmaxf(mx, pmax[((size_t)b * 32 + p) * N + n]);
  float s = 0;
#pragma unroll
  for (int p = 0; p < 32; ++p)
    s += psum[((size_t)b * 32 + p) * N + n] * __expf(pmax[((size_t)b * 32 + p) * N + n] - mx);
  cvec[i] = mx + __logf(s);
}

// ---------------------------------------------------------------- rodrigues + transform
__global__ __launch_bounds__(256) void k_rod(const float* __restrict__ pose,
                                             const float* __restrict__ p3d,
                                             float* __restrict__ p3dt) {
  int b = blockIdx.y;
  int n = blockIdx.x * 256 + threadIdx.x;
  const float* aa = pose + b * 6;
  float ax = aa[0], ay = aa[1], az = aa[2];
  float th = fmaxf(sqrtf(ax * ax + ay * ay + az * az), 1e-8f);
  float rx = ax / th, ry = ay / th, rz = az / th;
  float c = cosf(th), s = sinf(th), oc = 1.f - c;
  float R00 = c + oc * rx * rx,      R01 = oc * rx * ry - s * rz, R02 = oc * rx * rz + s * ry;
  float R10 = oc * ry * rx + s * rz, R11 = c + oc * ry * ry,      R12 = oc * ry * rz - s * rx;
  float R20 = oc * rz * rx - s * ry, R21 = oc * rz * ry + s * rx, R22 = c + oc * rz * rz;
  const float* p = p3d + ((size_t)b * N + n) * 3;
  float x = p[0], y = p[1], z = p[2];
  float X = R00 * x + R01 * y + R02 * z + aa[3];
  float Y = R10 * x + R11 * y + R12 * z + aa[4];
  float Z = R20 * x + R21 * y + R22 * z + aa[5];
  float inr = 1.f / sqrtf(X * X + Y * Y + Z * Z);
  float* o = p3dt + ((size_t)b * N + n) * 3;
  o[0] = X * inr; o[1] = Y * inr; o[2] = Z * inr;
}

// ---------------------------------------------------------------- final error (applies r,c offsets)
__global__ __launch_bounds__(256) void k_err(const float* __restrict__ l0,
                                             const float* __restrict__ r,
                                             const float* __restrict__ cvec,
                                             const float* __restrict__ f2,
                                             const float* __restrict__ p3dt,
                                             float* __restrict__ rowsum) {
  __shared__ float red[256];
  int m = blockIdx.x, b = blockIdx.y, t = threadIdx.x;
  const float* row = l0 + ((size_t)b * N + m) * N;
  const float* cl = cvec + (size_t)b * N;
  const float rm = r[(size_t)b * N + m];
  const float* f = f2 + ((size_t)b * N + m) * 3;
  float fx = f[0], fy = f[1], fz = f[2];
  float s = 0;
  for (int n = t; n < N; n += 256) {
    const float* pp = p3dt + ((size_t)b * N + n) * 3;
    float dot = fx * pp[0] + fy * pp[1] + fz * pp[2];
    s += __expf(row[n] - rm - cl[n]) * (1.f - dot);
  }
  red[t] = s; __syncthreads();
  for (int sft = 128; sft > 0; sft >>= 1) {
    if (t < sft) red[t] += red[t + sft];
    __syncthreads();
  }
  if (t == 0) rowsum[(size_t)b * N + m] = red[0];
}

__global__ __launch_bounds__(256) void k_err_fin(const float* __restrict__ rowsum,
                                                 float* __restrict__ out) {
  __shared__ float red[256];
  int b = blockIdx.x, t = threadIdx.x;
  float s = 0;
  for (int i = t; i < N; i += 256) s += rowsum[(size_t)b * N + i];
  red[t] = s; __syncthreads();
  for (int sft = 128; sft > 0; sft >>= 1) {
    if (t < sft) red[t] += red[t + sft];
    __syncthreads();
  }
  if (t == 0) out[b] = red[0];
}

// ================================================================= host
extern "C" void kernel_launch(void* const* d_in, const int* in_sizes, int n_in,
                              void* d_out, int out_size, void* d_ws, size_t ws_size,
                              hipStream_t stream) {
  const float* p2d     = (const float*)d_in[0];
  const float* p3d     = (const float*)d_in[1];
  const float* pose    = (const float*)d_in[2];
  const float* enc2d_w = (const float*)d_in[3];
  const float* enc2d_b = (const float*)d_in[4];
  const float* enc3d_w = (const float*)d_in[5];
  const float* enc3d_b = (const float*)d_in[6];
  const float* proj_w  = (const float*)d_in[7];
  const float* proj_b  = (const float*)d_in[8];
  const float* merge_w = (const float*)d_in[9];
  const float* merge_b = (const float*)d_in[10];
  const float* mlp1_w  = (const float*)d_in[11];
  const float* mlp1_b  = (const float*)d_in[12];
  const float* bn_g    = (const float*)d_in[13];
  const float* bn_b    = (const float*)d_in[14];
  const float* mlp2_w  = (const float*)d_in[15];
  const float* mlp2_b  = (const float*)d_in[16];

  float* W = (float*)d_ws;
  size_t off = 0;
  auto alloc = [&](size_t nelem) { float* p = W + off; off += nelem; return p; };
  const size_t SET = (size_t)B * D * N;
  float* f2    = alloc((size_t)B * N * 3);
  float* p3dt  = alloc((size_t)B * N * 3);
  float* descA = alloc(2 * SET);
  float* descB = alloc(2 * SET);
  float* qkv   = alloc(3 * 2 * SET);
  float* attnb = alloc(2 * SET);
  float* msgb  = alloc(2 * SET);
  float* hb    = alloc((size_t)2 * B * 256 * N);
  float* stat  = alloc(2 * 256 * 2);
  float* la    = alloc((size_t)B * N * N);
  float* pmax  = alloc((size_t)B * 32 * N);
  float* psum  = alloc((size_t)B * 32 * N);
  float* cvec  = alloc((size_t)B * N);
  float* rvec  = alloc((size_t)B * N);
  float* rowsum= alloc((size_t)B * N);
  (void)ws_size; (void)in_sizes; (void)n_in; (void)out_size;

  float* Qb = qkv;
  float* Kb = qkv + 2 * SET;
  float* Vb = qkv + 4 * SET;
  const size_t DS = (size_t)D * N;

  k_norm2d<<<(B * N) / 256, 256, 0, stream>>>(p2d, f2);
  k_encode<<<dim3(N, B), 256, 0, stream>>>(f2, enc2d_w, enc2d_b, descA);
  k_encode<<<dim3(N, B), 256, 0, stream>>>(p3d, enc3d_w, enc3d_b, descA + SET);

  float* dc = descA;
  float* dn = descB;
  for (int i = 0; i < 6; ++i) {
    int cross = (i & 1);
    const float* pw = proj_w + (size_t)i * 3 * D * D;
    const float* pb = proj_b + (size_t)i * 3 * D;
    float* d0 = dc;
    float* d1 = dc + SET;
    const float* sA = cross ? d1 : d0;
    const float* sB = cross ? d0 : d1;

    k_gemm<<<dim3(64, 6), 256, 0, stream>>>(
        d0, d1, sA, sB, pw, pb, nullptr, qkv, nullptr, nullptr, nullptr,
        D, D, DS, DS, D, 2 * SET, 1);
    k_attn<<<dim3(N / 128, NH, 2 * B), 512, 0, stream>>>(Qb, Kb, Vb, attnb);
    k_gemm<<<dim3(64, 2), 256, 0, stream>>>(
        attnb, attnb + SET, nullptr, nullptr, merge_w + (size_t)i * D * D,
        merge_b + (size_t)i * D, nullptr, msgb, nullptr, nullptr, nullptr,
        D, D, DS, DS, D, 0, 0);
    k_gemm<<<dim3(64, 4), 256, 0, stream>>>(
        dc, dc + SET, msgb, msgb + SET, mlp1_w + (size_t)i * 256 * 256,
        mlp1_b + (size_t)i * 256, nullptr, hb, nullptr, nullptr, nullptr,
        256, 128, DS, DS, 256, 0, 0);
    k_bnstat<<<dim3(256, 2), 256, 0, stream>>>(hb, stat);
    k_gemm<<<dim3(64, 2), 256, 0, stream>>>(
        hb, hb + (size_t)B * 256 * N, nullptr, nullptr,
        mlp2_w + (size_t)i * D * 256, mlp2_b + (size_t)i * D, dc, dn,
        stat, bn_g + (size_t)i * 256, bn_b + (size_t)i * 256,
        256, 256, (size_t)256 * N, 0, D, 0, 0);
    float* tmp = dc; dc = dn; dn = tmp;
  }

  k_dist<<<dim3(N / 8, B), 256, 0, stream>>>(dc, dc + SET, la);
  for (int it = 0; it < 10; ++it) {
    k_row_r<<<B * N, 256, 0, stream>>>(la, cvec, rvec, it > 0 ? 1 : 0);
    k_col_part<<<dim3(N / 256, 32, B), 256, 0, stream>>>(la, rvec, pmax, psum);
    k_col_fin<<<(B * N) / 256, 256, 0, stream>>>(pmax, psum, cvec);
  }
  k_rod<<<dim3(N / 256, B), 256, 0, stream>>>(pose, p3d, p3dt);
  k_err<<<dim3(N, B), 256, 0, stream>>>(la, rvec, cvec, f2, p3dt, rowsum);
  k_err_fin<<<B, 256, 0, stream>>>(rowsum, (float*)d_out);
}

// Round 17
// 874.555 us; speedup vs baseline: 2.1839x; 1.0729x over previous
//
#include <hip/hip_runtime.h>
#include <hip/hip_bf16.h>

constexpr int B   = 4;
constexpr int N   = 1024;
constexpr int D   = 128;
constexpr int KNN = 10;
constexpr int NH  = 4;

typedef _Float16 half2v __attribute__((ext_vector_type(2)));
typedef _Float16 f16x4  __attribute__((ext_vector_type(4)));
typedef _Float16 f16x8  __attribute__((ext_vector_type(8)));
typedef float    f32x4  __attribute__((ext_vector_type(4)));

static __device__ __forceinline__ half2v pkrtz(float a, float b) {
  return __builtin_bit_cast(half2v, __builtin_amdgcn_cvt_pkrtz(a, b));
}
static __device__ __forceinline__ float h2f(half2v h) {
  return __builtin_bit_cast(float, h);
}

// ---------------------------------------------------------------- norm p2d
__global__ __launch_bounds__(256) void k_norm2d(const float* __restrict__ p2d,
                                                float* __restrict__ f2) {
  int i = blockIdx.x * 256 + threadIdx.x;  // over B*N
  const float* p = p2d + (size_t)i * 3;
  float x = p[0], y = p[1], z = p[2];
  float inr = 1.f / sqrtf(x * x + y * y + z * z);
  float* o = f2 + (size_t)i * 3;
  o[0] = x * inr; o[1] = y * inr; o[2] = z * inr;
}

// ---------------------------------------------------------------- KNN encode v2: wave-per-query
// grid (N/4, B), 256 thr = 4 waves. Points staged ONCE in SoA LDS; each wave
// owns one query with its 1024 distances in 16 regs/lane (j = i*64 + lane).
// Top-10 = 10 x (15 local compares + 6-level shfl_xor (val,idx), lowest-index
// tie-break) — ZERO barriers in the selection loop (old version: ~100/block).
__global__ __launch_bounds__(256) void k_encode(const float* __restrict__ pts,
                                                const float* __restrict__ w,
                                                const float* __restrict__ bias,
                                                float* __restrict__ desc) {
  __shared__ float Px[N], Py[N], Pz[N], Xx[N];
  const int t = threadIdx.x;
  const int l = t & 63, wv = t >> 6;
  const int n = blockIdx.x * 4 + wv;
  const int b = blockIdx.y;
  const float* pb = pts + (size_t)b * N * 3;
  for (int i = t; i < N; i += 256) {
    float x = pb[i * 3 + 0], y = pb[i * 3 + 1], z = pb[i * 3 + 2];
    Px[i] = x; Py[i] = y; Pz[i] = z;
    Xx[i] = x * x + y * y + z * z;
  }
  __syncthreads();
  const float cx = Px[n], cy = Py[n], cz = Pz[n], cxx = Xx[n];
  // distances in registers: j = i*64 + l
  float dist[16];
#pragma unroll
  for (int i = 0; i < 16; ++i) {
    int j = i * 64 + l;
    float ip = cx * Px[j] + cy * Py[j] + cz * Pz[j];
    dist[i] = 2.f * ip - cxx - Xx[j];
  }
  float sx = 0.f, sy = 0.f, sz = 0.f;
#pragma unroll
  for (int kk = 0; kk < KNN; ++kk) {
    // local best over 16 regs (ascending i -> lowest index kept on tie)
    float bv = dist[0]; int bi = l;
#pragma unroll
    for (int i = 1; i < 16; ++i) {
      if (dist[i] > bv) { bv = dist[i]; bi = i * 64 + l; }
    }
    // wave butterfly reduce (val, idx), tie-break lowest idx
#pragma unroll
    for (int sft = 1; sft < 64; sft <<= 1) {
      float v2 = __shfl_xor(bv, sft, 64);
      int   i2 = __shfl_xor(bi, sft, 64);
      if (v2 > bv || (v2 == bv && i2 < bi)) { bv = v2; bi = i2; }
    }
    // accumulate neighbor coords (all lanes redundantly, LDS broadcast)
    sx += Px[bi]; sy += Py[bi]; sz += Pz[bi];
    // invalidate winner in its owner's registers
    if ((bi & 63) == l) {
      int io = bi >> 6;
#pragma unroll
      for (int i = 0; i < 16; ++i)
        if (i == io) dist[i] = -3.0e38f;
    }
  }
  const float invk = 1.f / KNN;
  float feat[6];
  feat[0] = sx * invk - cx; feat[1] = sy * invk - cy; feat[2] = sz * invk - cz;
  feat[3] = cx; feat[4] = cy; feat[5] = cz;
  // epilogue: 2 channels per lane
#pragma unroll
  for (int rep = 0; rep < 2; ++rep) {
    int c = rep * 64 + l;
    const float* wr = w + c * 6;
    float a = bias[c];
#pragma unroll
    for (int j = 0; j < 6; ++j) a += wr[j] * feat[j];
    desc[((size_t)b * D + c) * N + n] = a;
  }
}

// ---------------------------------------------------------------- tiled GEMM conv v3: MFMA f16 (R15, validated)
__global__ __launch_bounds__(256) void k_gemm(
    const float* __restrict__ pA0, const float* __restrict__ pA1,
    const float* __restrict__ pB0, const float* __restrict__ pB1,
    const float* __restrict__ w, const float* __restrict__ bias,
    const float* __restrict__ res, float* __restrict__ out,
    const float* __restrict__ stat, const float* __restrict__ g,
    const float* __restrict__ bt,
    int Cin, int catOff, size_t a_bstr, size_t b_bstr,
    int segCout, size_t segStride, int qkvMode) {
  __shared__ _Float16 As[64][48];
  __shared__ half2v   Bs[16][132];
  __shared__ float Ac[256], Bc[256];
  const int tid = threadIdx.x;
  const int wv  = tid >> 6;
  const int l   = tid & 63;
  const int wo  = wv >> 1;
  const int wn  = wv & 1;
  const int lr  = l & 15;
  const int lg  = l >> 4;
  const int o0 = blockIdx.y * 64;
  const int zb = blockIdx.x;
  const int z  = zb >> 3;
  const int n0 = (zb & 7) * 128;
  const int s = z >> 2, b = z & 3;
  const int seg = o0 / segCout;
  const int oo  = o0 % segCout;

  const float* XA = (s ? pA1 : pA0) + (size_t)b * a_bstr;
  const float* XB = pB0 ? ((s ? pB1 : pB0) + (size_t)b * b_bstr) : nullptr;
  const bool segB = qkvMode && (seg > 0);

  if (stat) {
    const float* st = stat + (size_t)s * 256 * 2;
    float A = st[tid * 2 + 1] * g[tid];
    Ac[tid] = A;
    Bc[tid] = fmaf(-st[tid * 2 + 0], A, bt[tid]);
  }

  f32x4 acc[2][4];
#pragma unroll
  for (int i = 0; i < 2; ++i)
#pragma unroll
    for (int j = 0; j < 4; ++j) acc[i][j] = (f32x4){0.f, 0.f, 0.f, 0.f};

  for (int kb = 0; kb < Cin; kb += 32) {
    __syncthreads();
#pragma unroll
    for (int j = 0; j < 2; ++j) {
      int idx = j * 256 + tid;
      int o = idx >> 3, c4 = (idx & 7) * 4;
      float4 wvv = *(const float4*)&w[(size_t)(o0 + o) * Cin + kb + c4];
      *(half2v*)&As[o][c4]     = pkrtz(wvv.x, wvv.y);
      *(half2v*)&As[o][c4 + 2] = pkrtz(wvv.z, wvv.w);
    }
#pragma unroll
    for (int j = 0; j < 2; ++j) {
      int idx = j * 256 + tid;
      int rp = idx >> 5, c4 = (idx & 31) * 4;
      int c0 = kb + 2 * rp, c1 = c0 + 1;
      const float* s0; int cc0 = c0;
      const float* s1; int cc1 = c1;
      if (qkvMode) {
        s0 = segB ? XB : XA; s1 = s0;
      } else {
        if (c0 >= catOff) { s0 = XB; cc0 = c0 - catOff; } else s0 = XA;
        if (c1 >= catOff) { s1 = XB; cc1 = c1 - catOff; } else s1 = XA;
      }
      float4 v0 = *(const float4*)&s0[(size_t)cc0 * N + n0 + c4];
      float4 v1 = *(const float4*)&s1[(size_t)cc1 * N + n0 + c4];
      if (stat) {
        float A0 = Ac[c0], B0 = Bc[c0], A1 = Ac[c1], B1 = Bc[c1];
        v0.x = fmaxf(fmaf(v0.x, A0, B0), 0.f);
        v0.y = fmaxf(fmaf(v0.y, A0, B0), 0.f);
        v0.z = fmaxf(fmaf(v0.z, A0, B0), 0.f);
        v0.w = fmaxf(fmaf(v0.w, A0, B0), 0.f);
        v1.x = fmaxf(fmaf(v1.x, A1, B1), 0.f);
        v1.y = fmaxf(fmaf(v1.y, A1, B1), 0.f);
        v1.z = fmaxf(fmaf(v1.z, A1, B1), 0.f);
        v1.w = fmaxf(fmaf(v1.w, A1, B1), 0.f);
      }
      float4 packed;
      packed.x = h2f(pkrtz(v0.x, v1.x));
      packed.y = h2f(pkrtz(v0.y, v1.y));
      packed.z = h2f(pkrtz(v0.z, v1.z));
      packed.w = h2f(pkrtz(v0.w, v1.w));
      *(float4*)&Bs[rp][c4] = packed;
    }
    __syncthreads();
    f16x8 afr0 = *(const f16x8*)&As[wo * 32 + lr][lg * 8];
    f16x8 afr1 = *(const f16x8*)&As[wo * 32 + 16 + lr][lg * 8];
#pragma unroll
    for (int tj = 0; tj < 4; ++tj) {
      int nn = wn * 64 + tj * 16 + lr;
      float4 btmp;
      btmp.x = *(const float*)&Bs[lg * 4 + 0][nn];
      btmp.y = *(const float*)&Bs[lg * 4 + 1][nn];
      btmp.z = *(const float*)&Bs[lg * 4 + 2][nn];
      btmp.w = *(const float*)&Bs[lg * 4 + 3][nn];
      f16x8 bfr = __builtin_bit_cast(f16x8, btmp);
      acc[0][tj] = __builtin_amdgcn_mfma_f32_16x16x32_f16(afr0, bfr, acc[0][tj], 0, 0, 0);
      acc[1][tj] = __builtin_amdgcn_mfma_f32_16x16x32_f16(afr1, bfr, acc[1][tj], 0, 0, 0);
    }
  }
#pragma unroll
  for (int ti = 0; ti < 2; ++ti) {
#pragma unroll
    for (int tj = 0; tj < 4; ++tj) {
      int nn = n0 + wn * 64 + tj * 16 + lr;
#pragma unroll
      for (int r = 0; r < 4; ++r) {
        int lrow = wo * 32 + ti * 16 + lg * 4 + r;
        size_t ob = (size_t)seg * segStride +
                    ((size_t)z * segCout + oo + lrow) * N + nn;
        float v = acc[ti][tj][r] + bias[o0 + lrow];
        if (res) v += res[ob];
        out[ob] = v;
      }
    }
  }
}

// ---------------------------------------------------------------- attention v10: MFMA flash (R16, validated)
__global__ __launch_bounds__(512) void k_attn(const float* __restrict__ Q,
                                              const float* __restrict__ Kt,
                                              const float* __restrict__ Vt,
                                              float* __restrict__ O) {
  __shared__ _Float16 Klds[128][40];
  __shared__ _Float16 Vlds[32][136];
  const int t  = threadIdx.x;
  const int l  = t & 63, w = t >> 6;
  const int lr = l & 15, lg = l >> 4;
  const int q0 = blockIdx.x * 128 + w * 16;
  const int h  = blockIdx.y;
  const int z  = blockIdx.z;
  const size_t base = (size_t)z * (size_t)(D * N);
  const float* Kg = Kt + base + (size_t)h * N;
  const float* Vg = Vt + base + (size_t)h * N;
  const float scale = 0.17677669529663687f;

  f16x8 qfrag;
  {
    float qv[8];
#pragma unroll
    for (int j = 0; j < 8; ++j)
      qv[j] = Q[base + (size_t)((lg * 8 + j) * 4 + h) * N + q0 + lr] * scale;
    float4 qp;
    qp.x = h2f(pkrtz(qv[0], qv[1]));
    qp.y = h2f(pkrtz(qv[2], qv[3]));
    qp.z = h2f(pkrtz(qv[4], qv[5]));
    qp.w = h2f(pkrtz(qv[6], qv[7]));
    qfrag = __builtin_bit_cast(f16x8, qp);
  }

  f32x4 oacc0 = (f32x4){0.f, 0.f, 0.f, 0.f};
  f32x4 oacc1 = (f32x4){0.f, 0.f, 0.f, 0.f};
  float m = -1e30f, lsum = 0.f;

  for (int c = 0; c < 8; ++c) {
    const int k0 = c * 128;
    __syncthreads();
    {
      int kk = t & 127, d0 = (t >> 7) * 8;
      float kv[8];
#pragma unroll
      for (int j = 0; j < 8; ++j)
        kv[j] = Kg[(size_t)((d0 + j) * 4) * N + k0 + kk];
      float4 pk;
      pk.x = h2f(pkrtz(kv[0], kv[1]));
      pk.y = h2f(pkrtz(kv[2], kv[3]));
      pk.z = h2f(pkrtz(kv[4], kv[5]));
      pk.w = h2f(pkrtz(kv[6], kv[7]));
      *(float4*)&Klds[kk][d0] = pk;
      int dv = t & 31, ko = (t >> 5) * 8;
      const float* vp = Vg + (size_t)(dv * 4) * N + k0 + ko;
      float4 v0 = *(const float4*)vp;
      float4 v1 = *(const float4*)(vp + 4);
      float4 pv;
      pv.x = h2f(pkrtz(v0.x, v0.y)); pv.y = h2f(pkrtz(v0.z, v0.w));
      pv.z = h2f(pkrtz(v1.x, v1.y)); pv.w = h2f(pkrtz(v1.z, v1.w));
      *(float4*)&Vlds[dv][ko] = pv;
    }
    __syncthreads();
#pragma unroll
    for (int kt = 0; kt < 8; ++kt) {
      f16x8 kfrag = *(const f16x8*)&Klds[kt * 16 + lr][lg * 8];
      f32x4 s = __builtin_amdgcn_mfma_f32_16x16x32_f16(
          kfrag, qfrag, (f32x4){0.f, 0.f, 0.f, 0.f}, 0, 0, 0);
      float tmax = fmaxf(fmaxf(s[0], s[1]), fmaxf(s[2], s[3]));
      tmax = fmaxf(tmax, __shfl_xor(tmax, 16, 64));
      tmax = fmaxf(tmax, __shfl_xor(tmax, 32, 64));
      float nm = fmaxf(m, tmax);
      float corr = __expf(m - nm);
      m = nm;
      lsum *= corr;
#pragma unroll
      for (int r = 0; r < 4; ++r) { oacc0[r] *= corr; oacc1[r] *= corr; }
      float p0 = __expf(s[0] - m), p1 = __expf(s[1] - m);
      float p2 = __expf(s[2] - m), p3 = __expf(s[3] - m);
      float ts = p0 + p1 + p2 + p3;
      ts += __shfl_xor(ts, 16, 64);
      ts += __shfl_xor(ts, 32, 64);
      lsum += ts;
      float2 ptmp;
      ptmp.x = h2f(pkrtz(p0, p1));
      ptmp.y = h2f(pkrtz(p2, p3));
      f16x4 pfrag = __builtin_bit_cast(f16x4, ptmp);
      float2 vt0 = *(const float2*)&Vlds[lr][kt * 16 + lg * 4];
      float2 vt1 = *(const float2*)&Vlds[16 + lr][kt * 16 + lg * 4];
      f16x4 vf0 = __builtin_bit_cast(f16x4, vt0);
      f16x4 vf1 = __builtin_bit_cast(f16x4, vt1);
      oacc0 = __builtin_amdgcn_mfma_f32_16x16x16f16(vf0, pfrag, oacc0, 0, 0, 0);
      oacc1 = __builtin_amdgcn_mfma_f32_16x16x16f16(vf1, pfrag, oacc1, 0, 0, 0);
    }
  }
  float invL = 1.f / lsum;
#pragma unroll
  for (int r = 0; r < 4; ++r) {
    int d0 = lg * 4 + r;
    O[base + (size_t)(d0 * 4 + h) * N + q0 + lr] = oacc0[r] * invL;
    int d1 = 16 + lg * 4 + r;
    O[base + (size_t)(d1 * 4 + h) * N + q0 + lr] = oacc1[r] * invL;
  }
}

// ---------------------------------------------------------------- BN stats (single pass)
__global__ __launch_bounds__(256) void k_bnstat(const float* __restrict__ h,
                                                float* __restrict__ stat) {
  int c = blockIdx.x, s = blockIdx.y, t = threadIdx.x;
  __shared__ float red[256], red2[256];
  const float* base = h + ((size_t)s * B * 256 + c) * N;
  float sum = 0, sq = 0;
  for (int b = 0; b < B; ++b)
    for (int i = t; i < N; i += 256) {
      float v = base[(size_t)b * 256 * N + i];
      sum += v; sq = fmaf(v, v, sq);
    }
  red[t] = sum; red2[t] = sq; __syncthreads();
  for (int sft = 128; sft > 0; sft >>= 1) {
    if (t < sft) { red[t] += red[t + sft]; red2[t] += red2[t + sft]; }
    __syncthreads();
  }
  if (t == 0) {
    float mean = red[0] / (float)(B * N);
    float var = fmaxf(red2[0] / (float)(B * N) - mean * mean, 0.f);
    stat[(s * 256 + c) * 2 + 0] = mean;
    stat[(s * 256 + c) * 2 + 1] = 1.f / sqrtf(var + 1e-5f);
  }
}

// ---------------------------------------------------------------- pairwise dist (8-m tile)
__global__ __launch_bounds__(256) void k_dist(const float* __restrict__ d0,
                                              const float* __restrict__ d1,
                                              float* __restrict__ la) {
  __shared__ float xm[8][128];
  __shared__ float n0s[8];
  int m0 = blockIdx.x * 8, b = blockIdx.y, t = threadIdx.x;
  const float* p0 = d0 + (size_t)b * D * N;
  const float* p1 = d1 + (size_t)b * D * N;
  for (int i = t; i < 8 * 128; i += 256) {
    int mm = i >> 7, d = i & 127;
    xm[mm][d] = p0[(size_t)d * N + m0 + mm];
  }
  __syncthreads();
  if (t < 8) {
    float s = 0;
    for (int d = 0; d < 128; ++d) s += xm[t][d] * xm[t][d];
    n0s[t] = s;
  }
  __syncthreads();
  float dot[8][4] = {{0}};
  float n1[4] = {0, 0, 0, 0};
  for (int d = 0; d < 128; ++d) {
    float v[4];
#pragma unroll
    for (int u = 0; u < 4; ++u) {
      v[u] = p1[(size_t)d * N + t + u * 256];
      n1[u] = fmaf(v[u], v[u], n1[u]);
    }
#pragma unroll
    for (int mm = 0; mm < 8; ++mm) {
      float x = xm[mm][d];
#pragma unroll
      for (int u = 0; u < 4; ++u) dot[mm][u] = fmaf(x, v[u], dot[mm][u]);
    }
  }
  for (int mm = 0; mm < 8; ++mm) {
    float* row = la + ((size_t)b * N + m0 + mm) * N;
#pragma unroll
    for (int u = 0; u < 4; ++u) {
      float dist2 = fmaxf(n0s[mm] + n1[u] - 2.f * dot[mm][u], 1e-30f);
      row[t + u * 256] = -sqrtf(dist2);
    }
  }
}

// ---------------------------------------------------------------- sinkhorn offset form
__global__ __launch_bounds__(256) void k_row_r(const float* __restrict__ l0,
                                               const float* __restrict__ cvec,
                                               float* __restrict__ r,
                                               int useC) {
  __shared__ float red[256];
  int t = threadIdx.x;
  int bm = blockIdx.x;              // over B*N
  int b = bm >> 10;
  const float* row = l0 + (size_t)bm * N;
  float v0 = row[t], v1 = row[t + 256], v2 = row[t + 512], v3 = row[t + 768];
  if (useC) {
    const float* cl = cvec + (size_t)b * N;
    v0 -= cl[t]; v1 -= cl[t + 256]; v2 -= cl[t + 512]; v3 -= cl[t + 768];
  }
  float mx = fmaxf(fmaxf(v0, v1), fmaxf(v2, v3));
  red[t] = mx; __syncthreads();
  for (int s = 128; s > 0; s >>= 1) {
    if (t < s) red[t] = fmaxf(red[t], red[t + s]);
    __syncthreads();
  }
  mx = red[0]; __syncthreads();
  float se = __expf(v0 - mx) + __expf(v1 - mx) + __expf(v2 - mx) + __expf(v3 - mx);
  red[t] = se; __syncthreads();
  for (int s = 128; s > 0; s >>= 1) {
    if (t < s) red[t] += red[t + s];
    __syncthreads();
  }
  if (t == 0) r[bm] = mx + __logf(red[0]);
}

__global__ __launch_bounds__(256) void k_col_part(const float* __restrict__ l0,
                                                  const float* __restrict__ r,
                                                  float* __restrict__ pmax,
                                                  float* __restrict__ psum) {
  int t = threadIdx.x;
  int n = blockIdx.x * 256 + t;
  int p = blockIdx.y, b = blockIdx.z;
  const float* base = l0 + ((size_t)b * N + p * 32) * N + n;
  const float* rr = r + (size_t)b * N + p * 32;
  float mx = -1e30f, s = 0;
  for (int m = 0; m < 32; ++m) {
    float v = base[(size_t)m * N] - rr[m];
    if (v > mx) { s = s * __expf(mx - v) + 1.f; mx = v; }
    else s += __expf(v - mx);
  }
  pmax[((size_t)b * 32 + p) * N + n] = mx;
  psum[((size_t)b * 32 + p) * N + n] = s;
}

__global__ __launch_bounds__(256) void k_col_fin(const float* __restrict__ pmax,
                                                 const float* __restrict__ psum,
                                                 float* __restrict__ cvec) {
  int i = blockIdx.x * 256 + threadIdx.x;  // over B*N
  int b = i / N, n = i % N;
  float mx = -1e30f;
#pragma unroll
  for (int p = 0; p < 32; ++p) mx = fmaxf(mx, pmax[((size_t)b * 32 + p) * N + n]);
  float s = 0;
#pragma unroll
  for (int p = 0; p < 32; ++p)
    s += psum[((size_t)b * 32 + p) * N + n] * __expf(pmax[((size_t)b * 32 + p) * N + n] - mx);
  cvec[i] = mx + __logf(s);
}

// ---------------------------------------------------------------- rodrigues + transform
__global__ __launch_bounds__(256) void k_rod(const float* __restrict__ pose,
                                             const float* __restrict__ p3d,
                                             float* __restrict__ p3dt) {
  int b = blockIdx.y;
  int n = blockIdx.x * 256 + threadIdx.x;
  const float* aa = pose + b * 6;
  float ax = aa[0], ay = aa[1], az = aa[2];
  float th = fmaxf(sqrtf(ax * ax + ay * ay + az * az), 1e-8f);
  float rx = ax / th, ry = ay / th, rz = az / th;
  float c = cosf(th), s = sinf(th), oc = 1.f - c;
  float R00 = c + oc * rx * rx,      R01 = oc * rx * ry - s * rz, R02 = oc * rx * rz + s * ry;
  float R10 = oc * ry * rx + s * rz, R11 = c + oc * ry * ry,      R12 = oc * ry * rz - s * rx;
  float R20 = oc * rz * rx - s * ry, R21 = oc * rz * ry + s * rx, R22 = c + oc * rz * rz;
  const float* p = p3d + ((size_t)b * N + n) * 3;
  float x = p[0], y = p[1], z = p[2];
  float X = R00 * x + R01 * y + R02 * z + aa[3];
  float Y = R10 * x + R11 * y + R12 * z + aa[4];
  float Z = R20 * x + R21 * y + R22 * z + aa[5];
  float inr = 1.f / sqrtf(X * X + Y * Y + Z * Z);
  float* o = p3dt + ((size_t)b * N + n) * 3;
  o[0] = X * inr; o[1] = Y * inr; o[2] = Z * inr;
}

// ---------------------------------------------------------------- final error (applies r,c offsets)
__global__ __launch_bounds__(256) void k_err(const float* __restrict__ l0,
                                             const float* __restrict__ r,
                                             const float* __restrict__ cvec,
                                             const float* __restrict__ f2,
                                             const float* __restrict__ p3dt,
                                             float* __restrict__ rowsum) {
  __shared__ float red[256];
  int m = blockIdx.x, b = blockIdx.y, t = threadIdx.x;
  const float* row = l0 + ((size_t)b * N + m) * N;
  const float* cl = cvec + (size_t)b * N;
  const float rm = r[(size_t)b * N + m];
  const float* f = f2 + ((size_t)b * N + m) * 3;
  float fx = f[0], fy = f[1], fz = f[2];
  float s = 0;
  for (int n = t; n < N; n += 256) {
    const float* pp = p3dt + ((size_t)b * N + n) * 3;
    float dot = fx * pp[0] + fy * pp[1] + fz * pp[2];
    s += __expf(row[n] - rm - cl[n]) * (1.f - dot);
  }
  red[t] = s; __syncthreads();
  for (int sft = 128; sft > 0; sft >>= 1) {
    if (t < sft) red[t] += red[t + sft];
    __syncthreads();
  }
  if (t == 0) rowsum[(size_t)b * N + m] = red[0];
}

__global__ __launch_bounds__(256) void k_err_fin(const float* __restrict__ rowsum,
                                                 float* __restrict__ out) {
  __shared__ float red[256];
  int b = blockIdx.x, t = threadIdx.x;
  float s = 0;
  for (int i = t; i < N; i += 256) s += rowsum[(size_t)b * N + i];
  red[t] = s; __syncthreads();
  for (int sft = 128; sft > 0; sft >>= 1) {
    if (t < sft) red[t] += red[t + sft];
    __syncthreads();
  }
  if (t == 0) out[b] = red[0];
}

// ================================================================= host
extern "C" void kernel_launch(void* const* d_in, const int* in_sizes, int n_in,
                              void* d_out, int out_size, void* d_ws, size_t ws_size,
                              hipStream_t stream) {
  const float* p2d     = (const float*)d_in[0];
  const float* p3d     = (const float*)d_in[1];
  const float* pose    = (const float*)d_in[2];
  const float* enc2d_w = (const float*)d_in[3];
  const float* enc2d_b = (const float*)d_in[4];
  const float* enc3d_w = (const float*)d_in[5];
  const float* enc3d_b = (const float*)d_in[6];
  const float* proj_w  = (const float*)d_in[7];
  const float* proj_b  = (const float*)d_in[8];
  const float* merge_w = (const float*)d_in[9];
  const float* merge_b = (const float*)d_in[10];
  const float* mlp1_w  = (const float*)d_in[11];
  const float* mlp1_b  = (const float*)d_in[12];
  const float* bn_g    = (const float*)d_in[13];
  const float* bn_b    = (const float*)d_in[14];
  const float* mlp2_w  = (const float*)d_in[15];
  const float* mlp2_b  = (const float*)d_in[16];

  float* W = (float*)d_ws;
  size_t off = 0;
  auto alloc = [&](size_t nelem) { float* p = W + off; off += nelem; return p; };
  const size_t SET = (size_t)B * D * N;
  float* f2    = alloc((size_t)B * N * 3);
  float* p3dt  = alloc((size_t)B * N * 3);
  float* descA = alloc(2 * SET);
  float* descB = alloc(2 * SET);
  float* qkv   = alloc(3 * 2 * SET);
  float* attnb = alloc(2 * SET);
  float* msgb  = alloc(2 * SET);
  float* hb    = alloc((size_t)2 * B * 256 * N);
  float* stat  = alloc(2 * 256 * 2);
  float* la    = alloc((size_t)B * N * N);
  float* pmax  = alloc((size_t)B * 32 * N);
  float* psum  = alloc((size_t)B * 32 * N);
  float* cvec  = alloc((size_t)B * N);
  float* rvec  = alloc((size_t)B * N);
  float* rowsum= alloc((size_t)B * N);
  (void)ws_size; (void)in_sizes; (void)n_in; (void)out_size;

  float* Qb = qkv;
  float* Kb = qkv + 2 * SET;
  float* Vb = qkv + 4 * SET;
  const size_t DS = (size_t)D * N;

  k_norm2d<<<(B * N) / 256, 256, 0, stream>>>(p2d, f2);
  k_encode<<<dim3(N / 4, B), 256, 0, stream>>>(f2, enc2d_w, enc2d_b, descA);
  k_encode<<<dim3(N / 4, B), 256, 0, stream>>>(p3d, enc3d_w, enc3d_b, descA + SET);

  float* dc = descA;
  float* dn = descB;
  for (int i = 0; i < 6; ++i) {
    int cross = (i & 1);
    const float* pw = proj_w + (size_t)i * 3 * D * D;
    const float* pb = proj_b + (size_t)i * 3 * D;
    float* d0 = dc;
    float* d1 = dc + SET;
    const float* sA = cross ? d1 : d0;
    const float* sB = cross ? d0 : d1;

    k_gemm<<<dim3(64, 6), 256, 0, stream>>>(
        d0, d1, sA, sB, pw, pb, nullptr, qkv, nullptr, nullptr, nullptr,
        D, D, DS, DS, D, 2 * SET, 1);
    k_attn<<<dim3(N / 128, NH, 2 * B), 512, 0, stream>>>(Qb, Kb, Vb, attnb);
    k_gemm<<<dim3(64, 2), 256, 0, stream>>>(
        attnb, attnb + SET, nullptr, nullptr, merge_w + (size_t)i * D * D,
        merge_b + (size_t)i * D, nullptr, msgb, nullptr, nullptr, nullptr,
        D, D, DS, DS, D, 0, 0);
    k_gemm<<<dim3(64, 4), 256, 0, stream>>>(
        dc, dc + SET, msgb, msgb + SET, mlp1_w + (size_t)i * 256 * 256,
        mlp1_b + (size_t)i * 256, nullptr, hb, nullptr, nullptr, nullptr,
        256, 128, DS, DS, 256, 0, 0);
    k_bnstat<<<dim3(256, 2), 256, 0, stream>>>(hb, stat);
    k_gemm<<<dim3(64, 2), 256, 0, stream>>>(
        hb, hb + (size_t)B * 256 * N, nullptr, nullptr,
        mlp2_w + (size_t)i * D * 256, mlp2_b + (size_t)i * D, dc, dn,
        stat, bn_g + (size_t)i * 256, bn_b + (size_t)i * 256,
        256, 256, (size_t)256 * N, 0, D, 0, 0);
    float* tmp = dc; dc = dn; dn = tmp;
  }

  k_dist<<<dim3(N / 8, B), 256, 0, stream>>>(dc, dc + SET, la);
  for (int it = 0; it < 10; ++it) {
    k_row_r<<<B * N, 256, 0, stream>>>(la, cvec, rvec, it > 0 ? 1 : 0);
    k_col_part<<<dim3(N / 256, 32, B), 256, 0, stream>>>(la, rvec, pmax, psum);
    k_col_fin<<<(B * N) / 256, 256, 0, stream>>>(pmax, psum, cvec);
  }
  k_rod<<<dim3(N / 256, B), 256, 0, stream>>>(pose, p3d, p3dt);
  k_err<<<dim3(N, B), 256, 0, stream>>>(la, rvec, cvec, f2, p3dt, rowsum);
  k_err_fin<<<B, 256, 0, stream>>>(rowsum, (float*)d_out);
}